// Round 7
// baseline (330.824 us; speedup 1.0000x reference)
//
#include <hip/hip_runtime.h>
#include <math.h>

#define NQ      6400
#define NCAMS   6
#define LTOT    7979
#define DM      256
#define DFFN    1024

typedef __attribute__((ext_vector_type(8))) short bf16x8;
typedef __attribute__((ext_vector_type(4))) float f32x4;

__device__ inline unsigned short f32_to_bf16(float f) {
    unsigned u = __float_as_uint(f);
    unsigned r = u + 0x7FFF + ((u >> 16) & 1);   // round-to-nearest-even
    return (unsigned short)(r >> 16);
}

// ---------------------------------------------------------------------------
// Weight transpose + convert: WT[n][k] (bf16) = W[k][n] (fp32), all weights
// in one launch. wsT layout (shorts): WvT@0, WqT@65536 ([384][256]),
// WoT@163840, W1T@229376 ([1024][256]), W2T@491520 ([256][1024]).
// ---------------------------------------------------------------------------
__global__ __launch_bounds__(256) void wt_kernel(
    const float* __restrict__ Wv, const float* __restrict__ Woff,
    const float* __restrict__ Wattn, const float* __restrict__ Wout,
    const float* __restrict__ W1, const float* __restrict__ W2,
    unsigned short* __restrict__ wsT)
{
    int b = blockIdx.x;
    const float* src; int K, N, t0, dstoff;
    if (b < 64)       { src = Wv;    K = 256;  N = 256;  t0 = 0;   dstoff = 0; }
    else if (b < 128) { src = Woff;  K = 256;  N = 256;  t0 = 64;  dstoff = 65536; }
    else if (b < 160) { src = Wattn; K = 256;  N = 128;  t0 = 128; dstoff = 131072; }
    else if (b < 224) { src = Wout;  K = 256;  N = 256;  t0 = 160; dstoff = 163840; }
    else if (b < 480) { src = W1;    K = 256;  N = 1024; t0 = 224; dstoff = 229376; }
    else              { src = W2;    K = 1024; N = 256;  t0 = 480; dstoff = 491520; }
    int t = b - t0;
    int ntn = N >> 5;
    int kt = t / ntn, nt = t - kt * ntn;
    __shared__ float tile[32][33];
    int tx = threadIdx.x & 31, ty = threadIdx.x >> 5;
    #pragma unroll
    for (int i = 0; i < 4; ++i)
        tile[ty + i * 8][tx] = src[(size_t)(kt * 32 + ty + i * 8) * N + nt * 32 + tx];
    __syncthreads();
    #pragma unroll
    for (int i = 0; i < 4; ++i) {
        int nn = nt * 32 + ty + i * 8;
        wsT[dstoff + (size_t)nn * K + kt * 32 + tx] = f32_to_bf16(tile[tx][ty + i * 8]);
    }
}

// ---------------------------------------------------------------------------
// Value projection: A fp32 (converted inline while staging), BT bf16.
// BM=BN=128, BK=32 -> bf16 head-major (cam, head, pixel, 32ch) output.
// ---------------------------------------------------------------------------
__global__ __launch_bounds__(256) void gemm_v_kernel(
    const float* __restrict__ A, const unsigned short* __restrict__ BT,
    const float* __restrict__ bias, unsigned short* __restrict__ Cb, int M)
{
    const int K = 256;
    __shared__ __align__(16) unsigned short As[128][40];
    __shared__ __align__(16) unsigned short Bs[128][40];

    const int tid  = threadIdx.x;
    const int wave = tid >> 6, lane = tid & 63;
    const int wm = wave >> 1, wn = wave & 1;
    const int quad = lane >> 4, l16 = lane & 15;
    const int m0 = blockIdx.y * 128, n0 = blockIdx.x * 128;

    f32x4 acc[4][4] = {};

    for (int k0 = 0; k0 < K; k0 += 32) {
        #pragma unroll
        for (int i = 0; i < 2; ++i) {            // A: 128x32 fp32 -> bf16
            int idx = tid + 256 * i;
            int r = idx >> 2, kc = (idx & 3) * 8;
            int gr = m0 + r;
            float4 f0, f1;
            if (gr < M) {
                f0 = *(const float4*)(A + (size_t)gr * K + k0 + kc);
                f1 = *(const float4*)(A + (size_t)gr * K + k0 + kc + 4);
            } else { f0 = make_float4(0,0,0,0); f1 = f0; }
            uint4 o;
            o.x = f32_to_bf16(f0.x) | ((unsigned)f32_to_bf16(f0.y) << 16);
            o.y = f32_to_bf16(f0.z) | ((unsigned)f32_to_bf16(f0.w) << 16);
            o.z = f32_to_bf16(f1.x) | ((unsigned)f32_to_bf16(f1.y) << 16);
            o.w = f32_to_bf16(f1.z) | ((unsigned)f32_to_bf16(f1.w) << 16);
            *(uint4*)&As[r][kc] = o;
        }
        #pragma unroll
        for (int i = 0; i < 2; ++i) {            // B: 128 rows x 32 k bf16
            int idx = tid + 256 * i;
            int r = idx >> 2, kc = (idx & 3) * 8;
            *(uint4*)&Bs[r][kc] = *(const uint4*)(BT + (size_t)(n0 + r) * K + k0 + kc);
        }
        __syncthreads();
        bf16x8 af[4], bfr[4];
        #pragma unroll
        for (int mi = 0; mi < 4; ++mi)
            af[mi] = *(const bf16x8*)&As[wm * 64 + mi * 16 + l16][quad * 8];
        #pragma unroll
        for (int ni = 0; ni < 4; ++ni)
            bfr[ni] = *(const bf16x8*)&Bs[wn * 64 + ni * 16 + l16][quad * 8];
        #pragma unroll
        for (int mi = 0; mi < 4; ++mi)
            #pragma unroll
            for (int ni = 0; ni < 4; ++ni)
                acc[mi][ni] = __builtin_amdgcn_mfma_f32_16x16x32_bf16(
                    af[mi], bfr[ni], acc[mi][ni], 0, 0, 0);
        __syncthreads();
    }

    #pragma unroll
    for (int mi = 0; mi < 4; ++mi) {
        #pragma unroll
        for (int r = 0; r < 4; ++r) {
            int gm = m0 + wm * 64 + mi * 16 + quad * 4 + r;
            if (gm >= M) continue;
            int cam = gm / LTOT;
            int pix = gm - cam * LTOT;
            #pragma unroll
            for (int ni = 0; ni < 4; ++ni) {
                int gn = n0 + wn * 64 + ni * 16 + l16;
                int head = gn >> 5, ch = gn & 31;
                float v = acc[mi][ni][r] + bias[gn];
                Cb[(((size_t)(cam * 8 + head)) * LTOT + pix) * 32 + ch] = f32_to_bf16(v);
            }
        }
    }
}

// ---------------------------------------------------------------------------
// Fused query projections (A fp32 converted inline): blocks x=0,1 -> qoff;
// x=2 -> softmax(attn) -> qaw. BM=64, combined WqT [384][256].
// ---------------------------------------------------------------------------
__global__ __launch_bounds__(256) void qproj_kernel(
    const float* __restrict__ A, const unsigned short* __restrict__ WqT,
    const float* __restrict__ b_off, const float* __restrict__ b_attn,
    float* __restrict__ qoff, float* __restrict__ qaw)
{
    const int K = 256;
    __shared__ __align__(16) unsigned short As[64][40];
    __shared__ __align__(16) unsigned short Bs[128][40];

    const int tid  = threadIdx.x;
    const int wave = tid >> 6, lane = tid & 63;
    const int wm = wave >> 1, wn = wave & 1;
    const int quad = lane >> 4, l16 = lane & 15;
    const int m0 = blockIdx.y * 64, n0 = blockIdx.x * 128;
    const int is_attn = (n0 == 256);

    f32x4 acc[2][4] = {};

    for (int k0 = 0; k0 < K; k0 += 32) {
        {                                        // A: 64x32 fp32 -> bf16
            int r = tid >> 2, kc = (tid & 3) * 8;
            float4 f0 = *(const float4*)(A + (size_t)(m0 + r) * K + k0 + kc);
            float4 f1 = *(const float4*)(A + (size_t)(m0 + r) * K + k0 + kc + 4);
            uint4 o;
            o.x = f32_to_bf16(f0.x) | ((unsigned)f32_to_bf16(f0.y) << 16);
            o.y = f32_to_bf16(f0.z) | ((unsigned)f32_to_bf16(f0.w) << 16);
            o.z = f32_to_bf16(f1.x) | ((unsigned)f32_to_bf16(f1.y) << 16);
            o.w = f32_to_bf16(f1.z) | ((unsigned)f32_to_bf16(f1.w) << 16);
            *(uint4*)&As[r][kc] = o;
        }
        #pragma unroll
        for (int i = 0; i < 2; ++i) {
            int idx = tid + 256 * i;
            int r = idx >> 2, kc = (idx & 3) * 8;
            *(uint4*)&Bs[r][kc] = *(const uint4*)(WqT + (size_t)(n0 + r) * K + k0 + kc);
        }
        __syncthreads();
        bf16x8 af[2], bfr[4];
        #pragma unroll
        for (int mi = 0; mi < 2; ++mi)
            af[mi] = *(const bf16x8*)&As[wm * 32 + mi * 16 + l16][quad * 8];
        #pragma unroll
        for (int ni = 0; ni < 4; ++ni)
            bfr[ni] = *(const bf16x8*)&Bs[wn * 64 + ni * 16 + l16][quad * 8];
        #pragma unroll
        for (int mi = 0; mi < 2; ++mi)
            #pragma unroll
            for (int ni = 0; ni < 4; ++ni)
                acc[mi][ni] = __builtin_amdgcn_mfma_f32_16x16x32_bf16(
                    af[mi], bfr[ni], acc[mi][ni], 0, 0, 0);
        __syncthreads();
    }

    if (is_attn) {
        #pragma unroll
        for (int mi = 0; mi < 2; ++mi) {
            #pragma unroll
            for (int r = 0; r < 4; ++r) {
                int gm = m0 + wm * 32 + mi * 16 + quad * 4 + r;
                #pragma unroll
                for (int ni = 0; ni < 4; ++ni) {
                    int gn = wn * 64 + ni * 16 + l16;
                    float v = acc[mi][ni][r] + b_attn[gn];
                    float mx = v;
                    #pragma unroll
                    for (int s = 1; s < 16; s <<= 1)
                        mx = fmaxf(mx, __shfl_xor(mx, s, 64));
                    float e = __expf(v - mx);
                    float sum = e;
                    #pragma unroll
                    for (int s = 1; s < 16; s <<= 1)
                        sum += __shfl_xor(sum, s, 64);
                    qaw[(size_t)gm * 128 + gn] = e / sum;
                }
            }
        }
    } else {
        #pragma unroll
        for (int mi = 0; mi < 2; ++mi) {
            #pragma unroll
            for (int r = 0; r < 4; ++r) {
                int gm = m0 + wm * 32 + mi * 16 + quad * 4 + r;
                #pragma unroll
                for (int ni = 0; ni < 4; ++ni) {
                    int gn = n0 + wn * 64 + ni * 16 + l16;
                    qoff[(size_t)gm * 256 + gn] = acc[mi][ni][r] + b_off[gn];
                }
            }
        }
    }
}

// ---------------------------------------------------------------------------
// Head-partitioned deformable sampling, ALL corner tables prebuilt (52 KB
// LDS) -> 1 barrier before a fully barrier-free gather stream.
// refpts for all 6 cams prefetched into registers before table build.
// ---------------------------------------------------------------------------
__global__ __launch_bounds__(256) void sample_kernel(
    const unsigned short* __restrict__ vb, // (6, 8, 7979, 32) bf16
    const float* __restrict__ qoff,        // (6400, 256)
    const float* __restrict__ aw,          // (6400, 128)
    const float* __restrict__ refpts,      // (6, 1, 6400, 4, 2)
    const int*   __restrict__ bev_mask,    // (6, 1, 6400, 4)
    unsigned short* __restrict__ outsum,   // (6400, 256) bf16
    float* __restrict__ visb)              // (6400)
{
    const int bid = blockIdx.x;
    const int h   = bid & 7;
    const int q0  = (bid >> 3) * 16;
    const int tid = threadIdx.x;
    const int sq  = tid >> 4;
    const int tup = tid & 15;
    const int lvl = tup >> 2;
    const int n_s = q0 + sq;
    const int tg  = (tid >> 2) & 3;
    const int cg  = tid & 3;

    __shared__ int2  s_tab[NCAMS][4][272];
    __shared__ float s_vis[NCAMS][16];
    __shared__ int   s_cnt[NCAMS];
    __shared__ int   s_nvis[16];

    if (tid < 96) {
        int cam = tid >> 4, q = tid & 15;
        const int* bm = bev_mask + ((size_t)cam * NQ + q0 + q) * 4;
        s_vis[cam][q] = ((bm[0] + bm[1] + bm[2] + bm[3]) > 0) ? 1.f : 0.f;
    }
    __syncthreads();
    if (tid < NCAMS) {
        float s = 0.f;
        #pragma unroll
        for (int q = 0; q < 16; ++q) s += s_vis[tid][q];
        s_cnt[tid] = (int)s;
    }
    if (tid >= 32 && tid < 48) {
        int q = tid - 32;
        float s = 0.f;
        #pragma unroll
        for (int cam = 0; cam < NCAMS; ++cam) s += s_vis[cam][q];
        s_nvis[q] = (int)s;
    }

    const float my_aw = aw[(size_t)n_s * 128 + h * 16 + tup];
    const float offx  = qoff[(size_t)n_s * 256 + h * 32 + tup * 2];
    const float offy  = qoff[(size_t)n_s * 256 + h * 32 + tup * 2 + 1];
    const int Wl   = (lvl == 0) ? 100 : (lvl == 1) ? 50 : (lvl == 2) ? 25 : 13;
    const int Hl   = (lvl == 0) ? 60  : (lvl == 1) ? 30 : (lvl == 2) ? 15 : 8;
    const int base = (lvl == 0) ? 0   : (lvl == 1) ? 6000 : (lvl == 2) ? 7500 : 7875;
    const float dx = offx / (float)Wl;
    const float dy = offy / (float)Hl;
    const int tabi = sq * 17 + tup;

    // prefetch all 6 cams' refpoints (independent loads, hides latency)
    float2 rp[NCAMS];
    #pragma unroll
    for (int k = 0; k < NCAMS; ++k)
        rp[k] = *(const float2*)(refpts + (((size_t)k * NQ + n_s) * 4 + lvl) * 2);
    __syncthreads();   // covers s_cnt/s_nvis writes

    // build all 6 cam tables (weights fold in per-query visibility)
    #pragma unroll
    for (int k = 0; k < NCAMS; ++k) {
        float fx = (rp[k].x + dx) * (float)Wl - 0.5f;
        float fy = (rp[k].y + dy) * (float)Hl - 0.5f;
        float x0f = floorf(fx), y0f = floorf(fy);
        float lx = fx - x0f, ly = fy - y0f;
        int x0 = (int)x0f, y0 = (int)y0f;
        int x1 = x0 + 1, y1 = y0 + 1;
        float wb = my_aw * s_vis[k][sq];
        float w00 = (1.f - lx) * (1.f - ly) * wb;
        float w01 = lx * (1.f - ly) * wb;
        float w10 = (1.f - lx) * ly * wb;
        float w11 = lx * ly * wb;
        bool vx0 = (x0 >= 0) & (x0 < Wl), vx1 = (x1 >= 0) & (x1 < Wl);
        bool vy0 = (y0 >= 0) & (y0 < Hl), vy1 = (y1 >= 0) & (y1 < Hl);
        s_tab[k][0][tabi] = make_int2((vx0 & vy0) ? (base + y0 * Wl + x0) * 64 : 0,
                                      __float_as_int((vx0 & vy0) ? w00 : 0.f));
        s_tab[k][1][tabi] = make_int2((vx1 & vy0) ? (base + y0 * Wl + x1) * 64 : 0,
                                      __float_as_int((vx1 & vy0) ? w01 : 0.f));
        s_tab[k][2][tabi] = make_int2((vx0 & vy1) ? (base + y1 * Wl + x0) * 64 : 0,
                                      __float_as_int((vx0 & vy1) ? w10 : 0.f));
        s_tab[k][3][tabi] = make_int2((vx1 & vy1) ? (base + y1 * Wl + x1) * 64 : 0,
                                      __float_as_int((vx1 & vy1) ? w11 : 0.f));
    }
    __syncthreads();

    float a0 = 0.f, a1 = 0.f, a2 = 0.f, a3 = 0.f;
    float a4 = 0.f, a5 = 0.f, a6 = 0.f, a7 = 0.f;

    for (int k = 0; k < NCAMS; ++k) {
        if (s_cnt[k] == 0) continue;
        const char* vkh = (const char*)vb + (size_t)(k * 8 + h) * (LTOT * 64) + cg * 16;
        #pragma unroll
        for (int j = 0; j < 4; ++j) {
            int ti = sq * 17 + tg * 4 + j;
            #pragma unroll
            for (int corner = 0; corner < 4; ++corner) {
                int2 t = s_tab[k][corner][ti];
                float w = __int_as_float(t.y);
                uint4 d = *(const uint4*)(vkh + t.x);
                a0 += w * __uint_as_float(d.x << 16);
                a1 += w * __uint_as_float(d.x & 0xFFFF0000u);
                a2 += w * __uint_as_float(d.y << 16);
                a3 += w * __uint_as_float(d.y & 0xFFFF0000u);
                a4 += w * __uint_as_float(d.z << 16);
                a5 += w * __uint_as_float(d.z & 0xFFFF0000u);
                a6 += w * __uint_as_float(d.w << 16);
                a7 += w * __uint_as_float(d.w & 0xFFFF0000u);
            }
        }
    }

    a0 += __shfl_xor(a0, 4, 64); a0 += __shfl_xor(a0, 8, 64);
    a1 += __shfl_xor(a1, 4, 64); a1 += __shfl_xor(a1, 8, 64);
    a2 += __shfl_xor(a2, 4, 64); a2 += __shfl_xor(a2, 8, 64);
    a3 += __shfl_xor(a3, 4, 64); a3 += __shfl_xor(a3, 8, 64);
    a4 += __shfl_xor(a4, 4, 64); a4 += __shfl_xor(a4, 8, 64);
    a5 += __shfl_xor(a5, 4, 64); a5 += __shfl_xor(a5, 8, 64);
    a6 += __shfl_xor(a6, 4, 64); a6 += __shfl_xor(a6, 8, 64);
    a7 += __shfl_xor(a7, 4, 64); a7 += __shfl_xor(a7, 8, 64);

    if ((tid & 12) == 0) {
        int nv = s_nvis[sq];
        float sc = 1.f / (float)(nv > 0 ? nv : 1);
        uint4 o;
        o.x = f32_to_bf16(a0 * sc) | ((unsigned)f32_to_bf16(a1 * sc) << 16);
        o.y = f32_to_bf16(a2 * sc) | ((unsigned)f32_to_bf16(a3 * sc) << 16);
        o.z = f32_to_bf16(a4 * sc) | ((unsigned)f32_to_bf16(a5 * sc) << 16);
        o.w = f32_to_bf16(a6 * sc) | ((unsigned)f32_to_bf16(a7 * sc) << 16);
        *(uint4*)(outsum + (size_t)n_s * 256 + h * 32 + cg * 8) = o;
    }
    if (h == 0 && tid < 16) visb[q0 + tid] = (s_nvis[tid] > 0) ? 1.f : 0.f;
}

// ---------------------------------------------------------------------------
// Fused output-projection + residual + LN1. BM=32, BN=256, K=256.
// A=outsum bf16, BT=WoT. Writes xbuf (fp32) + xbf (bf16).
// ---------------------------------------------------------------------------
__global__ __launch_bounds__(256) void projln1_kernel(
    const unsigned short* __restrict__ A, const unsigned short* __restrict__ BT,
    const float* __restrict__ query, const float* __restrict__ visb,
    const float* __restrict__ b_out, const float* __restrict__ g,
    const float* __restrict__ b,
    float* __restrict__ xout, unsigned short* __restrict__ xbf)
{
    const int K = 256;
    __shared__ __align__(16) unsigned short As[32][40];
    __shared__ __align__(16) unsigned short Bs[256][40];
    __shared__ float sred[2][4][4][2];
    __shared__ float ssred[2][4][4][2];
    __shared__ float s_mu[32], s_rs[32];

    const int tid  = threadIdx.x;
    const int wave = tid >> 6, lane = tid & 63;
    const int wm = wave >> 1, wn = wave & 1;
    const int quad = lane >> 4, l16 = lane & 15;
    const int m0 = blockIdx.x * 32;

    f32x4 acc[8] = {};

    for (int k0 = 0; k0 < K; k0 += 32) {
        {
            int r = tid >> 3, kc = (tid & 7) * 4;
            *(uint2*)&As[r][kc] = *(const uint2*)(A + (size_t)(m0 + r) * K + k0 + kc);
        }
        {
            const unsigned short* src = BT + (size_t)tid * K + k0;
            *(uint4*)&Bs[tid][0]  = *(const uint4*)(src);
            *(uint4*)&Bs[tid][8]  = *(const uint4*)(src + 8);
            *(uint4*)&Bs[tid][16] = *(const uint4*)(src + 16);
            *(uint4*)&Bs[tid][24] = *(const uint4*)(src + 24);
        }
        __syncthreads();
        bf16x8 af = *(const bf16x8*)&As[wm * 16 + l16][quad * 8];
        #pragma unroll
        for (int ni = 0; ni < 8; ++ni) {
            bf16x8 bfr = *(const bf16x8*)&Bs[wn * 128 + ni * 16 + l16][quad * 8];
            acc[ni] = __builtin_amdgcn_mfma_f32_16x16x32_bf16(af, bfr, acc[ni], 0, 0, 0);
        }
        __syncthreads();
    }

    float vals[8][4];
    #pragma unroll
    for (int r = 0; r < 4; ++r) {
        int gm = m0 + wm * 16 + quad * 4 + r;
        float vs = visb[gm];
        float s = 0.f, ss = 0.f;
        #pragma unroll
        for (int ni = 0; ni < 8; ++ni) {
            int gn = wn * 128 + ni * 16 + l16;
            float v = acc[ni][r] + vs * b_out[gn]
                    + query[(size_t)gm * 256 + gn] * (1.f + vs);
            vals[ni][r] = v;
            s += v; ss += v * v;
        }
        #pragma unroll
        for (int m = 1; m < 16; m <<= 1) {
            s  += __shfl_xor(s,  m, 64);
            ss += __shfl_xor(ss, m, 64);
        }
        if (l16 == 0) {
            sred[wm][quad][r][wn]  = s;
            ssred[wm][quad][r][wn] = ss;
        }
    }
    __syncthreads();
    if (tid < 32) {
        int lwm = tid >> 4, lq = (tid >> 2) & 3, lr = tid & 3;
        float s  = sred[lwm][lq][lr][0]  + sred[lwm][lq][lr][1];
        float ss = ssred[lwm][lq][lr][0] + ssred[lwm][lq][lr][1];
        float mu = s * (1.f / 256.f);
        float var = ss * (1.f / 256.f) - mu * mu;
        s_mu[tid] = mu;
        s_rs[tid] = rsqrtf(var + 1e-5f);
    }
    __syncthreads();

    #pragma unroll
    for (int r = 0; r < 4; ++r) {
        int rowl = wm * 16 + quad * 4 + r;
        int gm = m0 + rowl;
        float mu = s_mu[rowl], rs = s_rs[rowl];
        #pragma unroll
        for (int ni = 0; ni < 8; ++ni) {
            int gn = wn * 128 + ni * 16 + l16;
            float res = (vals[ni][r] - mu) * rs * g[gn] + b[gn];
            xout[(size_t)gm * 256 + gn] = res;
            xbf[(size_t)gm * 256 + gn] = f32_to_bf16(res);
        }
    }
}

// ---------------------------------------------------------------------------
// FFN layer 1: hbf = bf16(relu(xbf @ W1 + b1)). BM=BN=128, K=256, bf16 in.
// ---------------------------------------------------------------------------
__global__ __launch_bounds__(256) void gemm_ffn1_kernel(
    const unsigned short* __restrict__ A, const unsigned short* __restrict__ BT,
    const float* __restrict__ bias, unsigned short* __restrict__ Cb)
{
    const int K = 256, N = DFFN;
    __shared__ __align__(16) unsigned short As[128][40];
    __shared__ __align__(16) unsigned short Bs[128][40];

    const int tid  = threadIdx.x;
    const int wave = tid >> 6, lane = tid & 63;
    const int wm = wave >> 1, wn = wave & 1;
    const int quad = lane >> 4, l16 = lane & 15;
    const int m0 = blockIdx.y * 128, n0 = blockIdx.x * 128;

    f32x4 acc[4][4] = {};

    for (int k0 = 0; k0 < K; k0 += 32) {
        #pragma unroll
        for (int i = 0; i < 2; ++i) {
            int idx = tid + 256 * i;
            int r = idx >> 2, kc = (idx & 3) * 8;
            *(uint4*)&As[r][kc] = *(const uint4*)(A + (size_t)(m0 + r) * K + k0 + kc);
        }
        #pragma unroll
        for (int i = 0; i < 2; ++i) {
            int idx = tid + 256 * i;
            int r = idx >> 2, kc = (idx & 3) * 8;
            *(uint4*)&Bs[r][kc] = *(const uint4*)(BT + (size_t)(n0 + r) * K + k0 + kc);
        }
        __syncthreads();
        bf16x8 af[4], bfr[4];
        #pragma unroll
        for (int mi = 0; mi < 4; ++mi)
            af[mi] = *(const bf16x8*)&As[wm * 64 + mi * 16 + l16][quad * 8];
        #pragma unroll
        for (int ni = 0; ni < 4; ++ni)
            bfr[ni] = *(const bf16x8*)&Bs[wn * 64 + ni * 16 + l16][quad * 8];
        #pragma unroll
        for (int mi = 0; mi < 4; ++mi)
            #pragma unroll
            for (int ni = 0; ni < 4; ++ni)
                acc[mi][ni] = __builtin_amdgcn_mfma_f32_16x16x32_bf16(
                    af[mi], bfr[ni], acc[mi][ni], 0, 0, 0);
        __syncthreads();
    }

    #pragma unroll
    for (int mi = 0; mi < 4; ++mi) {
        #pragma unroll
        for (int r = 0; r < 4; ++r) {
            int gm = m0 + wm * 64 + mi * 16 + quad * 4 + r;
            #pragma unroll
            for (int ni = 0; ni < 4; ++ni) {
                int gn = n0 + wn * 64 + ni * 16 + l16;
                float v = acc[mi][ni][r] + bias[gn];
                Cb[(size_t)gm * N + gn] = f32_to_bf16(fmaxf(v, 0.f));
            }
        }
    }
}

// ---------------------------------------------------------------------------
// Fused FFN layer 2 + residual + LN2 -> final output.
// BM=32, BN=256, K=1024. A=hbf bf16, BT=W2T [256][1024].
// out = LN( xbuf + hbf@W2 + b2 ).
// ---------------------------------------------------------------------------
__global__ __launch_bounds__(256) void projln2_kernel(
    const unsigned short* __restrict__ A, const unsigned short* __restrict__ BT,
    const float* __restrict__ xres, const float* __restrict__ bias,
    const float* __restrict__ g, const float* __restrict__ b,
    float* __restrict__ out)
{
    const int K = DFFN;
    __shared__ __align__(16) unsigned short As[32][40];
    __shared__ __align__(16) unsigned short Bs[256][40];
    __shared__ float sred[2][4][4][2];
    __shared__ float ssred[2][4][4][2];
    __shared__ float s_mu[32], s_rs[32];

    const int tid  = threadIdx.x;
    const int wave = tid >> 6, lane = tid & 63;
    const int wm = wave >> 1, wn = wave & 1;
    const int quad = lane >> 4, l16 = lane & 15;
    const int m0 = blockIdx.x * 32;

    f32x4 acc[8] = {};

    for (int k0 = 0; k0 < K; k0 += 32) {
        {
            int r = tid >> 3, kc = (tid & 7) * 4;
            *(uint2*)&As[r][kc] = *(const uint2*)(A + (size_t)(m0 + r) * K + k0 + kc);
        }
        {
            const unsigned short* src = BT + (size_t)tid * K + k0;
            *(uint4*)&Bs[tid][0]  = *(const uint4*)(src);
            *(uint4*)&Bs[tid][8]  = *(const uint4*)(src + 8);
            *(uint4*)&Bs[tid][16] = *(const uint4*)(src + 16);
            *(uint4*)&Bs[tid][24] = *(const uint4*)(src + 24);
        }
        __syncthreads();
        bf16x8 af = *(const bf16x8*)&As[wm * 16 + l16][quad * 8];
        #pragma unroll
        for (int ni = 0; ni < 8; ++ni) {
            bf16x8 bfr = *(const bf16x8*)&Bs[wn * 128 + ni * 16 + l16][quad * 8];
            acc[ni] = __builtin_amdgcn_mfma_f32_16x16x32_bf16(af, bfr, acc[ni], 0, 0, 0);
        }
        __syncthreads();
    }

    float vals[8][4];
    #pragma unroll
    for (int r = 0; r < 4; ++r) {
        int gm = m0 + wm * 16 + quad * 4 + r;
        float s = 0.f, ss = 0.f;
        #pragma unroll
        for (int ni = 0; ni < 8; ++ni) {
            int gn = wn * 128 + ni * 16 + l16;
            float v = acc[ni][r] + bias[gn] + xres[(size_t)gm * 256 + gn];
            vals[ni][r] = v;
            s += v; ss += v * v;
        }
        #pragma unroll
        for (int m = 1; m < 16; m <<= 1) {
            s  += __shfl_xor(s,  m, 64);
            ss += __shfl_xor(ss, m, 64);
        }
        if (l16 == 0) {
            sred[wm][quad][r][wn]  = s;
            ssred[wm][quad][r][wn] = ss;
        }
    }
    __syncthreads();
    if (tid < 32) {
        int lwm = tid >> 4, lq = (tid >> 2) & 3, lr = tid & 3;
        float s  = sred[lwm][lq][lr][0]  + sred[lwm][lq][lr][1];
        float ss = ssred[lwm][lq][lr][0] + ssred[lwm][lq][lr][1];
        float mu = s * (1.f / 256.f);
        float var = ss * (1.f / 256.f) - mu * mu;
        s_mu[tid] = mu;
        s_rs[tid] = rsqrtf(var + 1e-5f);
    }
    __syncthreads();

    #pragma unroll
    for (int r = 0; r < 4; ++r) {
        int rowl = wm * 16 + quad * 4 + r;
        int gm = m0 + rowl;
        float mu = s_mu[rowl], rs = s_rs[rowl];
        #pragma unroll
        for (int ni = 0; ni < 8; ++ni) {
            int gn = wn * 128 + ni * 16 + l16;
            out[(size_t)gm * 256 + gn] = (vals[ni][r] - mu) * rs * g[gn] + b[gn];
        }
    }
}

// ---------------------------------------------------------------------------
extern "C" void kernel_launch(void* const* d_in, const int* in_sizes, int n_in,
                              void* d_out, int out_size, void* d_ws, size_t ws_size,
                              hipStream_t stream)
{
    const float* query   = (const float*)d_in[0];
    const float* value   = (const float*)d_in[2];
    const float* refpts  = (const float*)d_in[3];
    const int*   bevmask = (const int*)d_in[6];
    const float* W_value = (const float*)d_in[7];
    const float* b_value = (const float*)d_in[8];
    const float* W_off   = (const float*)d_in[9];
    const float* b_off   = (const float*)d_in[10];
    const float* W_attn  = (const float*)d_in[11];
    const float* b_attn  = (const float*)d_in[12];
    const float* W_out   = (const float*)d_in[13];
    const float* b_out   = (const float*)d_in[14];
    const float* ln1_g   = (const float*)d_in[15];
    const float* ln1_b   = (const float*)d_in[16];
    const float* W1      = (const float*)d_in[17];
    const float* b1      = (const float*)d_in[18];
    const float* W2      = (const float*)d_in[19];
    const float* b2      = (const float*)d_in[20];
    const float* ln2_g   = (const float*)d_in[21];
    const float* ln2_b   = (const float*)d_in[22];
    float* out = (float*)d_out;

    // workspace layout (byte offsets, temporal aliasing):
    //  [0)          vb bf16 24,511,488      (gemm_v -> sample)
    //  [0)          xbuf fp32 6,553,600     (projln1 -> projln2)  [vb dead]
    //  [7,000,000)  xbf bf16 3,276,800      (projln1 -> ffn1)     [vb dead]
    //  [11,000,000) hbf bf16 13,107,200     (ffn1 -> projln2)     [vb dead]
    //  [25,000,000) qoff fp32 6,553,600     (qproj -> sample)
    //  [32,000,000) qaw fp32 3,276,800      (qproj -> sample)
    //  [35,300,000) outsum bf16 3,276,800   (sample -> projln1)
    //  [38,600,000) visb 25,600             (sample -> projln1)
    //  [38,700,000) wsT bf16 1,507,328      (wt -> all GEMMs)
    char* ws = (char*)d_ws;
    unsigned short* vb     = (unsigned short*)(ws + 0);
    float*          xbuf   = (float*)(ws + 0);
    unsigned short* xbf    = (unsigned short*)(ws + 7000000);
    unsigned short* hbf    = (unsigned short*)(ws + 11000000);
    float*          qoff   = (float*)(ws + 25000000);
    float*          qaw    = (float*)(ws + 32000000);
    unsigned short* outsum = (unsigned short*)(ws + 35300000);
    float*          visb   = (float*)(ws + 38600000);
    unsigned short* wsT    = (unsigned short*)(ws + 38700000);

    unsigned short* WvT = wsT;            // [256][256]
    unsigned short* WqT = wsT + 65536;    // [384][256]
    unsigned short* WoT = wsT + 163840;   // [256][256]
    unsigned short* W1T = wsT + 229376;   // [1024][256]
    unsigned short* W2T = wsT + 491520;   // [256][1024]

    const int MV = NCAMS * LTOT;  // 47874

    // P0: weight transpose+convert
    wt_kernel<<<dim3(736), 256, 0, stream>>>(
        W_value, W_off, W_attn, W_out, W1, W2, wsT);
    // K1: v = value @ W_value + b_value -> bf16 head-major (inline cvt)
    gemm_v_kernel<<<dim3(2, (MV + 127) / 128), 256, 0, stream>>>(
        value, WvT, b_value, vb, MV);
    // K2: fused qoff + attn-softmax projections (inline cvt)
    qproj_kernel<<<dim3(3, 100), 256, 0, stream>>>(
        query, WqT, b_off, b_attn, qoff, qaw);
    // K3: head-partitioned sampling (all tables prebuilt, barrier-free gather)
    sample_kernel<<<dim3(3200), 256, 0, stream>>>(
        vb, qoff, qaw, refpts, bevmask, outsum, visb);
    // K4+LN1 fused: x = LN(outsum@W_out + residual algebra)
    projln1_kernel<<<dim3(200), 256, 0, stream>>>(
        outsum, WoT, query, visb, b_out, ln1_g, ln1_b, xbuf, xbf);
    // K5: hbf = bf16(relu(x @ W1 + b1)), 128x128 tiles
    gemm_ffn1_kernel<<<dim3(8, 50), 256, 0, stream>>>(
        xbf, W1T, b1, hbf);
    // K6+LN2 fused: out = LN(x + h@W2 + b2)
    projln2_kernel<<<dim3(200), 256, 0, stream>>>(
        hbf, W2T, xbuf, b2, ln2_g, ln2_b, out);
}

// Round 8
// 326.632 us; speedup vs baseline: 1.0128x; 1.0128x over previous
//
#include <hip/hip_runtime.h>
#include <math.h>

#define NQ      6400
#define NCAMS   6
#define LTOT    7979
#define DM      256
#define DFFN    1024

typedef __attribute__((ext_vector_type(8))) short bf16x8;
typedef __attribute__((ext_vector_type(4))) float f32x4;

__device__ inline unsigned short f32_to_bf16(float f) {
    unsigned u = __float_as_uint(f);
    unsigned r = u + 0x7FFF + ((u >> 16) & 1);   // round-to-nearest-even
    return (unsigned short)(r >> 16);
}

// ---------------------------------------------------------------------------
// head_kernel: one launch covering three independent jobs via block ranges.
//  b <  750 : value projection (BM=BN=128, K=256, fp32 A+B converted inline)
//             -> vb bf16 head-major (cam, head, pixel, 32ch)
//  b < 1050 : query projections (BM=64): x=0,1 -> qoff; x=2 -> softmax -> qaw
//  else     : weight transpose+convert for WoT/W1T/W2T (used post-sample)
// No intra-launch dependencies: gemm parts convert their weights themselves.
// ---------------------------------------------------------------------------
__global__ __launch_bounds__(256) void head_kernel(
    const float* __restrict__ value, const float* __restrict__ query,
    const float* __restrict__ Wv, const float* __restrict__ bv,
    const float* __restrict__ Woff, const float* __restrict__ boff,
    const float* __restrict__ Wattn, const float* __restrict__ battn,
    const float* __restrict__ Wout, const float* __restrict__ W1,
    const float* __restrict__ W2,
    unsigned short* __restrict__ vb, float* __restrict__ qoff,
    float* __restrict__ qaw, unsigned short* __restrict__ wsT)
{
    __shared__ __align__(16) unsigned char smem[20480];
    const int b = blockIdx.x;
    const int tid = threadIdx.x;

    if (b < 750) {
        // ---------------- value projection ----------------
        unsigned short (*As)[40] = (unsigned short(*)[40])smem;           // 128 rows
        unsigned short (*Bs)[40] = (unsigned short(*)[40])(smem + 10240); // 128 rows
        const int wave = tid >> 6, lane = tid & 63;
        const int wm = wave >> 1, wn = wave & 1;
        const int quad = lane >> 4, l16 = lane & 15;
        const int m0 = (b >> 1) * 128, n0 = (b & 1) * 128;
        const int M = NCAMS * LTOT;

        f32x4 acc[4][4] = {};

        for (int k0 = 0; k0 < 256; k0 += 32) {
            #pragma unroll
            for (int i = 0; i < 2; ++i) {          // A: 128x32 fp32 -> bf16
                int idx = tid + 256 * i;
                int r = idx >> 2, kc = (idx & 3) * 8;
                int gr = m0 + r;
                float4 f0, f1;
                if (gr < M) {
                    f0 = *(const float4*)(value + (size_t)gr * 256 + k0 + kc);
                    f1 = *(const float4*)(value + (size_t)gr * 256 + k0 + kc + 4);
                } else { f0 = make_float4(0.f,0.f,0.f,0.f); f1 = f0; }
                uint4 o;
                o.x = f32_to_bf16(f0.x) | ((unsigned)f32_to_bf16(f0.y) << 16);
                o.y = f32_to_bf16(f0.z) | ((unsigned)f32_to_bf16(f0.w) << 16);
                o.z = f32_to_bf16(f1.x) | ((unsigned)f32_to_bf16(f1.y) << 16);
                o.w = f32_to_bf16(f1.z) | ((unsigned)f32_to_bf16(f1.w) << 16);
                *(uint4*)&As[r][kc] = o;
            }
            #pragma unroll
            for (int i = 0; i < 4; ++i) {          // B: W_value fp32 [k][n] -> Bs[n][k]
                int idx = tid + 256 * i;
                int kr = idx >> 5, c = (idx & 31) * 4;
                float4 f = *(const float4*)(Wv + (size_t)(k0 + kr) * 256 + n0 + c);
                Bs[c    ][kr] = f32_to_bf16(f.x);
                Bs[c + 1][kr] = f32_to_bf16(f.y);
                Bs[c + 2][kr] = f32_to_bf16(f.z);
                Bs[c + 3][kr] = f32_to_bf16(f.w);
            }
            __syncthreads();
            bf16x8 af[4], bfr[4];
            #pragma unroll
            for (int mi = 0; mi < 4; ++mi)
                af[mi] = *(const bf16x8*)&As[wm * 64 + mi * 16 + l16][quad * 8];
            #pragma unroll
            for (int ni = 0; ni < 4; ++ni)
                bfr[ni] = *(const bf16x8*)&Bs[wn * 64 + ni * 16 + l16][quad * 8];
            #pragma unroll
            for (int mi = 0; mi < 4; ++mi)
                #pragma unroll
                for (int ni = 0; ni < 4; ++ni)
                    acc[mi][ni] = __builtin_amdgcn_mfma_f32_16x16x32_bf16(
                        af[mi], bfr[ni], acc[mi][ni], 0, 0, 0);
            __syncthreads();
        }

        #pragma unroll
        for (int mi = 0; mi < 4; ++mi) {
            #pragma unroll
            for (int r = 0; r < 4; ++r) {
                int gm = m0 + wm * 64 + mi * 16 + quad * 4 + r;
                if (gm >= M) continue;
                int cam = gm / LTOT;
                int pix = gm - cam * LTOT;
                #pragma unroll
                for (int ni = 0; ni < 4; ++ni) {
                    int gn = n0 + wn * 64 + ni * 16 + l16;
                    int head = gn >> 5, ch = gn & 31;
                    float v = acc[mi][ni][r] + bv[gn];
                    vb[(((size_t)(cam * 8 + head)) * LTOT + pix) * 32 + ch] = f32_to_bf16(v);
                }
            }
        }
    } else if (b < 1050) {
        // ---------------- query projections ----------------
        unsigned short (*As)[40] = (unsigned short(*)[40])smem;          // 64 rows
        unsigned short (*Bs)[40] = (unsigned short(*)[40])(smem + 5120); // 128 rows
        const int t = b - 750;
        const int bx = t / 100, by = t % 100;
        const int wave = tid >> 6, lane = tid & 63;
        const int wm = wave >> 1, wn = wave & 1;
        const int quad = lane >> 4, l16 = lane & 15;
        const int m0 = by * 64;
        const int is_attn = (bx == 2);
        const float* Wsrc  = is_attn ? Wattn : Woff;
        const int   stride = is_attn ? 128 : 256;
        const int   nbase  = is_attn ? 0 : bx * 128;

        f32x4 acc[2][4] = {};

        for (int k0 = 0; k0 < 256; k0 += 32) {
            {                                       // A: 64x32 fp32 -> bf16
                int r = tid >> 2, kc = (tid & 3) * 8;
                float4 f0 = *(const float4*)(query + (size_t)(m0 + r) * 256 + k0 + kc);
                float4 f1 = *(const float4*)(query + (size_t)(m0 + r) * 256 + k0 + kc + 4);
                uint4 o;
                o.x = f32_to_bf16(f0.x) | ((unsigned)f32_to_bf16(f0.y) << 16);
                o.y = f32_to_bf16(f0.z) | ((unsigned)f32_to_bf16(f0.w) << 16);
                o.z = f32_to_bf16(f1.x) | ((unsigned)f32_to_bf16(f1.y) << 16);
                o.w = f32_to_bf16(f1.z) | ((unsigned)f32_to_bf16(f1.w) << 16);
                *(uint4*)&As[r][kc] = o;
            }
            #pragma unroll
            for (int i = 0; i < 4; ++i) {           // B: W fp32 [k][n] -> Bs[n][k]
                int idx = tid + 256 * i;
                int kr = idx >> 5, c = (idx & 31) * 4;
                float4 f = *(const float4*)(Wsrc + (size_t)(k0 + kr) * stride + nbase + c);
                Bs[c    ][kr] = f32_to_bf16(f.x);
                Bs[c + 1][kr] = f32_to_bf16(f.y);
                Bs[c + 2][kr] = f32_to_bf16(f.z);
                Bs[c + 3][kr] = f32_to_bf16(f.w);
            }
            __syncthreads();
            bf16x8 af[2], bfr[4];
            #pragma unroll
            for (int mi = 0; mi < 2; ++mi)
                af[mi] = *(const bf16x8*)&As[wm * 32 + mi * 16 + l16][quad * 8];
            #pragma unroll
            for (int ni = 0; ni < 4; ++ni)
                bfr[ni] = *(const bf16x8*)&Bs[wn * 64 + ni * 16 + l16][quad * 8];
            #pragma unroll
            for (int mi = 0; mi < 2; ++mi)
                #pragma unroll
                for (int ni = 0; ni < 4; ++ni)
                    acc[mi][ni] = __builtin_amdgcn_mfma_f32_16x16x32_bf16(
                        af[mi], bfr[ni], acc[mi][ni], 0, 0, 0);
            __syncthreads();
        }

        if (is_attn) {
            #pragma unroll
            for (int mi = 0; mi < 2; ++mi) {
                #pragma unroll
                for (int r = 0; r < 4; ++r) {
                    int gm = m0 + wm * 32 + mi * 16 + quad * 4 + r;
                    #pragma unroll
                    for (int ni = 0; ni < 4; ++ni) {
                        int gn = wn * 64 + ni * 16 + l16;
                        float v = acc[mi][ni][r] + battn[gn];
                        float mx = v;
                        #pragma unroll
                        for (int s = 1; s < 16; s <<= 1)
                            mx = fmaxf(mx, __shfl_xor(mx, s, 64));
                        float e = __expf(v - mx);
                        float sum = e;
                        #pragma unroll
                        for (int s = 1; s < 16; s <<= 1)
                            sum += __shfl_xor(sum, s, 64);
                        qaw[(size_t)gm * 128 + gn] = e / sum;
                    }
                }
            }
        } else {
            #pragma unroll
            for (int mi = 0; mi < 2; ++mi) {
                #pragma unroll
                for (int r = 0; r < 4; ++r) {
                    int gm = m0 + wm * 32 + mi * 16 + quad * 4 + r;
                    #pragma unroll
                    for (int ni = 0; ni < 4; ++ni) {
                        int gn = nbase + wn * 64 + ni * 16 + l16;
                        qoff[(size_t)gm * 256 + gn] = acc[mi][ni][r] + boff[gn];
                    }
                }
            }
        }
    } else {
        // ---------------- weight transpose (WoT, W1T, W2T) ----------------
        float (*tile)[33] = (float(*)[33])smem;
        int t = b - 1050;
        const float* src; int K, N, dstoff;
        if (t < 64)       { src = Wout; K = 256;  N = 256;  dstoff = 0; }
        else if (t < 320) { src = W1;   K = 256;  N = 1024; dstoff = 65536;  t -= 64; }
        else              { src = W2;   K = 1024; N = 256;  dstoff = 327680; t -= 320; }
        int ntn = N >> 5;
        int kt = t / ntn, nt = t - kt * ntn;
        int tx = tid & 31, ty = tid >> 5;
        #pragma unroll
        for (int i = 0; i < 4; ++i)
            tile[ty + i * 8][tx] = src[(size_t)(kt * 32 + ty + i * 8) * N + nt * 32 + tx];
        __syncthreads();
        #pragma unroll
        for (int i = 0; i < 4; ++i) {
            int nn = nt * 32 + ty + i * 8;
            wsT[dstoff + (size_t)nn * K + kt * 32 + tx] = f32_to_bf16(tile[tx][ty + i * 8]);
        }
    }
}

// ---------------------------------------------------------------------------
// Head-partitioned deformable sampling, all 6 cam corner tables prebuilt
// (52 KB LDS) -> barrier-free gather stream. (Unchanged from R7: 70 us.)
// ---------------------------------------------------------------------------
__global__ __launch_bounds__(256) void sample_kernel(
    const unsigned short* __restrict__ vb, // (6, 8, 7979, 32) bf16
    const float* __restrict__ qoff,        // (6400, 256)
    const float* __restrict__ aw,          // (6400, 128)
    const float* __restrict__ refpts,      // (6, 1, 6400, 4, 2)
    const int*   __restrict__ bev_mask,    // (6, 1, 6400, 4)
    unsigned short* __restrict__ outsum,   // (6400, 256) bf16
    float* __restrict__ visb)              // (6400)
{
    const int bid = blockIdx.x;
    const int h   = bid & 7;
    const int q0  = (bid >> 3) * 16;
    const int tid = threadIdx.x;
    const int sq  = tid >> 4;
    const int tup = tid & 15;
    const int lvl = tup >> 2;
    const int n_s = q0 + sq;
    const int tg  = (tid >> 2) & 3;
    const int cg  = tid & 3;

    __shared__ int2  s_tab[NCAMS][4][272];
    __shared__ float s_vis[NCAMS][16];
    __shared__ int   s_cnt[NCAMS];
    __shared__ int   s_nvis[16];

    if (tid < 96) {
        int cam = tid >> 4, q = tid & 15;
        const int* bm = bev_mask + ((size_t)cam * NQ + q0 + q) * 4;
        s_vis[cam][q] = ((bm[0] + bm[1] + bm[2] + bm[3]) > 0) ? 1.f : 0.f;
    }
    __syncthreads();
    if (tid < NCAMS) {
        float s = 0.f;
        #pragma unroll
        for (int q = 0; q < 16; ++q) s += s_vis[tid][q];
        s_cnt[tid] = (int)s;
    }
    if (tid >= 32 && tid < 48) {
        int q = tid - 32;
        float s = 0.f;
        #pragma unroll
        for (int cam = 0; cam < NCAMS; ++cam) s += s_vis[cam][q];
        s_nvis[q] = (int)s;
    }

    const float my_aw = aw[(size_t)n_s * 128 + h * 16 + tup];
    const float offx  = qoff[(size_t)n_s * 256 + h * 32 + tup * 2];
    const float offy  = qoff[(size_t)n_s * 256 + h * 32 + tup * 2 + 1];
    const int Wl   = (lvl == 0) ? 100 : (lvl == 1) ? 50 : (lvl == 2) ? 25 : 13;
    const int Hl   = (lvl == 0) ? 60  : (lvl == 1) ? 30 : (lvl == 2) ? 15 : 8;
    const int base = (lvl == 0) ? 0   : (lvl == 1) ? 6000 : (lvl == 2) ? 7500 : 7875;
    const float dx = offx / (float)Wl;
    const float dy = offy / (float)Hl;
    const int tabi = sq * 17 + tup;

    float2 rp[NCAMS];
    #pragma unroll
    for (int k = 0; k < NCAMS; ++k)
        rp[k] = *(const float2*)(refpts + (((size_t)k * NQ + n_s) * 4 + lvl) * 2);
    __syncthreads();

    #pragma unroll
    for (int k = 0; k < NCAMS; ++k) {
        float fx = (rp[k].x + dx) * (float)Wl - 0.5f;
        float fy = (rp[k].y + dy) * (float)Hl - 0.5f;
        float x0f = floorf(fx), y0f = floorf(fy);
        float lx = fx - x0f, ly = fy - y0f;
        int x0 = (int)x0f, y0 = (int)y0f;
        int x1 = x0 + 1, y1 = y0 + 1;
        float wb = my_aw * s_vis[k][sq];
        float w00 = (1.f - lx) * (1.f - ly) * wb;
        float w01 = lx * (1.f - ly) * wb;
        float w10 = (1.f - lx) * ly * wb;
        float w11 = lx * ly * wb;
        bool vx0 = (x0 >= 0) & (x0 < Wl), vx1 = (x1 >= 0) & (x1 < Wl);
        bool vy0 = (y0 >= 0) & (y0 < Hl), vy1 = (y1 >= 0) & (y1 < Hl);
        s_tab[k][0][tabi] = make_int2((vx0 & vy0) ? (base + y0 * Wl + x0) * 64 : 0,
                                      __float_as_int((vx0 & vy0) ? w00 : 0.f));
        s_tab[k][1][tabi] = make_int2((vx1 & vy0) ? (base + y0 * Wl + x1) * 64 : 0,
                                      __float_as_int((vx1 & vy0) ? w01 : 0.f));
        s_tab[k][2][tabi] = make_int2((vx0 & vy1) ? (base + y1 * Wl + x0) * 64 : 0,
                                      __float_as_int((vx0 & vy1) ? w10 : 0.f));
        s_tab[k][3][tabi] = make_int2((vx1 & vy1) ? (base + y1 * Wl + x1) * 64 : 0,
                                      __float_as_int((vx1 & vy1) ? w11 : 0.f));
    }
    __syncthreads();

    float a0 = 0.f, a1 = 0.f, a2 = 0.f, a3 = 0.f;
    float a4 = 0.f, a5 = 0.f, a6 = 0.f, a7 = 0.f;

    for (int k = 0; k < NCAMS; ++k) {
        if (s_cnt[k] == 0) continue;
        const char* vkh = (const char*)vb + (size_t)(k * 8 + h) * (LTOT * 64) + cg * 16;
        #pragma unroll
        for (int j = 0; j < 4; ++j) {
            int ti = sq * 17 + tg * 4 + j;
            #pragma unroll
            for (int corner = 0; corner < 4; ++corner) {
                int2 t = s_tab[k][corner][ti];
                float w = __int_as_float(t.y);
                uint4 d = *(const uint4*)(vkh + t.x);
                a0 += w * __uint_as_float(d.x << 16);
                a1 += w * __uint_as_float(d.x & 0xFFFF0000u);
                a2 += w * __uint_as_float(d.y << 16);
                a3 += w * __uint_as_float(d.y & 0xFFFF0000u);
                a4 += w * __uint_as_float(d.z << 16);
                a5 += w * __uint_as_float(d.z & 0xFFFF0000u);
                a6 += w * __uint_as_float(d.w << 16);
                a7 += w * __uint_as_float(d.w & 0xFFFF0000u);
            }
        }
    }

    a0 += __shfl_xor(a0, 4, 64); a0 += __shfl_xor(a0, 8, 64);
    a1 += __shfl_xor(a1, 4, 64); a1 += __shfl_xor(a1, 8, 64);
    a2 += __shfl_xor(a2, 4, 64); a2 += __shfl_xor(a2, 8, 64);
    a3 += __shfl_xor(a3, 4, 64); a3 += __shfl_xor(a3, 8, 64);
    a4 += __shfl_xor(a4, 4, 64); a4 += __shfl_xor(a4, 8, 64);
    a5 += __shfl_xor(a5, 4, 64); a5 += __shfl_xor(a5, 8, 64);
    a6 += __shfl_xor(a6, 4, 64); a6 += __shfl_xor(a6, 8, 64);
    a7 += __shfl_xor(a7, 4, 64); a7 += __shfl_xor(a7, 8, 64);

    if ((tid & 12) == 0) {
        int nv = s_nvis[sq];
        float sc = 1.f / (float)(nv > 0 ? nv : 1);
        uint4 o;
        o.x = f32_to_bf16(a0 * sc) | ((unsigned)f32_to_bf16(a1 * sc) << 16);
        o.y = f32_to_bf16(a2 * sc) | ((unsigned)f32_to_bf16(a3 * sc) << 16);
        o.z = f32_to_bf16(a4 * sc) | ((unsigned)f32_to_bf16(a5 * sc) << 16);
        o.w = f32_to_bf16(a6 * sc) | ((unsigned)f32_to_bf16(a7 * sc) << 16);
        *(uint4*)(outsum + (size_t)n_s * 256 + h * 32 + cg * 8) = o;
    }
    if (h == 0 && tid < 16) visb[q0 + tid] = (s_nvis[tid] > 0) ? 1.f : 0.f;
}

// ---------------------------------------------------------------------------
// Fused output-projection + residual + LN1. BM=32, BN=256, K=256.
// ---------------------------------------------------------------------------
__global__ __launch_bounds__(256) void projln1_kernel(
    const unsigned short* __restrict__ A, const unsigned short* __restrict__ BT,
    const float* __restrict__ query, const float* __restrict__ visb,
    const float* __restrict__ b_out, const float* __restrict__ g,
    const float* __restrict__ b,
    float* __restrict__ xout, unsigned short* __restrict__ xbf)
{
    const int K = 256;
    __shared__ __align__(16) unsigned short As[32][40];
    __shared__ __align__(16) unsigned short Bs[256][40];
    __shared__ float sred[2][4][4][2];
    __shared__ float ssred[2][4][4][2];
    __shared__ float s_mu[32], s_rs[32];

    const int tid  = threadIdx.x;
    const int wave = tid >> 6, lane = tid & 63;
    const int wm = wave >> 1, wn = wave & 1;
    const int quad = lane >> 4, l16 = lane & 15;
    const int m0 = blockIdx.x * 32;

    f32x4 acc[8] = {};

    for (int k0 = 0; k0 < K; k0 += 32) {
        {
            int r = tid >> 3, kc = (tid & 7) * 4;
            *(uint2*)&As[r][kc] = *(const uint2*)(A + (size_t)(m0 + r) * K + k0 + kc);
        }
        {
            const unsigned short* src = BT + (size_t)tid * K + k0;
            *(uint4*)&Bs[tid][0]  = *(const uint4*)(src);
            *(uint4*)&Bs[tid][8]  = *(const uint4*)(src + 8);
            *(uint4*)&Bs[tid][16] = *(const uint4*)(src + 16);
            *(uint4*)&Bs[tid][24] = *(const uint4*)(src + 24);
        }
        __syncthreads();
        bf16x8 af = *(const bf16x8*)&As[wm * 16 + l16][quad * 8];
        #pragma unroll
        for (int ni = 0; ni < 8; ++ni) {
            bf16x8 bfr = *(const bf16x8*)&Bs[wn * 128 + ni * 16 + l16][quad * 8];
            acc[ni] = __builtin_amdgcn_mfma_f32_16x16x32_bf16(af, bfr, acc[ni], 0, 0, 0);
        }
        __syncthreads();
    }

    float vals[8][4];
    #pragma unroll
    for (int r = 0; r < 4; ++r) {
        int gm = m0 + wm * 16 + quad * 4 + r;
        float vs = visb[gm];
        float s = 0.f, ss = 0.f;
        #pragma unroll
        for (int ni = 0; ni < 8; ++ni) {
            int gn = wn * 128 + ni * 16 + l16;
            float v = acc[ni][r] + vs * b_out[gn]
                    + query[(size_t)gm * 256 + gn] * (1.f + vs);
            vals[ni][r] = v;
            s += v; ss += v * v;
        }
        #pragma unroll
        for (int m = 1; m < 16; m <<= 1) {
            s  += __shfl_xor(s,  m, 64);
            ss += __shfl_xor(ss, m, 64);
        }
        if (l16 == 0) {
            sred[wm][quad][r][wn]  = s;
            ssred[wm][quad][r][wn] = ss;
        }
    }
    __syncthreads();
    if (tid < 32) {
        int lwm = tid >> 4, lq = (tid >> 2) & 3, lr = tid & 3;
        float s  = sred[lwm][lq][lr][0]  + sred[lwm][lq][lr][1];
        float ss = ssred[lwm][lq][lr][0] + ssred[lwm][lq][lr][1];
        float mu = s * (1.f / 256.f);
        float var = ss * (1.f / 256.f) - mu * mu;
        s_mu[tid] = mu;
        s_rs[tid] = rsqrtf(var + 1e-5f);
    }
    __syncthreads();

    #pragma unroll
    for (int r = 0; r < 4; ++r) {
        int rowl = wm * 16 + quad * 4 + r;
        int gm = m0 + rowl;
        float mu = s_mu[rowl], rs = s_rs[rowl];
        #pragma unroll
        for (int ni = 0; ni < 8; ++ni) {
            int gn = wn * 128 + ni * 16 + l16;
            float res = (vals[ni][r] - mu) * rs * g[gn] + b[gn];
            xout[(size_t)gm * 256 + gn] = res;
            xbf[(size_t)gm * 256 + gn] = f32_to_bf16(res);
        }
    }
}

// ---------------------------------------------------------------------------
// MFMA bf16 GEMM, BM=64 BN=128 BK=32, bf16 A + BT. Split-K over gridDim.z
// (each z writes its own C buffer; bias only on z==0).
// mode 0: fp32 out; mode 1: relu -> bf16 out (Cb).
// ---------------------------------------------------------------------------
__global__ __launch_bounds__(256) void gemm64_kernel(
    const unsigned short* __restrict__ A, const unsigned short* __restrict__ BT,
    const float* __restrict__ bias, float* __restrict__ C,
    unsigned short* __restrict__ Cb,
    int M, int N, int K, int mode)
{
    __shared__ __align__(16) unsigned short As[64][40];
    __shared__ __align__(16) unsigned short Bs[128][40];

    const int tid  = threadIdx.x;
    const int wave = tid >> 6, lane = tid & 63;
    const int wm = wave >> 1, wn = wave & 1;
    const int quad = lane >> 4, l16 = lane & 15;
    const int m0 = blockIdx.y * 64, n0 = blockIdx.x * 128;
    const int nz = gridDim.z;
    const int klen = K / nz;
    const int kbase = blockIdx.z * klen;

    f32x4 acc[2][4] = {};

    for (int k0 = kbase; k0 < kbase + klen; k0 += 32) {
        {
            int r = tid >> 2, kc = (tid & 3) * 8;
            int gr = m0 + r;
            uint4 d = (gr < M) ? *(const uint4*)(A + (size_t)gr * K + k0 + kc)
                               : make_uint4(0u, 0u, 0u, 0u);
            *(uint4*)&As[r][kc] = d;
        }
        #pragma unroll
        for (int i = 0; i < 2; ++i) {
            int idx = tid + 256 * i;
            int r = idx >> 2, kc = (idx & 3) * 8;
            *(uint4*)&Bs[r][kc] = *(const uint4*)(BT + (size_t)(n0 + r) * K + k0 + kc);
        }
        __syncthreads();
        bf16x8 af[2], bfr[4];
        #pragma unroll
        for (int mi = 0; mi < 2; ++mi)
            af[mi] = *(const bf16x8*)&As[wm * 32 + mi * 16 + l16][quad * 8];
        #pragma unroll
        for (int ni = 0; ni < 4; ++ni)
            bfr[ni] = *(const bf16x8*)&Bs[wn * 64 + ni * 16 + l16][quad * 8];
        #pragma unroll
        for (int mi = 0; mi < 2; ++mi)
            #pragma unroll
            for (int ni = 0; ni < 4; ++ni)
                acc[mi][ni] = __builtin_amdgcn_mfma_f32_16x16x32_bf16(
                    af[mi], bfr[ni], acc[mi][ni], 0, 0, 0);
        __syncthreads();
    }

    const float* bz = (blockIdx.z == 0) ? bias : nullptr;
    float* Cz = C ? (C + (size_t)blockIdx.z * M * N) : nullptr;

    #pragma unroll
    for (int mi = 0; mi < 2; ++mi) {
        #pragma unroll
        for (int r = 0; r < 4; ++r) {
            int gm = m0 + wm * 32 + mi * 16 + quad * 4 + r;
            if (gm >= M) continue;
            #pragma unroll
            for (int ni = 0; ni < 4; ++ni) {
                int gn = n0 + wn * 64 + ni * 16 + l16;
                float v = acc[mi][ni][r] + (bz ? bz[gn] : 0.f);
                if (mode == 1) {
                    Cb[(size_t)gm * N + gn] = f32_to_bf16(fmaxf(v, 0.f));
                } else {
                    Cz[(size_t)gm * N + gn] = v;
                }
            }
        }
    }
}

// ---------------------------------------------------------------------------
// Vectorized LN2: one wave per row (float4 per lane), 4 rows per block.
// out = LN( x + f0 + f1 )
// ---------------------------------------------------------------------------
__global__ __launch_bounds__(256) void ln2v_kernel(
    const float* __restrict__ x, const float* __restrict__ f0,
    const float* __restrict__ f1,
    const float* __restrict__ g, const float* __restrict__ b,
    float* __restrict__ out)
{
    int row  = blockIdx.x * 4 + (threadIdx.x >> 6);
    int lane = threadIdx.x & 63;
    size_t base = (size_t)row * 256 + lane * 4;
    float4 xv = *(const float4*)(x + base);
    float4 av = *(const float4*)(f0 + base);
    float4 cv = *(const float4*)(f1 + base);
    float t0 = xv.x + av.x + cv.x;
    float t1 = xv.y + av.y + cv.y;
    float t2 = xv.z + av.z + cv.z;
    float t3 = xv.w + av.w + cv.w;
    float s  = t0 + t1 + t2 + t3;
    float ss = t0 * t0 + t1 * t1 + t2 * t2 + t3 * t3;
    #pragma unroll
    for (int m = 1; m < 64; m <<= 1) {
        s  += __shfl_xor(s,  m, 64);
        ss += __shfl_xor(ss, m, 64);
    }
    float mu = s * (1.f / 256.f);
    float rs = rsqrtf(ss * (1.f / 256.f) - mu * mu + 1e-5f);
    float4 gv = *(const float4*)(g + lane * 4);
    float4 bv = *(const float4*)(b + lane * 4);
    float4 o;
    o.x = (t0 - mu) * rs * gv.x + bv.x;
    o.y = (t1 - mu) * rs * gv.y + bv.y;
    o.z = (t2 - mu) * rs * gv.z + bv.z;
    o.w = (t3 - mu) * rs * gv.w + bv.w;
    *(float4*)(out + base) = o;
}

// ---------------------------------------------------------------------------
extern "C" void kernel_launch(void* const* d_in, const int* in_sizes, int n_in,
                              void* d_out, int out_size, void* d_ws, size_t ws_size,
                              hipStream_t stream)
{
    const float* query   = (const float*)d_in[0];
    const float* value   = (const float*)d_in[2];
    const float* refpts  = (const float*)d_in[3];
    const int*   bevmask = (const int*)d_in[6];
    const float* W_value = (const float*)d_in[7];
    const float* b_value = (const float*)d_in[8];
    const float* W_off   = (const float*)d_in[9];
    const float* b_off   = (const float*)d_in[10];
    const float* W_attn  = (const float*)d_in[11];
    const float* b_attn  = (const float*)d_in[12];
    const float* W_out   = (const float*)d_in[13];
    const float* b_out   = (const float*)d_in[14];
    const float* ln1_g   = (const float*)d_in[15];
    const float* ln1_b   = (const float*)d_in[16];
    const float* W1      = (const float*)d_in[17];
    const float* b1      = (const float*)d_in[18];
    const float* W2      = (const float*)d_in[19];
    const float* b2      = (const float*)d_in[20];
    const float* ln2_g   = (const float*)d_in[21];
    const float* ln2_b   = (const float*)d_in[22];
    float* out = (float*)d_out;

    // workspace layout (byte offsets, temporal aliasing):
    //  [0)          vb bf16 24,511,488      (head -> sample)
    //  [0)          xbuf fp32 6,553,600     (projln1 -> ln2)   [vb dead]
    //  [7,000,000)  xbf bf16 3,276,800      (projln1 -> ffn1)  [vb dead]
    //  [11,000,000) hbf bf16 13,107,200     (ffn1 -> K6)       [vb dead]
    //  [25,000,000) qoff fp32 6,553,600     (head -> sample)
    //  [32,000,000) qaw fp32 3,276,800      (head -> sample)
    //  [35,300,000) outsum bf16 3,276,800   (sample -> projln1)
    //  [38,600,000) visb 25,600             (sample -> projln1)
    //  [38,700,000) wsT bf16 1,179,648      (head -> tail GEMMs)
    //  [41,000,000) ffnout fp32 2x6,553,600 (K6 -> ln2)
    char* ws = (char*)d_ws;
    unsigned short* vb     = (unsigned short*)(ws + 0);
    float*          xbuf   = (float*)(ws + 0);
    unsigned short* xbf    = (unsigned short*)(ws + 7000000);
    unsigned short* hbf    = (unsigned short*)(ws + 11000000);
    float*          qoff   = (float*)(ws + 25000000);
    float*          qaw    = (float*)(ws + 32000000);
    unsigned short* outsum = (unsigned short*)(ws + 35300000);
    float*          visb   = (float*)(ws + 38600000);
    unsigned short* wsT    = (unsigned short*)(ws + 38700000);
    float*          ffnout = (float*)(ws + 41000000);

    unsigned short* WoT = wsT;            // [256][256]
    unsigned short* W1T = wsT + 65536;    // [1024][256]
    unsigned short* W2T = wsT + 327680;   // [256][1024]

    // L1: value proj (750) + query proj (300) + weight transpose (576)
    head_kernel<<<dim3(1626), 256, 0, stream>>>(
        value, query, W_value, b_value, W_off, b_off, W_attn, b_attn,
        W_out, W1, W2, vb, qoff, qaw, wsT);
    // L2: head-partitioned sampling
    sample_kernel<<<dim3(3200), 256, 0, stream>>>(
        vb, qoff, qaw, refpts, bevmask, outsum, visb);
    // L3: x = LN(outsum@W_out + residual algebra)
    projln1_kernel<<<dim3(200), 256, 0, stream>>>(
        outsum, WoT, query, visb, b_out, ln1_g, ln1_b, xbuf, xbf);
    // L4: hbf = bf16(relu(x @ W1 + b1))
    gemm64_kernel<<<dim3(8, 100, 1), 256, 0, stream>>>(
        xbf, W1T, b1, nullptr, hbf, NQ, DFFN, 256, 1);
    // L5: ffnout[z] = h @ W2 (+b2 on z=0), split-K x2
    gemm64_kernel<<<dim3(2, 100, 2), 256, 0, stream>>>(
        hbf, W2T, b2, ffnout, nullptr, NQ, 256, DFFN, 0);
    // L6: out = LN(x + f0 + f1)
    ln2v_kernel<<<dim3(1600), 256, 0, stream>>>(
        xbuf, ffnout, ffnout + (size_t)NQ * 256, ln2_g, ln2_b, out);
}

// Round 9
// 308.583 us; speedup vs baseline: 1.0721x; 1.0585x over previous
//
#include <hip/hip_runtime.h>
#include <math.h>

#define NQ      6400
#define NCAMS   6
#define LTOT    7979
#define DM      256
#define DFFN    1024

typedef __attribute__((ext_vector_type(8))) short bf16x8;
typedef __attribute__((ext_vector_type(4))) float f32x4;

__device__ inline unsigned short f32_to_bf16(float f) {
    unsigned u = __float_as_uint(f);
    unsigned r = u + 0x7FFF + ((u >> 16) & 1);   // round-to-nearest-even
    return (unsigned short)(r >> 16);
}

// ---------------------------------------------------------------------------
// Weight transpose + convert: WT[n][k] (bf16) = W[k][n] (fp32), all 5 weights.
// wsT layout (shorts): WvT@0, WqT@65536 ([384][256]: W_off rows 0..255,
// W_attn rows 256..383), WoT@163840, W1T@229376 ([1024][256]),
// W2T@491520 ([256][1024]).
// ---------------------------------------------------------------------------
__global__ __launch_bounds__(256) void wt_kernel(
    const float* __restrict__ Wv, const float* __restrict__ Woff,
    const float* __restrict__ Wattn, const float* __restrict__ Wout,
    const float* __restrict__ W1, const float* __restrict__ W2,
    unsigned short* __restrict__ wsT)
{
    int b = blockIdx.x;
    const float* src; int K, N, t0, dstoff;
    if (b < 64)       { src = Wv;    K = 256;  N = 256;  t0 = 0;   dstoff = 0; }
    else if (b < 128) { src = Woff;  K = 256;  N = 256;  t0 = 64;  dstoff = 65536; }
    else if (b < 160) { src = Wattn; K = 256;  N = 128;  t0 = 128; dstoff = 131072; }
    else if (b < 224) { src = Wout;  K = 256;  N = 256;  t0 = 160; dstoff = 163840; }
    else if (b < 480) { src = W1;    K = 256;  N = 1024; t0 = 224; dstoff = 229376; }
    else              { src = W2;    K = 1024; N = 256;  t0 = 480; dstoff = 491520; }
    int t = b - t0;
    int ntn = N >> 5;
    int kt = t / ntn, nt = t - kt * ntn;
    __shared__ float tile[32][33];
    int tx = threadIdx.x & 31, ty = threadIdx.x >> 5;
    #pragma unroll
    for (int i = 0; i < 4; ++i)
        tile[ty + i * 8][tx] = src[(size_t)(kt * 32 + ty + i * 8) * N + nt * 32 + tx];
    __syncthreads();
    #pragma unroll
    for (int i = 0; i < 4; ++i) {
        int nn = nt * 32 + ty + i * 8;
        wsT[dstoff + (size_t)nn * K + kt * 32 + tx] = f32_to_bf16(tile[tx][ty + i * 8]);
    }
}

// ---------------------------------------------------------------------------
// head_kernel: merged value projection + query projections (preconverted
// bf16 weights, uint4 staging).
//  b <  750 : value proj (BM=BN=128): A fp32 converted inline, B=WvT uint4.
//             -> vb bf16 head-major (cam, head, pixel, 32ch)
//  else     : query projections (BM=64): bx=0,1 -> qoff; bx=2 -> softmax->qaw
// ---------------------------------------------------------------------------
__global__ __launch_bounds__(256) void head_kernel(
    const float* __restrict__ value, const float* __restrict__ query,
    const unsigned short* __restrict__ WvT, const unsigned short* __restrict__ WqT,
    const float* __restrict__ bv, const float* __restrict__ boff,
    const float* __restrict__ battn,
    unsigned short* __restrict__ vb, float* __restrict__ qoff,
    float* __restrict__ qaw)
{
    __shared__ __align__(16) unsigned char smem[20480];
    const int b = blockIdx.x;
    const int tid = threadIdx.x;
    const int wave = tid >> 6, lane = tid & 63;
    const int wm = wave >> 1, wn = wave & 1;
    const int quad = lane >> 4, l16 = lane & 15;

    if (b < 750) {
        unsigned short (*As)[40] = (unsigned short(*)[40])smem;
        unsigned short (*Bs)[40] = (unsigned short(*)[40])(smem + 10240);
        const int m0 = (b >> 1) * 128, n0 = (b & 1) * 128;
        const int M = NCAMS * LTOT;

        f32x4 acc[4][4] = {};

        for (int k0 = 0; k0 < 256; k0 += 32) {
            #pragma unroll
            for (int i = 0; i < 2; ++i) {          // A: 128x32 fp32 -> bf16
                int idx = tid + 256 * i;
                int r = idx >> 2, kc = (idx & 3) * 8;
                int gr = m0 + r;
                float4 f0, f1;
                if (gr < M) {
                    f0 = *(const float4*)(value + (size_t)gr * 256 + k0 + kc);
                    f1 = *(const float4*)(value + (size_t)gr * 256 + k0 + kc + 4);
                } else { f0 = make_float4(0.f,0.f,0.f,0.f); f1 = f0; }
                uint4 o;
                o.x = f32_to_bf16(f0.x) | ((unsigned)f32_to_bf16(f0.y) << 16);
                o.y = f32_to_bf16(f0.z) | ((unsigned)f32_to_bf16(f0.w) << 16);
                o.z = f32_to_bf16(f1.x) | ((unsigned)f32_to_bf16(f1.y) << 16);
                o.w = f32_to_bf16(f1.z) | ((unsigned)f32_to_bf16(f1.w) << 16);
                *(uint4*)&As[r][kc] = o;
            }
            #pragma unroll
            for (int i = 0; i < 2; ++i) {          // B: WvT bf16, uint4
                int idx = tid + 256 * i;
                int r = idx >> 2, kc = (idx & 3) * 8;
                *(uint4*)&Bs[r][kc] = *(const uint4*)(WvT + (size_t)(n0 + r) * 256 + k0 + kc);
            }
            __syncthreads();
            bf16x8 af[4], bfr[4];
            #pragma unroll
            for (int mi = 0; mi < 4; ++mi)
                af[mi] = *(const bf16x8*)&As[wm * 64 + mi * 16 + l16][quad * 8];
            #pragma unroll
            for (int ni = 0; ni < 4; ++ni)
                bfr[ni] = *(const bf16x8*)&Bs[wn * 64 + ni * 16 + l16][quad * 8];
            #pragma unroll
            for (int mi = 0; mi < 4; ++mi)
                #pragma unroll
                for (int ni = 0; ni < 4; ++ni)
                    acc[mi][ni] = __builtin_amdgcn_mfma_f32_16x16x32_bf16(
                        af[mi], bfr[ni], acc[mi][ni], 0, 0, 0);
            __syncthreads();
        }

        #pragma unroll
        for (int mi = 0; mi < 4; ++mi) {
            #pragma unroll
            for (int r = 0; r < 4; ++r) {
                int gm = m0 + wm * 64 + mi * 16 + quad * 4 + r;
                if (gm >= M) continue;
                int cam = gm / LTOT;
                int pix = gm - cam * LTOT;
                #pragma unroll
                for (int ni = 0; ni < 4; ++ni) {
                    int gn = n0 + wn * 64 + ni * 16 + l16;
                    int head = gn >> 5, ch = gn & 31;
                    float v = acc[mi][ni][r] + bv[gn];
                    vb[(((size_t)(cam * 8 + head)) * LTOT + pix) * 32 + ch] = f32_to_bf16(v);
                }
            }
        }
    } else {
        unsigned short (*As)[40] = (unsigned short(*)[40])smem;
        unsigned short (*Bs)[40] = (unsigned short(*)[40])(smem + 5120);
        const int t = b - 750;
        const int bx = t / 100, by = t % 100;
        const int m0 = by * 64, n0 = bx * 128;
        const int is_attn = (bx == 2);

        f32x4 acc[2][4] = {};

        for (int k0 = 0; k0 < 256; k0 += 32) {
            {                                       // A: 64x32 fp32 -> bf16
                int r = tid >> 2, kc = (tid & 3) * 8;
                float4 f0 = *(const float4*)(query + (size_t)(m0 + r) * 256 + k0 + kc);
                float4 f1 = *(const float4*)(query + (size_t)(m0 + r) * 256 + k0 + kc + 4);
                uint4 o;
                o.x = f32_to_bf16(f0.x) | ((unsigned)f32_to_bf16(f0.y) << 16);
                o.y = f32_to_bf16(f0.z) | ((unsigned)f32_to_bf16(f0.w) << 16);
                o.z = f32_to_bf16(f1.x) | ((unsigned)f32_to_bf16(f1.y) << 16);
                o.w = f32_to_bf16(f1.z) | ((unsigned)f32_to_bf16(f1.w) << 16);
                *(uint4*)&As[r][kc] = o;
            }
            #pragma unroll
            for (int i = 0; i < 2; ++i) {           // B: WqT bf16, uint4
                int idx = tid + 256 * i;
                int r = idx >> 2, kc = (idx & 3) * 8;
                *(uint4*)&Bs[r][kc] = *(const uint4*)(WqT + (size_t)(n0 + r) * 256 + k0 + kc);
            }
            __syncthreads();
            bf16x8 af[2], bfr[4];
            #pragma unroll
            for (int mi = 0; mi < 2; ++mi)
                af[mi] = *(const bf16x8*)&As[wm * 32 + mi * 16 + l16][quad * 8];
            #pragma unroll
            for (int ni = 0; ni < 4; ++ni)
                bfr[ni] = *(const bf16x8*)&Bs[wn * 64 + ni * 16 + l16][quad * 8];
            #pragma unroll
            for (int mi = 0; mi < 2; ++mi)
                #pragma unroll
                for (int ni = 0; ni < 4; ++ni)
                    acc[mi][ni] = __builtin_amdgcn_mfma_f32_16x16x32_bf16(
                        af[mi], bfr[ni], acc[mi][ni], 0, 0, 0);
            __syncthreads();
        }

        if (is_attn) {
            #pragma unroll
            for (int mi = 0; mi < 2; ++mi) {
                #pragma unroll
                for (int r = 0; r < 4; ++r) {
                    int gm = m0 + wm * 32 + mi * 16 + quad * 4 + r;
                    #pragma unroll
                    for (int ni = 0; ni < 4; ++ni) {
                        int gn = wn * 64 + ni * 16 + l16;
                        float v = acc[mi][ni][r] + battn[gn];
                        float mx = v;
                        #pragma unroll
                        for (int s = 1; s < 16; s <<= 1)
                            mx = fmaxf(mx, __shfl_xor(mx, s, 64));
                        float e = __expf(v - mx);
                        float sum = e;
                        #pragma unroll
                        for (int s = 1; s < 16; s <<= 1)
                            sum += __shfl_xor(sum, s, 64);
                        qaw[(size_t)gm * 128 + gn] = e / sum;
                    }
                }
            }
        } else {
            #pragma unroll
            for (int mi = 0; mi < 2; ++mi) {
                #pragma unroll
                for (int r = 0; r < 4; ++r) {
                    int gm = m0 + wm * 32 + mi * 16 + quad * 4 + r;
                    #pragma unroll
                    for (int ni = 0; ni < 4; ++ni) {
                        int gn = n0 + wn * 64 + ni * 16 + l16;
                        qoff[(size_t)gm * 256 + gn] = acc[mi][ni][r] + boff[gn];
                    }
                }
            }
        }
    }
}

// ---------------------------------------------------------------------------
// Head-partitioned deformable sampling. Corner tables packed to 1 uint per
// corner (pix<<16 | bf16(weight)), tuple-major -> one ds_read_b128 fetches
// all 4 corners. LDS 26.6 KB -> ~6 blocks/CU occupancy.
// ---------------------------------------------------------------------------
__global__ __launch_bounds__(256) void sample_kernel(
    const unsigned short* __restrict__ vb, // (6, 8, 7979, 32) bf16
    const float* __restrict__ qoff,        // (6400, 256)
    const float* __restrict__ aw,          // (6400, 128)
    const float* __restrict__ refpts,      // (6, 1, 6400, 4, 2)
    const int*   __restrict__ bev_mask,    // (6, 1, 6400, 4)
    unsigned short* __restrict__ outsum,   // (6400, 256) bf16
    float* __restrict__ visb)              // (6400)
{
    const int bid = blockIdx.x;
    const int h   = bid & 7;
    const int q0  = (bid >> 3) * 16;
    const int tid = threadIdx.x;
    const int sq  = tid >> 4;
    const int tup = tid & 15;
    const int lvl = tup >> 2;
    const int n_s = q0 + sq;
    const int tg  = (tid >> 2) & 3;
    const int cg  = tid & 3;

    __shared__ unsigned s_tab[NCAMS][272][4];   // [cam][sq*17+tup][corner]
    __shared__ float s_vis[NCAMS][16];
    __shared__ int   s_cnt[NCAMS];
    __shared__ int   s_nvis[16];

    if (tid < 96) {
        int cam = tid >> 4, q = tid & 15;
        const int* bm = bev_mask + ((size_t)cam * NQ + q0 + q) * 4;
        s_vis[cam][q] = ((bm[0] + bm[1] + bm[2] + bm[3]) > 0) ? 1.f : 0.f;
    }
    __syncthreads();
    if (tid < NCAMS) {
        float s = 0.f;
        #pragma unroll
        for (int q = 0; q < 16; ++q) s += s_vis[tid][q];
        s_cnt[tid] = (int)s;
    }
    if (tid >= 32 && tid < 48) {
        int q = tid - 32;
        float s = 0.f;
        #pragma unroll
        for (int cam = 0; cam < NCAMS; ++cam) s += s_vis[cam][q];
        s_nvis[q] = (int)s;
    }

    const float my_aw = aw[(size_t)n_s * 128 + h * 16 + tup];
    const float offx  = qoff[(size_t)n_s * 256 + h * 32 + tup * 2];
    const float offy  = qoff[(size_t)n_s * 256 + h * 32 + tup * 2 + 1];
    const int Wl   = (lvl == 0) ? 100 : (lvl == 1) ? 50 : (lvl == 2) ? 25 : 13;
    const int Hl   = (lvl == 0) ? 60  : (lvl == 1) ? 30 : (lvl == 2) ? 15 : 8;
    const int base = (lvl == 0) ? 0   : (lvl == 1) ? 6000 : (lvl == 2) ? 7500 : 7875;
    const float dx = offx / (float)Wl;
    const float dy = offy / (float)Hl;
    const int tabi = sq * 17 + tup;

    float2 rp[NCAMS];
    #pragma unroll
    for (int k = 0; k < NCAMS; ++k)
        rp[k] = *(const float2*)(refpts + (((size_t)k * NQ + n_s) * 4 + lvl) * 2);
    __syncthreads();   // covers s_cnt/s_nvis writes

    #pragma unroll
    for (int k = 0; k < NCAMS; ++k) {
        float fx = (rp[k].x + dx) * (float)Wl - 0.5f;
        float fy = (rp[k].y + dy) * (float)Hl - 0.5f;
        float x0f = floorf(fx), y0f = floorf(fy);
        float lx = fx - x0f, ly = fy - y0f;
        int x0 = (int)x0f, y0 = (int)y0f;
        int x1 = x0 + 1, y1 = y0 + 1;
        float wb = my_aw * s_vis[k][sq];
        float w00 = (1.f - lx) * (1.f - ly) * wb;
        float w01 = lx * (1.f - ly) * wb;
        float w10 = (1.f - lx) * ly * wb;
        float w11 = lx * ly * wb;
        bool vx0 = (x0 >= 0) & (x0 < Wl), vx1 = (x1 >= 0) & (x1 < Wl);
        bool vy0 = (y0 >= 0) & (y0 < Hl), vy1 = (y1 >= 0) & (y1 < Hl);
        uint4 o;
        o.x = (vx0 & vy0) ? (((unsigned)(base + y0 * Wl + x0) << 16) | f32_to_bf16(w00)) : 0u;
        o.y = (vx1 & vy0) ? (((unsigned)(base + y0 * Wl + x1) << 16) | f32_to_bf16(w01)) : 0u;
        o.z = (vx0 & vy1) ? (((unsigned)(base + y1 * Wl + x0) << 16) | f32_to_bf16(w10)) : 0u;
        o.w = (vx1 & vy1) ? (((unsigned)(base + y1 * Wl + x1) << 16) | f32_to_bf16(w11)) : 0u;
        *(uint4*)&s_tab[k][tabi][0] = o;
    }
    __syncthreads();

    float a0 = 0.f, a1 = 0.f, a2 = 0.f, a3 = 0.f;
    float a4 = 0.f, a5 = 0.f, a6 = 0.f, a7 = 0.f;

    for (int k = 0; k < NCAMS; ++k) {
        if (s_cnt[k] == 0) continue;
        const char* vkh = (const char*)vb + (size_t)(k * 8 + h) * (LTOT * 64) + cg * 16;
        #pragma unroll
        for (int j = 0; j < 4; ++j) {
            uint4 t4 = *(const uint4*)&s_tab[k][sq * 17 + tg * 4 + j][0];
            #pragma unroll
            for (int corner = 0; corner < 4; ++corner) {
                unsigned tc = (corner == 0) ? t4.x : (corner == 1) ? t4.y
                            : (corner == 2) ? t4.z : t4.w;
                float w = __uint_as_float(tc << 16);
                uint4 d = *(const uint4*)(vkh + ((size_t)(tc >> 16) << 6));
                a0 += w * __uint_as_float(d.x << 16);
                a1 += w * __uint_as_float(d.x & 0xFFFF0000u);
                a2 += w * __uint_as_float(d.y << 16);
                a3 += w * __uint_as_float(d.y & 0xFFFF0000u);
                a4 += w * __uint_as_float(d.z << 16);
                a5 += w * __uint_as_float(d.z & 0xFFFF0000u);
                a6 += w * __uint_as_float(d.w << 16);
                a7 += w * __uint_as_float(d.w & 0xFFFF0000u);
            }
        }
    }

    a0 += __shfl_xor(a0, 4, 64); a0 += __shfl_xor(a0, 8, 64);
    a1 += __shfl_xor(a1, 4, 64); a1 += __shfl_xor(a1, 8, 64);
    a2 += __shfl_xor(a2, 4, 64); a2 += __shfl_xor(a2, 8, 64);
    a3 += __shfl_xor(a3, 4, 64); a3 += __shfl_xor(a3, 8, 64);
    a4 += __shfl_xor(a4, 4, 64); a4 += __shfl_xor(a4, 8, 64);
    a5 += __shfl_xor(a5, 4, 64); a5 += __shfl_xor(a5, 8, 64);
    a6 += __shfl_xor(a6, 4, 64); a6 += __shfl_xor(a6, 8, 64);
    a7 += __shfl_xor(a7, 4, 64); a7 += __shfl_xor(a7, 8, 64);

    if ((tid & 12) == 0) {
        int nv = s_nvis[sq];
        float sc = 1.f / (float)(nv > 0 ? nv : 1);
        uint4 o;
        o.x = f32_to_bf16(a0 * sc) | ((unsigned)f32_to_bf16(a1 * sc) << 16);
        o.y = f32_to_bf16(a2 * sc) | ((unsigned)f32_to_bf16(a3 * sc) << 16);
        o.z = f32_to_bf16(a4 * sc) | ((unsigned)f32_to_bf16(a5 * sc) << 16);
        o.w = f32_to_bf16(a6 * sc) | ((unsigned)f32_to_bf16(a7 * sc) << 16);
        *(uint4*)(outsum + (size_t)n_s * 256 + h * 32 + cg * 8) = o;
    }
    if (h == 0 && tid < 16) visb[q0 + tid] = (s_nvis[tid] > 0) ? 1.f : 0.f;
}

// ---------------------------------------------------------------------------
// Fused output-projection + residual + LN1. BM=32, BN=256, K=256.
// ---------------------------------------------------------------------------
__global__ __launch_bounds__(256) void projln1_kernel(
    const unsigned short* __restrict__ A, const unsigned short* __restrict__ BT,
    const float* __restrict__ query, const float* __restrict__ visb,
    const float* __restrict__ b_out, const float* __restrict__ g,
    const float* __restrict__ b,
    float* __restrict__ xout, unsigned short* __restrict__ xbf)
{
    const int K = 256;
    __shared__ __align__(16) unsigned short As[32][40];
    __shared__ __align__(16) unsigned short Bs[256][40];
    __shared__ float sred[2][4][4][2];
    __shared__ float ssred[2][4][4][2];
    __shared__ float s_mu[32], s_rs[32];

    const int tid  = threadIdx.x;
    const int wave = tid >> 6, lane = tid & 63;
    const int wm = wave >> 1, wn = wave & 1;
    const int quad = lane >> 4, l16 = lane & 15;
    const int m0 = blockIdx.x * 32;

    f32x4 acc[8] = {};

    for (int k0 = 0; k0 < K; k0 += 32) {
        {
            int r = tid >> 3, kc = (tid & 7) * 4;
            *(uint2*)&As[r][kc] = *(const uint2*)(A + (size_t)(m0 + r) * K + k0 + kc);
        }
        {
            const unsigned short* src = BT + (size_t)tid * K + k0;
            *(uint4*)&Bs[tid][0]  = *(const uint4*)(src);
            *(uint4*)&Bs[tid][8]  = *(const uint4*)(src + 8);
            *(uint4*)&Bs[tid][16] = *(const uint4*)(src + 16);
            *(uint4*)&Bs[tid][24] = *(const uint4*)(src + 24);
        }
        __syncthreads();
        bf16x8 af = *(const bf16x8*)&As[wm * 16 + l16][quad * 8];
        #pragma unroll
        for (int ni = 0; ni < 8; ++ni) {
            bf16x8 bfr = *(const bf16x8*)&Bs[wn * 128 + ni * 16 + l16][quad * 8];
            acc[ni] = __builtin_amdgcn_mfma_f32_16x16x32_bf16(af, bfr, acc[ni], 0, 0, 0);
        }
        __syncthreads();
    }

    float vals[8][4];
    #pragma unroll
    for (int r = 0; r < 4; ++r) {
        int gm = m0 + wm * 16 + quad * 4 + r;
        float vs = visb[gm];
        float s = 0.f, ss = 0.f;
        #pragma unroll
        for (int ni = 0; ni < 8; ++ni) {
            int gn = wn * 128 + ni * 16 + l16;
            float v = acc[ni][r] + vs * b_out[gn]
                    + query[(size_t)gm * 256 + gn] * (1.f + vs);
            vals[ni][r] = v;
            s += v; ss += v * v;
        }
        #pragma unroll
        for (int m = 1; m < 16; m <<= 1) {
            s  += __shfl_xor(s,  m, 64);
            ss += __shfl_xor(ss, m, 64);
        }
        if (l16 == 0) {
            sred[wm][quad][r][wn]  = s;
            ssred[wm][quad][r][wn] = ss;
        }
    }
    __syncthreads();
    if (tid < 32) {
        int lwm = tid >> 4, lq = (tid >> 2) & 3, lr = tid & 3;
        float s  = sred[lwm][lq][lr][0]  + sred[lwm][lq][lr][1];
        float ss = ssred[lwm][lq][lr][0] + ssred[lwm][lq][lr][1];
        float mu = s * (1.f / 256.f);
        float var = ss * (1.f / 256.f) - mu * mu;
        s_mu[tid] = mu;
        s_rs[tid] = rsqrtf(var + 1e-5f);
    }
    __syncthreads();

    #pragma unroll
    for (int r = 0; r < 4; ++r) {
        int rowl = wm * 16 + quad * 4 + r;
        int gm = m0 + rowl;
        float mu = s_mu[rowl], rs = s_rs[rowl];
        #pragma unroll
        for (int ni = 0; ni < 8; ++ni) {
            int gn = wn * 128 + ni * 16 + l16;
            float res = (vals[ni][r] - mu) * rs * g[gn] + b[gn];
            xout[(size_t)gm * 256 + gn] = res;
            xbf[(size_t)gm * 256 + gn] = f32_to_bf16(res);
        }
    }
}

// ---------------------------------------------------------------------------
// MFMA bf16 GEMM, BM=64 BN=128 BK=32, bf16 A + BT. Split-K over gridDim.z.
// mode 0: fp32 out; mode 1: relu -> bf16 out (Cb).
// ---------------------------------------------------------------------------
__global__ __launch_bounds__(256) void gemm64_kernel(
    const unsigned short* __restrict__ A, const unsigned short* __restrict__ BT,
    const float* __restrict__ bias, float* __restrict__ C,
    unsigned short* __restrict__ Cb,
    int M, int N, int K, int mode)
{
    __shared__ __align__(16) unsigned short As[64][40];
    __shared__ __align__(16) unsigned short Bs[128][40];

    const int tid  = threadIdx.x;
    const int wave = tid >> 6, lane = tid & 63;
    const int wm = wave >> 1, wn = wave & 1;
    const int quad = lane >> 4, l16 = lane & 15;
    const int m0 = blockIdx.y * 64, n0 = blockIdx.x * 128;
    const int nz = gridDim.z;
    const int klen = K / nz;
    const int kbase = blockIdx.z * klen;

    f32x4 acc[2][4] = {};

    for (int k0 = kbase; k0 < kbase + klen; k0 += 32) {
        {
            int r = tid >> 2, kc = (tid & 3) * 8;
            int gr = m0 + r;
            uint4 d = (gr < M) ? *(const uint4*)(A + (size_t)gr * K + k0 + kc)
                               : make_uint4(0u, 0u, 0u, 0u);
            *(uint4*)&As[r][kc] = d;
        }
        #pragma unroll
        for (int i = 0; i < 2; ++i) {
            int idx = tid + 256 * i;
            int r = idx >> 2, kc = (idx & 3) * 8;
            *(uint4*)&Bs[r][kc] = *(const uint4*)(BT + (size_t)(n0 + r) * K + k0 + kc);
        }
        __syncthreads();
        bf16x8 af[2], bfr[4];
        #pragma unroll
        for (int mi = 0; mi < 2; ++mi)
            af[mi] = *(const bf16x8*)&As[wm * 32 + mi * 16 + l16][quad * 8];
        #pragma unroll
        for (int ni = 0; ni < 4; ++ni)
            bfr[ni] = *(const bf16x8*)&Bs[wn * 64 + ni * 16 + l16][quad * 8];
        #pragma unroll
        for (int mi = 0; mi < 2; ++mi)
            #pragma unroll
            for (int ni = 0; ni < 4; ++ni)
                acc[mi][ni] = __builtin_amdgcn_mfma_f32_16x16x32_bf16(
                    af[mi], bfr[ni], acc[mi][ni], 0, 0, 0);
        __syncthreads();
    }

    const float* bz = (blockIdx.z == 0) ? bias : nullptr;
    float* Cz = C ? (C + (size_t)blockIdx.z * M * N) : nullptr;

    #pragma unroll
    for (int mi = 0; mi < 2; ++mi) {
        #pragma unroll
        for (int r = 0; r < 4; ++r) {
            int gm = m0 + wm * 32 + mi * 16 + quad * 4 + r;
            if (gm >= M) continue;
            #pragma unroll
            for (int ni = 0; ni < 4; ++ni) {
                int gn = n0 + wn * 64 + ni * 16 + l16;
                float v = acc[mi][ni][r] + (bz ? bz[gn] : 0.f);
                if (mode == 1) {
                    Cb[(size_t)gm * N + gn] = f32_to_bf16(fmaxf(v, 0.f));
                } else {
                    Cz[(size_t)gm * N + gn] = v;
                }
            }
        }
    }
}

// ---------------------------------------------------------------------------
// Vectorized LN2: one wave per row (float4 per lane), 4 rows per block.
// ---------------------------------------------------------------------------
__global__ __launch_bounds__(256) void ln2v_kernel(
    const float* __restrict__ x, const float* __restrict__ f0,
    const float* __restrict__ f1,
    const float* __restrict__ g, const float* __restrict__ b,
    float* __restrict__ out)
{
    int row  = blockIdx.x * 4 + (threadIdx.x >> 6);
    int lane = threadIdx.x & 63;
    size_t base = (size_t)row * 256 + lane * 4;
    float4 xv = *(const float4*)(x + base);
    float4 av = *(const float4*)(f0 + base);
    float4 cv = *(const float4*)(f1 + base);
    float t0 = xv.x + av.x + cv.x;
    float t1 = xv.y + av.y + cv.y;
    float t2 = xv.z + av.z + cv.z;
    float t3 = xv.w + av.w + cv.w;
    float s  = t0 + t1 + t2 + t3;
    float ss = t0 * t0 + t1 * t1 + t2 * t2 + t3 * t3;
    #pragma unroll
    for (int m = 1; m < 64; m <<= 1) {
        s  += __shfl_xor(s,  m, 64);
        ss += __shfl_xor(ss, m, 64);
    }
    float mu = s * (1.f / 256.f);
    float rs = rsqrtf(ss * (1.f / 256.f) - mu * mu + 1e-5f);
    float4 gv = *(const float4*)(g + lane * 4);
    float4 bv = *(const float4*)(b + lane * 4);
    float4 o;
    o.x = (t0 - mu) * rs * gv.x + bv.x;
    o.y = (t1 - mu) * rs * gv.y + bv.y;
    o.z = (t2 - mu) * rs * gv.z + bv.z;
    o.w = (t3 - mu) * rs * gv.w + bv.w;
    *(float4*)(out + base) = o;
}

// ---------------------------------------------------------------------------
extern "C" void kernel_launch(void* const* d_in, const int* in_sizes, int n_in,
                              void* d_out, int out_size, void* d_ws, size_t ws_size,
                              hipStream_t stream)
{
    const float* query   = (const float*)d_in[0];
    const float* value   = (const float*)d_in[2];
    const float* refpts  = (const float*)d_in[3];
    const int*   bevmask = (const int*)d_in[6];
    const float* W_value = (const float*)d_in[7];
    const float* b_value = (const float*)d_in[8];
    const float* W_off   = (const float*)d_in[9];
    const float* b_off   = (const float*)d_in[10];
    const float* W_attn  = (const float*)d_in[11];
    const float* b_attn  = (const float*)d_in[12];
    const float* W_out   = (const float*)d_in[13];
    const float* b_out   = (const float*)d_in[14];
    const float* ln1_g   = (const float*)d_in[15];
    const float* ln1_b   = (const float*)d_in[16];
    const float* W1      = (const float*)d_in[17];
    const float* b1      = (const float*)d_in[18];
    const float* W2      = (const float*)d_in[19];
    const float* b2      = (const float*)d_in[20];
    const float* ln2_g   = (const float*)d_in[21];
    const float* ln2_b   = (const float*)d_in[22];
    float* out = (float*)d_out;

    // workspace layout (byte offsets, temporal aliasing):
    //  [0)          vb bf16 24,511,488      (head -> sample)
    //  [0)          xbuf fp32 6,553,600     (projln1 -> ln2)   [vb dead]
    //  [7,000,000)  xbf bf16 3,276,800      (projln1 -> ffn1)  [vb dead]
    //  [11,000,000) hbf bf16 13,107,200     (ffn1 -> ffn2)     [vb dead]
    //  [25,000,000) qoff fp32 6,553,600     (head -> sample)
    //  [32,000,000) qaw fp32 3,276,800      (head -> sample)
    //  [35,300,000) outsum bf16 3,276,800   (sample -> projln1)
    //  [38,600,000) visb 25,600             (sample -> projln1)
    //  [38,700,000) wsT bf16 1,507,328      (wt -> all GEMMs)
    //  [41,000,000) ffnout fp32 2x6,553,600 (ffn2 -> ln2)
    char* ws = (char*)d_ws;
    unsigned short* vb     = (unsigned short*)(ws + 0);
    float*          xbuf   = (float*)(ws + 0);
    unsigned short* xbf    = (unsigned short*)(ws + 7000000);
    unsigned short* hbf    = (unsigned short*)(ws + 11000000);
    float*          qoff   = (float*)(ws + 25000000);
    float*          qaw    = (float*)(ws + 32000000);
    unsigned short* outsum = (unsigned short*)(ws + 35300000);
    float*          visb   = (float*)(ws + 38600000);
    unsigned short* wsT    = (unsigned short*)(ws + 38700000);
    float*          ffnout = (float*)(ws + 41000000);

    unsigned short* WvT = wsT;            // [256][256]
    unsigned short* WqT = wsT + 65536;    // [384][256]
    unsigned short* WoT = wsT + 163840;   // [256][256]
    unsigned short* W1T = wsT + 229376;   // [1024][256]
    unsigned short* W2T = wsT + 491520;   // [256][1024]

    // L0: all weights -> transposed bf16
    wt_kernel<<<dim3(736), 256, 0, stream>>>(
        W_value, W_off, W_attn, W_out, W1, W2, wsT);
    // L1: value proj (750 blocks) + query proj (300 blocks)
    head_kernel<<<dim3(1050), 256, 0, stream>>>(
        value, query, WvT, WqT, b_value, b_off, b_attn, vb, qoff, qaw);
    // L2: head-partitioned sampling (packed tables)
    sample_kernel<<<dim3(3200), 256, 0, stream>>>(
        vb, qoff, qaw, refpts, bevmask, outsum, visb);
    // L3: x = LN(outsum@W_out + residual algebra)
    projln1_kernel<<<dim3(200), 256, 0, stream>>>(
        outsum, WoT, query, visb, b_out, ln1_g, ln1_b, xbuf, xbf);
    // L4: hbf = bf16(relu(x @ W1 + b1))
    gemm64_kernel<<<dim3(8, 100, 1), 256, 0, stream>>>(
        xbf, W1T, b1, nullptr, hbf, NQ, DFFN, 256, 1);
    // L5: ffnout[z] = h @ W2 (+b2 on z=0), split-K x2
    gemm64_kernel<<<dim3(2, 100, 2), 256, 0, stream>>>(
        hbf, W2T, b2, ffnout, nullptr, NQ, 256, DFFN, 0);
    // L6: out = LN(x + f0 + f1)
    ln2v_kernel<<<dim3(1600), 256, 0, stream>>>(
        xbuf, ffnout, ffnout + (size_t)NQ * 256, ln2_g, ln2_b, out);
}

// Round 10
// 301.125 us; speedup vs baseline: 1.0986x; 1.0248x over previous
//
#include <hip/hip_runtime.h>
#include <math.h>

#define NQ      6400
#define NCAMS   6
#define LTOT    7979
#define DM      256
#define DFFN    1024

typedef __attribute__((ext_vector_type(8))) short bf16x8;
typedef __attribute__((ext_vector_type(4))) float f32x4;
typedef __attribute__((ext_vector_type(2))) float f32x2;

__device__ inline unsigned short f32_to_bf16(float f) {
    unsigned u = __float_as_uint(f);
    unsigned r = u + 0x7FFF + ((u >> 16) & 1);   // round-to-nearest-even
    return (unsigned short)(r >> 16);
}

// ---------------------------------------------------------------------------
// Weight transpose + convert: WT[n][k] (bf16) = W[k][n] (fp32), all 5 weights.
// wsT layout (shorts): WvT@0, WqT@65536 ([384][256]), WoT@163840,
// W1T@229376 ([1024][256]), W2T@491520 ([256][1024]).
// ---------------------------------------------------------------------------
__global__ __launch_bounds__(256) void wt_kernel(
    const float* __restrict__ Wv, const float* __restrict__ Woff,
    const float* __restrict__ Wattn, const float* __restrict__ Wout,
    const float* __restrict__ W1, const float* __restrict__ W2,
    unsigned short* __restrict__ wsT)
{
    int b = blockIdx.x;
    const float* src; int K, N, t0, dstoff;
    if (b < 64)       { src = Wv;    K = 256;  N = 256;  t0 = 0;   dstoff = 0; }
    else if (b < 128) { src = Woff;  K = 256;  N = 256;  t0 = 64;  dstoff = 65536; }
    else if (b < 160) { src = Wattn; K = 256;  N = 128;  t0 = 128; dstoff = 131072; }
    else if (b < 224) { src = Wout;  K = 256;  N = 256;  t0 = 160; dstoff = 163840; }
    else if (b < 480) { src = W1;    K = 256;  N = 1024; t0 = 224; dstoff = 229376; }
    else              { src = W2;    K = 1024; N = 256;  t0 = 480; dstoff = 491520; }
    int t = b - t0;
    int ntn = N >> 5;
    int kt = t / ntn, nt = t - kt * ntn;
    __shared__ float tile[32][33];
    int tx = threadIdx.x & 31, ty = threadIdx.x >> 5;
    #pragma unroll
    for (int i = 0; i < 4; ++i)
        tile[ty + i * 8][tx] = src[(size_t)(kt * 32 + ty + i * 8) * N + nt * 32 + tx];
    __syncthreads();
    #pragma unroll
    for (int i = 0; i < 4; ++i) {
        int nn = nt * 32 + ty + i * 8;
        wsT[dstoff + (size_t)nn * K + kt * 32 + tx] = f32_to_bf16(tile[tx][ty + i * 8]);
    }
}

// ---------------------------------------------------------------------------
// head_kernel: merged value projection + query projections.
//  b <  750 : value proj (BM=BN=128) -> vb FP8 e4m3 head-major
//             (cam, head, pixel, 32ch), 32 B rows.
//  else     : query projections (BM=64): bx=0,1 -> qoff; bx=2 -> softmax->qaw
// ---------------------------------------------------------------------------
__global__ __launch_bounds__(256) void head_kernel(
    const float* __restrict__ value, const float* __restrict__ query,
    const unsigned short* __restrict__ WvT, const unsigned short* __restrict__ WqT,
    const float* __restrict__ bv, const float* __restrict__ boff,
    const float* __restrict__ battn,
    unsigned char* __restrict__ vb, float* __restrict__ qoff,
    float* __restrict__ qaw)
{
    __shared__ __align__(16) unsigned char smem[20480];
    const int b = blockIdx.x;
    const int tid = threadIdx.x;
    const int wave = tid >> 6, lane = tid & 63;
    const int wm = wave >> 1, wn = wave & 1;
    const int quad = lane >> 4, l16 = lane & 15;

    if (b < 750) {
        unsigned short (*As)[40] = (unsigned short(*)[40])smem;
        unsigned short (*Bs)[40] = (unsigned short(*)[40])(smem + 10240);
        const int m0 = (b >> 1) * 128, n0 = (b & 1) * 128;
        const int M = NCAMS * LTOT;

        f32x4 acc[4][4] = {};

        for (int k0 = 0; k0 < 256; k0 += 32) {
            #pragma unroll
            for (int i = 0; i < 2; ++i) {          // A: 128x32 fp32 -> bf16
                int idx = tid + 256 * i;
                int r = idx >> 2, kc = (idx & 3) * 8;
                int gr = m0 + r;
                float4 f0, f1;
                if (gr < M) {
                    f0 = *(const float4*)(value + (size_t)gr * 256 + k0 + kc);
                    f1 = *(const float4*)(value + (size_t)gr * 256 + k0 + kc + 4);
                } else { f0 = make_float4(0.f,0.f,0.f,0.f); f1 = f0; }
                uint4 o;
                o.x = f32_to_bf16(f0.x) | ((unsigned)f32_to_bf16(f0.y) << 16);
                o.y = f32_to_bf16(f0.z) | ((unsigned)f32_to_bf16(f0.w) << 16);
                o.z = f32_to_bf16(f1.x) | ((unsigned)f32_to_bf16(f1.y) << 16);
                o.w = f32_to_bf16(f1.z) | ((unsigned)f32_to_bf16(f1.w) << 16);
                *(uint4*)&As[r][kc] = o;
            }
            #pragma unroll
            for (int i = 0; i < 2; ++i) {          // B: WvT bf16, uint4
                int idx = tid + 256 * i;
                int r = idx >> 2, kc = (idx & 3) * 8;
                *(uint4*)&Bs[r][kc] = *(const uint4*)(WvT + (size_t)(n0 + r) * 256 + k0 + kc);
            }
            __syncthreads();
            bf16x8 af[4], bfr[4];
            #pragma unroll
            for (int mi = 0; mi < 4; ++mi)
                af[mi] = *(const bf16x8*)&As[wm * 64 + mi * 16 + l16][quad * 8];
            #pragma unroll
            for (int ni = 0; ni < 4; ++ni)
                bfr[ni] = *(const bf16x8*)&Bs[wn * 64 + ni * 16 + l16][quad * 8];
            #pragma unroll
            for (int mi = 0; mi < 4; ++mi)
                #pragma unroll
                for (int ni = 0; ni < 4; ++ni)
                    acc[mi][ni] = __builtin_amdgcn_mfma_f32_16x16x32_bf16(
                        af[mi], bfr[ni], acc[mi][ni], 0, 0, 0);
            __syncthreads();
        }

        #pragma unroll
        for (int mi = 0; mi < 4; ++mi) {
            #pragma unroll
            for (int r = 0; r < 4; ++r) {
                int gm = m0 + wm * 64 + mi * 16 + quad * 4 + r;
                if (gm >= M) continue;
                int cam = gm / LTOT;
                int pix = gm - cam * LTOT;
                #pragma unroll
                for (int ni = 0; ni < 4; ++ni) {
                    int gn = n0 + wn * 64 + ni * 16 + l16;
                    int head = gn >> 5, ch = gn & 31;
                    float v = acc[mi][ni][r] + bv[gn];
                    int p8 = __builtin_amdgcn_cvt_pk_fp8_f32(v, 0.f, 0, false);
                    vb[(((size_t)(cam * 8 + head)) * LTOT + pix) * 32 + ch] =
                        (unsigned char)(p8 & 0xFF);
                }
            }
        }
    } else {
        unsigned short (*As)[40] = (unsigned short(*)[40])smem;
        unsigned short (*Bs)[40] = (unsigned short(*)[40])(smem + 5120);
        const int t = b - 750;
        const int bx = t / 100, by = t % 100;
        const int m0 = by * 64, n0 = bx * 128;
        const int is_attn = (bx == 2);

        f32x4 acc[2][4] = {};

        for (int k0 = 0; k0 < 256; k0 += 32) {
            {                                       // A: 64x32 fp32 -> bf16
                int r = tid >> 2, kc = (tid & 3) * 8;
                float4 f0 = *(const float4*)(query + (size_t)(m0 + r) * 256 + k0 + kc);
                float4 f1 = *(const float4*)(query + (size_t)(m0 + r) * 256 + k0 + kc + 4);
                uint4 o;
                o.x = f32_to_bf16(f0.x) | ((unsigned)f32_to_bf16(f0.y) << 16);
                o.y = f32_to_bf16(f0.z) | ((unsigned)f32_to_bf16(f0.w) << 16);
                o.z = f32_to_bf16(f1.x) | ((unsigned)f32_to_bf16(f1.y) << 16);
                o.w = f32_to_bf16(f1.z) | ((unsigned)f32_to_bf16(f1.w) << 16);
                *(uint4*)&As[r][kc] = o;
            }
            #pragma unroll
            for (int i = 0; i < 2; ++i) {           // B: WqT bf16, uint4
                int idx = tid + 256 * i;
                int r = idx >> 2, kc = (idx & 3) * 8;
                *(uint4*)&Bs[r][kc] = *(const uint4*)(WqT + (size_t)(n0 + r) * 256 + k0 + kc);
            }
            __syncthreads();
            bf16x8 af[2], bfr[4];
            #pragma unroll
            for (int mi = 0; mi < 2; ++mi)
                af[mi] = *(const bf16x8*)&As[wm * 32 + mi * 16 + l16][quad * 8];
            #pragma unroll
            for (int ni = 0; ni < 4; ++ni)
                bfr[ni] = *(const bf16x8*)&Bs[wn * 64 + ni * 16 + l16][quad * 8];
            #pragma unroll
            for (int mi = 0; mi < 2; ++mi)
                #pragma unroll
                for (int ni = 0; ni < 4; ++ni)
                    acc[mi][ni] = __builtin_amdgcn_mfma_f32_16x16x32_bf16(
                        af[mi], bfr[ni], acc[mi][ni], 0, 0, 0);
            __syncthreads();
        }

        if (is_attn) {
            #pragma unroll
            for (int mi = 0; mi < 2; ++mi) {
                #pragma unroll
                for (int r = 0; r < 4; ++r) {
                    int gm = m0 + wm * 32 + mi * 16 + quad * 4 + r;
                    #pragma unroll
                    for (int ni = 0; ni < 4; ++ni) {
                        int gn = wn * 64 + ni * 16 + l16;
                        float v = acc[mi][ni][r] + battn[gn];
                        float mx = v;
                        #pragma unroll
                        for (int s = 1; s < 16; s <<= 1)
                            mx = fmaxf(mx, __shfl_xor(mx, s, 64));
                        float e = __expf(v - mx);
                        float sum = e;
                        #pragma unroll
                        for (int s = 1; s < 16; s <<= 1)
                            sum += __shfl_xor(sum, s, 64);
                        qaw[(size_t)gm * 128 + gn] = e / sum;
                    }
                }
            }
        } else {
            #pragma unroll
            for (int mi = 0; mi < 2; ++mi) {
                #pragma unroll
                for (int r = 0; r < 4; ++r) {
                    int gm = m0 + wm * 32 + mi * 16 + quad * 4 + r;
                    #pragma unroll
                    for (int ni = 0; ni < 4; ++ni) {
                        int gn = n0 + wn * 64 + ni * 16 + l16;
                        qoff[(size_t)gm * 256 + gn] = acc[mi][ni][r] + boff[gn];
                    }
                }
            }
        }
    }
}

// ---------------------------------------------------------------------------
// Head-partitioned deformable sampling, FP8 v (32 B rows). Packed corner
// tables (pix<<16 | bf16 weight), one ds_read_b128 per 4 corners.
// Gather: uint2 (8 fp8 ch) per lane, HW cvt_pk_f32_fp8 unpack.
// ---------------------------------------------------------------------------
__global__ __launch_bounds__(256) void sample_kernel(
    const unsigned char* __restrict__ vb,  // (6, 8, 7979, 32) fp8 e4m3
    const float* __restrict__ qoff,        // (6400, 256)
    const float* __restrict__ aw,          // (6400, 128)
    const float* __restrict__ refpts,      // (6, 1, 6400, 4, 2)
    const int*   __restrict__ bev_mask,    // (6, 1, 6400, 4)
    unsigned short* __restrict__ outsum,   // (6400, 256) bf16
    float* __restrict__ visb)              // (6400)
{
    const int bid = blockIdx.x;
    const int h   = bid & 7;
    const int q0  = (bid >> 3) * 16;
    const int tid = threadIdx.x;
    const int sq  = tid >> 4;
    const int tup = tid & 15;
    const int lvl = tup >> 2;
    const int n_s = q0 + sq;
    const int tg  = (tid >> 2) & 3;
    const int cg  = tid & 3;

    __shared__ unsigned s_tab[NCAMS][272][4];   // [cam][sq*17+tup][corner]
    __shared__ float s_vis[NCAMS][16];
    __shared__ int   s_cnt[NCAMS];
    __shared__ int   s_nvis[16];

    if (tid < 96) {
        int cam = tid >> 4, q = tid & 15;
        const int* bm = bev_mask + ((size_t)cam * NQ + q0 + q) * 4;
        s_vis[cam][q] = ((bm[0] + bm[1] + bm[2] + bm[3]) > 0) ? 1.f : 0.f;
    }
    __syncthreads();
    if (tid < NCAMS) {
        float s = 0.f;
        #pragma unroll
        for (int q = 0; q < 16; ++q) s += s_vis[tid][q];
        s_cnt[tid] = (int)s;
    }
    if (tid >= 32 && tid < 48) {
        int q = tid - 32;
        float s = 0.f;
        #pragma unroll
        for (int cam = 0; cam < NCAMS; ++cam) s += s_vis[cam][q];
        s_nvis[q] = (int)s;
    }

    const float my_aw = aw[(size_t)n_s * 128 + h * 16 + tup];
    const float offx  = qoff[(size_t)n_s * 256 + h * 32 + tup * 2];
    const float offy  = qoff[(size_t)n_s * 256 + h * 32 + tup * 2 + 1];
    const int Wl   = (lvl == 0) ? 100 : (lvl == 1) ? 50 : (lvl == 2) ? 25 : 13;
    const int Hl   = (lvl == 0) ? 60  : (lvl == 1) ? 30 : (lvl == 2) ? 15 : 8;
    const int base = (lvl == 0) ? 0   : (lvl == 1) ? 6000 : (lvl == 2) ? 7500 : 7875;
    const float dx = offx / (float)Wl;
    const float dy = offy / (float)Hl;
    const int tabi = sq * 17 + tup;

    float2 rp[NCAMS];
    #pragma unroll
    for (int k = 0; k < NCAMS; ++k)
        rp[k] = *(const float2*)(refpts + (((size_t)k * NQ + n_s) * 4 + lvl) * 2);
    __syncthreads();   // covers s_cnt/s_nvis writes

    #pragma unroll
    for (int k = 0; k < NCAMS; ++k) {
        float fx = (rp[k].x + dx) * (float)Wl - 0.5f;
        float fy = (rp[k].y + dy) * (float)Hl - 0.5f;
        float x0f = floorf(fx), y0f = floorf(fy);
        float lx = fx - x0f, ly = fy - y0f;
        int x0 = (int)x0f, y0 = (int)y0f;
        int x1 = x0 + 1, y1 = y0 + 1;
        float wb = my_aw * s_vis[k][sq];
        float w00 = (1.f - lx) * (1.f - ly) * wb;
        float w01 = lx * (1.f - ly) * wb;
        float w10 = (1.f - lx) * ly * wb;
        float w11 = lx * ly * wb;
        bool vx0 = (x0 >= 0) & (x0 < Wl), vx1 = (x1 >= 0) & (x1 < Wl);
        bool vy0 = (y0 >= 0) & (y0 < Hl), vy1 = (y1 >= 0) & (y1 < Hl);
        uint4 o;
        o.x = (vx0 & vy0) ? (((unsigned)(base + y0 * Wl + x0) << 16) | f32_to_bf16(w00)) : 0u;
        o.y = (vx1 & vy0) ? (((unsigned)(base + y0 * Wl + x1) << 16) | f32_to_bf16(w01)) : 0u;
        o.z = (vx0 & vy1) ? (((unsigned)(base + y1 * Wl + x0) << 16) | f32_to_bf16(w10)) : 0u;
        o.w = (vx1 & vy1) ? (((unsigned)(base + y1 * Wl + x1) << 16) | f32_to_bf16(w11)) : 0u;
        *(uint4*)&s_tab[k][tabi][0] = o;
    }
    __syncthreads();

    float a0 = 0.f, a1 = 0.f, a2 = 0.f, a3 = 0.f;
    float a4 = 0.f, a5 = 0.f, a6 = 0.f, a7 = 0.f;

    for (int k = 0; k < NCAMS; ++k) {
        if (s_cnt[k] == 0) continue;
        const char* vkh = (const char*)vb + (size_t)(k * 8 + h) * (LTOT * 32) + cg * 8;
        #pragma unroll
        for (int j = 0; j < 4; ++j) {
            uint4 t4 = *(const uint4*)&s_tab[k][sq * 17 + tg * 4 + j][0];
            #pragma unroll
            for (int corner = 0; corner < 4; ++corner) {
                unsigned tc = (corner == 0) ? t4.x : (corner == 1) ? t4.y
                            : (corner == 2) ? t4.z : t4.w;
                float w = __uint_as_float(tc << 16);
                uint2 d = *(const uint2*)(vkh + ((size_t)(tc >> 16) << 5));
                f32x2 p0 = __builtin_amdgcn_cvt_pk_f32_fp8(d.x, false);
                f32x2 p1 = __builtin_amdgcn_cvt_pk_f32_fp8(d.x, true);
                f32x2 p2 = __builtin_amdgcn_cvt_pk_f32_fp8(d.y, false);
                f32x2 p3 = __builtin_amdgcn_cvt_pk_f32_fp8(d.y, true);
                a0 += w * p0.x; a1 += w * p0.y;
                a2 += w * p1.x; a3 += w * p1.y;
                a4 += w * p2.x; a5 += w * p2.y;
                a6 += w * p3.x; a7 += w * p3.y;
            }
        }
    }

    a0 += __shfl_xor(a0, 4, 64); a0 += __shfl_xor(a0, 8, 64);
    a1 += __shfl_xor(a1, 4, 64); a1 += __shfl_xor(a1, 8, 64);
    a2 += __shfl_xor(a2, 4, 64); a2 += __shfl_xor(a2, 8, 64);
    a3 += __shfl_xor(a3, 4, 64); a3 += __shfl_xor(a3, 8, 64);
    a4 += __shfl_xor(a4, 4, 64); a4 += __shfl_xor(a4, 8, 64);
    a5 += __shfl_xor(a5, 4, 64); a5 += __shfl_xor(a5, 8, 64);
    a6 += __shfl_xor(a6, 4, 64); a6 += __shfl_xor(a6, 8, 64);
    a7 += __shfl_xor(a7, 4, 64); a7 += __shfl_xor(a7, 8, 64);

    if ((tid & 12) == 0) {
        int nv = s_nvis[sq];
        float sc = 1.f / (float)(nv > 0 ? nv : 1);
        uint4 o;
        o.x = f32_to_bf16(a0 * sc) | ((unsigned)f32_to_bf16(a1 * sc) << 16);
        o.y = f32_to_bf16(a2 * sc) | ((unsigned)f32_to_bf16(a3 * sc) << 16);
        o.z = f32_to_bf16(a4 * sc) | ((unsigned)f32_to_bf16(a5 * sc) << 16);
        o.w = f32_to_bf16(a6 * sc) | ((unsigned)f32_to_bf16(a7 * sc) << 16);
        *(uint4*)(outsum + (size_t)n_s * 256 + h * 32 + cg * 8) = o;
    }
    if (h == 0 && tid < 16) visb[q0 + tid] = (s_nvis[tid] > 0) ? 1.f : 0.f;
}

// ---------------------------------------------------------------------------
// Fused output-projection + residual + LN1. BM=32, BN=256, K=256.
// ---------------------------------------------------------------------------
__global__ __launch_bounds__(256) void projln1_kernel(
    const unsigned short* __restrict__ A, const unsigned short* __restrict__ BT,
    const float* __restrict__ query, const float* __restrict__ visb,
    const float* __restrict__ b_out, const float* __restrict__ g,
    const float* __restrict__ b,
    float* __restrict__ xout, unsigned short* __restrict__ xbf)
{
    const int K = 256;
    __shared__ __align__(16) unsigned short As[32][40];
    __shared__ __align__(16) unsigned short Bs[256][40];
    __shared__ float sred[2][4][4][2];
    __shared__ float ssred[2][4][4][2];
    __shared__ float s_mu[32], s_rs[32];

    const int tid  = threadIdx.x;
    const int wave = tid >> 6, lane = tid & 63;
    const int wm = wave >> 1, wn = wave & 1;
    const int quad = lane >> 4, l16 = lane & 15;
    const int m0 = blockIdx.x * 32;

    f32x4 acc[8] = {};

    for (int k0 = 0; k0 < K; k0 += 32) {
        {
            int r = tid >> 3, kc = (tid & 7) * 4;
            *(uint2*)&As[r][kc] = *(const uint2*)(A + (size_t)(m0 + r) * K + k0 + kc);
        }
        {
            const unsigned short* src = BT + (size_t)tid * K + k0;
            *(uint4*)&Bs[tid][0]  = *(const uint4*)(src);
            *(uint4*)&Bs[tid][8]  = *(const uint4*)(src + 8);
            *(uint4*)&Bs[tid][16] = *(const uint4*)(src + 16);
            *(uint4*)&Bs[tid][24] = *(const uint4*)(src + 24);
        }
        __syncthreads();
        bf16x8 af = *(const bf16x8*)&As[wm * 16 + l16][quad * 8];
        #pragma unroll
        for (int ni = 0; ni < 8; ++ni) {
            bf16x8 bfr = *(const bf16x8*)&Bs[wn * 128 + ni * 16 + l16][quad * 8];
            acc[ni] = __builtin_amdgcn_mfma_f32_16x16x32_bf16(af, bfr, acc[ni], 0, 0, 0);
        }
        __syncthreads();
    }

    float vals[8][4];
    #pragma unroll
    for (int r = 0; r < 4; ++r) {
        int gm = m0 + wm * 16 + quad * 4 + r;
        float vs = visb[gm];
        float s = 0.f, ss = 0.f;
        #pragma unroll
        for (int ni = 0; ni < 8; ++ni) {
            int gn = wn * 128 + ni * 16 + l16;
            float v = acc[ni][r] + vs * b_out[gn]
                    + query[(size_t)gm * 256 + gn] * (1.f + vs);
            vals[ni][r] = v;
            s += v; ss += v * v;
        }
        #pragma unroll
        for (int m = 1; m < 16; m <<= 1) {
            s  += __shfl_xor(s,  m, 64);
            ss += __shfl_xor(ss, m, 64);
        }
        if (l16 == 0) {
            sred[wm][quad][r][wn]  = s;
            ssred[wm][quad][r][wn] = ss;
        }
    }
    __syncthreads();
    if (tid < 32) {
        int lwm = tid >> 4, lq = (tid >> 2) & 3, lr = tid & 3;
        float s  = sred[lwm][lq][lr][0]  + sred[lwm][lq][lr][1];
        float ss = ssred[lwm][lq][lr][0] + ssred[lwm][lq][lr][1];
        float mu = s * (1.f / 256.f);
        float var = ss * (1.f / 256.f) - mu * mu;
        s_mu[tid] = mu;
        s_rs[tid] = rsqrtf(var + 1e-5f);
    }
    __syncthreads();

    #pragma unroll
    for (int r = 0; r < 4; ++r) {
        int rowl = wm * 16 + quad * 4 + r;
        int gm = m0 + rowl;
        float mu = s_mu[rowl], rs = s_rs[rowl];
        #pragma unroll
        for (int ni = 0; ni < 8; ++ni) {
            int gn = wn * 128 + ni * 16 + l16;
            float res = (vals[ni][r] - mu) * rs * g[gn] + b[gn];
            xout[(size_t)gm * 256 + gn] = res;
            xbf[(size_t)gm * 256 + gn] = f32_to_bf16(res);
        }
    }
}

// ---------------------------------------------------------------------------
// MFMA bf16 GEMM, BM=64 BN=128 BK=32, bf16 A + BT. Split-K over gridDim.z.
// mode 1: relu -> bf16 out; mode 2: plain bf16 out (split-K partials).
// ---------------------------------------------------------------------------
__global__ __launch_bounds__(256) void gemm64_kernel(
    const unsigned short* __restrict__ A, const unsigned short* __restrict__ BT,
    const float* __restrict__ bias, unsigned short* __restrict__ Cb,
    int M, int N, int K, int mode)
{
    __shared__ __align__(16) unsigned short As[64][40];
    __shared__ __align__(16) unsigned short Bs[128][40];

    const int tid  = threadIdx.x;
    const int wave = tid >> 6, lane = tid & 63;
    const int wm = wave >> 1, wn = wave & 1;
    const int quad = lane >> 4, l16 = lane & 15;
    const int m0 = blockIdx.y * 64, n0 = blockIdx.x * 128;
    const int nz = gridDim.z;
    const int klen = K / nz;
    const int kbase = blockIdx.z * klen;

    f32x4 acc[2][4] = {};

    for (int k0 = kbase; k0 < kbase + klen; k0 += 32) {
        {
            int r = tid >> 2, kc = (tid & 3) * 8;
            int gr = m0 + r;
            uint4 d = (gr < M) ? *(const uint4*)(A + (size_t)gr * K + k0 + kc)
                               : make_uint4(0u, 0u, 0u, 0u);
            *(uint4*)&As[r][kc] = d;
        }
        #pragma unroll
        for (int i = 0; i < 2; ++i) {
            int idx = tid + 256 * i;
            int r = idx >> 2, kc = (idx & 3) * 8;
            *(uint4*)&Bs[r][kc] = *(const uint4*)(BT + (size_t)(n0 + r) * K + k0 + kc);
        }
        __syncthreads();
        bf16x8 af[2], bfr[4];
        #pragma unroll
        for (int mi = 0; mi < 2; ++mi)
            af[mi] = *(const bf16x8*)&As[wm * 32 + mi * 16 + l16][quad * 8];
        #pragma unroll
        for (int ni = 0; ni < 4; ++ni)
            bfr[ni] = *(const bf16x8*)&Bs[wn * 64 + ni * 16 + l16][quad * 8];
        #pragma unroll
        for (int mi = 0; mi < 2; ++mi)
            #pragma unroll
            for (int ni = 0; ni < 4; ++ni)
                acc[mi][ni] = __builtin_amdgcn_mfma_f32_16x16x32_bf16(
                    af[mi], bfr[ni], acc[mi][ni], 0, 0, 0);
        __syncthreads();
    }

    const float* bz = (blockIdx.z == 0) ? bias : nullptr;
    unsigned short* Cz = Cb + (size_t)blockIdx.z * M * N;

    #pragma unroll
    for (int mi = 0; mi < 2; ++mi) {
        #pragma unroll
        for (int r = 0; r < 4; ++r) {
            int gm = m0 + wm * 32 + mi * 16 + quad * 4 + r;
            if (gm >= M) continue;
            #pragma unroll
            for (int ni = 0; ni < 4; ++ni) {
                int gn = n0 + wn * 64 + ni * 16 + l16;
                float v = acc[mi][ni][r] + (bz ? bz[gn] : 0.f);
                if (mode == 1) v = fmaxf(v, 0.f);
                Cz[(size_t)gm * N + gn] = f32_to_bf16(v);
            }
        }
    }
}

// ---------------------------------------------------------------------------
// Vectorized LN2: one wave per row; x fp32 + two bf16 split-K halves.
// ---------------------------------------------------------------------------
__global__ __launch_bounds__(256) void ln2v_kernel(
    const float* __restrict__ x, const unsigned short* __restrict__ f0,
    const unsigned short* __restrict__ f1,
    const float* __restrict__ g, const float* __restrict__ b,
    float* __restrict__ out)
{
    int row  = blockIdx.x * 4 + (threadIdx.x >> 6);
    int lane = threadIdx.x & 63;
    size_t base = (size_t)row * 256 + lane * 4;
    float4 xv = *(const float4*)(x + base);
    uint2 u0 = *(const uint2*)(f0 + base);
    uint2 u1 = *(const uint2*)(f1 + base);
    float t0 = xv.x + __uint_as_float(u0.x << 16)        + __uint_as_float(u1.x << 16);
    float t1 = xv.y + __uint_as_float(u0.x & 0xFFFF0000u) + __uint_as_float(u1.x & 0xFFFF0000u);
    float t2 = xv.z + __uint_as_float(u0.y << 16)        + __uint_as_float(u1.y << 16);
    float t3 = xv.w + __uint_as_float(u0.y & 0xFFFF0000u) + __uint_as_float(u1.y & 0xFFFF0000u);
    float s  = t0 + t1 + t2 + t3;
    float ss = t0 * t0 + t1 * t1 + t2 * t2 + t3 * t3;
    #pragma unroll
    for (int m = 1; m < 64; m <<= 1) {
        s  += __shfl_xor(s,  m, 64);
        ss += __shfl_xor(ss, m, 64);
    }
    float mu = s * (1.f / 256.f);
    float rs = rsqrtf(ss * (1.f / 256.f) - mu * mu + 1e-5f);
    float4 gv = *(const float4*)(g + lane * 4);
    float4 bv = *(const float4*)(b + lane * 4);
    float4 o;
    o.x = (t0 - mu) * rs * gv.x + bv.x;
    o.y = (t1 - mu) * rs * gv.y + bv.y;
    o.z = (t2 - mu) * rs * gv.z + bv.z;
    o.w = (t3 - mu) * rs * gv.w + bv.w;
    *(float4*)(out + base) = o;
}

// ---------------------------------------------------------------------------
extern "C" void kernel_launch(void* const* d_in, const int* in_sizes, int n_in,
                              void* d_out, int out_size, void* d_ws, size_t ws_size,
                              hipStream_t stream)
{
    const float* query   = (const float*)d_in[0];
    const float* value   = (const float*)d_in[2];
    const float* refpts  = (const float*)d_in[3];
    const int*   bevmask = (const int*)d_in[6];
    const float* W_value = (const float*)d_in[7];
    const float* b_value = (const float*)d_in[8];
    const float* W_off   = (const float*)d_in[9];
    const float* b_off   = (const float*)d_in[10];
    const float* W_attn  = (const float*)d_in[11];
    const float* b_attn  = (const float*)d_in[12];
    const float* W_out   = (const float*)d_in[13];
    const float* b_out   = (const float*)d_in[14];
    const float* ln1_g   = (const float*)d_in[15];
    const float* ln1_b   = (const float*)d_in[16];
    const float* W1      = (const float*)d_in[17];
    const float* b1      = (const float*)d_in[18];
    const float* W2      = (const float*)d_in[19];
    const float* b2      = (const float*)d_in[20];
    const float* ln2_g   = (const float*)d_in[21];
    const float* ln2_b   = (const float*)d_in[22];
    float* out = (float*)d_out;

    // workspace layout (byte offsets, temporal aliasing):
    //  [0)          vb fp8 12,255,744       (head -> sample)
    //  [0)          xbuf fp32 6,553,600     (projln1 -> ln2)   [vb dead]
    //  [7,000,000)  xbf bf16 3,276,800      (projln1 -> ffn1)  [vb dead]
    //  [13,000,000) hbf bf16 13,107,200     (ffn1 -> ffn2)
    //  [27,000,000) qoff fp32 6,553,600     (head -> sample)
    //  [34,000,000) qaw fp32 3,276,800      (head -> sample)
    //  [37,300,000) outsum bf16 3,276,800   (sample -> projln1)
    //  [40,600,000) visb 25,600             (sample -> projln1)
    //  [40,700,000) wsT bf16 1,507,328      (wt -> all GEMMs)
    //  [43,000,000) ffnout bf16 2x3,276,800 (ffn2 -> ln2)
    char* ws = (char*)d_ws;
    unsigned char*  vb     = (unsigned char*)(ws + 0);
    float*          xbuf   = (float*)(ws + 0);
    unsigned short* xbf    = (unsigned short*)(ws + 7000000);
    unsigned short* hbf    = (unsigned short*)(ws + 13000000);
    float*          qoff   = (float*)(ws + 27000000);
    float*          qaw    = (float*)(ws + 34000000);
    unsigned short* outsum = (unsigned short*)(ws + 37300000);
    float*          visb   = (float*)(ws + 40600000);
    unsigned short* wsT    = (unsigned short*)(ws + 40700000);
    unsigned short* ffnout = (unsigned short*)(ws + 43000000);

    unsigned short* WvT = wsT;            // [256][256]
    unsigned short* WqT = wsT + 65536;    // [384][256]
    unsigned short* WoT = wsT + 163840;   // [256][256]
    unsigned short* W1T = wsT + 229376;   // [1024][256]
    unsigned short* W2T = wsT + 491520;   // [256][1024]

    // L0: all weights -> transposed bf16
    wt_kernel<<<dim3(736), 256, 0, stream>>>(
        W_value, W_off, W_attn, W_out, W1, W2, wsT);
    // L1: value proj (750 blocks, fp8 out) + query proj (300 blocks)
    head_kernel<<<dim3(1050), 256, 0, stream>>>(
        value, query, WvT, WqT, b_value, b_off, b_attn, vb, qoff, qaw);
    // L2: head-partitioned sampling (fp8 v)
    sample_kernel<<<dim3(3200), 256, 0, stream>>>(
        vb, qoff, qaw, refpts, bevmask, outsum, visb);
    // L3: x = LN(outsum@W_out + residual algebra)
    projln1_kernel<<<dim3(200), 256, 0, stream>>>(
        outsum, WoT, query, visb, b_out, ln1_g, ln1_b, xbuf, xbf);
    // L4: hbf = bf16(relu(x @ W1 + b1))
    gemm64_kernel<<<dim3(8, 100, 1), 256, 0, stream>>>(
        xbf, W1T, b1, hbf, NQ, DFFN, 256, 1);
    // L5: ffnout[z] = bf16(h @ W2 (+b2 on z=0)), split-K x2
    gemm64_kernel<<<dim3(2, 100, 2), 256, 0, stream>>>(
        hbf, W2T, b2, ffnout, NQ, 256, DFFN, 2);
    // L6: out = LN(x + f0 + f1)
    ln2v_kernel<<<dim3(1600), 256, 0, stream>>>(
        xbuf, ffnout, ffnout + (size_t)NQ * 256, ln2_g, ln2_b, out);
}

// Round 11
// 293.419 us; speedup vs baseline: 1.1275x; 1.0263x over previous
//
#include <hip/hip_runtime.h>
#include <math.h>

#define NQ      6400
#define NCAMS   6
#define LTOT    7979
#define DM      256
#define DFFN    1024

typedef __attribute__((ext_vector_type(8))) short bf16x8;
typedef __attribute__((ext_vector_type(4))) float f32x4;
typedef __attribute__((ext_vector_type(2))) float f32x2;

__device__ inline unsigned short f32_to_bf16(float f) {
    unsigned u = __float_as_uint(f);
    unsigned r = u + 0x7FFF + ((u >> 16) & 1);   // round-to-nearest-even
    return (unsigned short)(r >> 16);
}

// ---------------------------------------------------------------------------
// wt_head: transpose+convert only the weights the head kernel needs.
// wsT layout (shorts): WvT@0, WqT@65536 ([384][256]). 160 blocks.
// ---------------------------------------------------------------------------
__global__ __launch_bounds__(256) void wt_head_kernel(
    const float* __restrict__ Wv, const float* __restrict__ Woff,
    const float* __restrict__ Wattn, unsigned short* __restrict__ wsT)
{
    int b = blockIdx.x;
    const float* src; int K, N, t0, dstoff;
    if (b < 64)       { src = Wv;    K = 256; N = 256; t0 = 0;   dstoff = 0; }
    else if (b < 128) { src = Woff;  K = 256; N = 256; t0 = 64;  dstoff = 65536; }
    else              { src = Wattn; K = 256; N = 128; t0 = 128; dstoff = 131072; }
    int t = b - t0;
    int ntn = N >> 5;
    int kt = t / ntn, nt = t - kt * ntn;
    __shared__ float tile[32][33];
    int tx = threadIdx.x & 31, ty = threadIdx.x >> 5;
    #pragma unroll
    for (int i = 0; i < 4; ++i)
        tile[ty + i * 8][tx] = src[(size_t)(kt * 32 + ty + i * 8) * N + nt * 32 + tx];
    __syncthreads();
    #pragma unroll
    for (int i = 0; i < 4; ++i) {
        int nn = nt * 32 + ty + i * 8;
        wsT[dstoff + (size_t)nn * K + kt * 32 + tx] = f32_to_bf16(tile[tx][ty + i * 8]);
    }
}

// ---------------------------------------------------------------------------
// head_kernel: merged value projection + query projections.
//  b <  750 : value proj (BM=BN=128) -> vb FP8 e4m3 head-major
//             (cam, head, pixel, 32ch), 32 B rows.
//  else     : query projections (BM=64): bx=0,1 -> qoff; bx=2 -> softmax->qaw
// ---------------------------------------------------------------------------
__global__ __launch_bounds__(256) void head_kernel(
    const float* __restrict__ value, const float* __restrict__ query,
    const unsigned short* __restrict__ WvT, const unsigned short* __restrict__ WqT,
    const float* __restrict__ bv, const float* __restrict__ boff,
    const float* __restrict__ battn,
    unsigned char* __restrict__ vb, float* __restrict__ qoff,
    float* __restrict__ qaw)
{
    __shared__ __align__(16) unsigned char smem[20480];
    const int b = blockIdx.x;
    const int tid = threadIdx.x;
    const int wave = tid >> 6, lane = tid & 63;
    const int wm = wave >> 1, wn = wave & 1;
    const int quad = lane >> 4, l16 = lane & 15;

    if (b < 750) {
        unsigned short (*As)[40] = (unsigned short(*)[40])smem;
        unsigned short (*Bs)[40] = (unsigned short(*)[40])(smem + 10240);
        const int m0 = (b >> 1) * 128, n0 = (b & 1) * 128;
        const int M = NCAMS * LTOT;

        f32x4 acc[4][4] = {};

        for (int k0 = 0; k0 < 256; k0 += 32) {
            #pragma unroll
            for (int i = 0; i < 2; ++i) {          // A: 128x32 fp32 -> bf16
                int idx = tid + 256 * i;
                int r = idx >> 2, kc = (idx & 3) * 8;
                int gr = m0 + r;
                float4 f0, f1;
                if (gr < M) {
                    f0 = *(const float4*)(value + (size_t)gr * 256 + k0 + kc);
                    f1 = *(const float4*)(value + (size_t)gr * 256 + k0 + kc + 4);
                } else { f0 = make_float4(0.f,0.f,0.f,0.f); f1 = f0; }
                uint4 o;
                o.x = f32_to_bf16(f0.x) | ((unsigned)f32_to_bf16(f0.y) << 16);
                o.y = f32_to_bf16(f0.z) | ((unsigned)f32_to_bf16(f0.w) << 16);
                o.z = f32_to_bf16(f1.x) | ((unsigned)f32_to_bf16(f1.y) << 16);
                o.w = f32_to_bf16(f1.z) | ((unsigned)f32_to_bf16(f1.w) << 16);
                *(uint4*)&As[r][kc] = o;
            }
            #pragma unroll
            for (int i = 0; i < 2; ++i) {          // B: WvT bf16, uint4
                int idx = tid + 256 * i;
                int r = idx >> 2, kc = (idx & 3) * 8;
                *(uint4*)&Bs[r][kc] = *(const uint4*)(WvT + (size_t)(n0 + r) * 256 + k0 + kc);
            }
            __syncthreads();
            bf16x8 af[4], bfr[4];
            #pragma unroll
            for (int mi = 0; mi < 4; ++mi)
                af[mi] = *(const bf16x8*)&As[wm * 64 + mi * 16 + l16][quad * 8];
            #pragma unroll
            for (int ni = 0; ni < 4; ++ni)
                bfr[ni] = *(const bf16x8*)&Bs[wn * 64 + ni * 16 + l16][quad * 8];
            #pragma unroll
            for (int mi = 0; mi < 4; ++mi)
                #pragma unroll
                for (int ni = 0; ni < 4; ++ni)
                    acc[mi][ni] = __builtin_amdgcn_mfma_f32_16x16x32_bf16(
                        af[mi], bfr[ni], acc[mi][ni], 0, 0, 0);
            __syncthreads();
        }

        #pragma unroll
        for (int mi = 0; mi < 4; ++mi) {
            #pragma unroll
            for (int r = 0; r < 4; ++r) {
                int gm = m0 + wm * 64 + mi * 16 + quad * 4 + r;
                if (gm >= M) continue;
                int cam = gm / LTOT;
                int pix = gm - cam * LTOT;
                #pragma unroll
                for (int ni = 0; ni < 4; ++ni) {
                    int gn = n0 + wn * 64 + ni * 16 + l16;
                    int head = gn >> 5, ch = gn & 31;
                    float v = acc[mi][ni][r] + bv[gn];
                    int p8 = __builtin_amdgcn_cvt_pk_fp8_f32(v, 0.f, 0, false);
                    vb[(((size_t)(cam * 8 + head)) * LTOT + pix) * 32 + ch] =
                        (unsigned char)(p8 & 0xFF);
                }
            }
        }
    } else {
        unsigned short (*As)[40] = (unsigned short(*)[40])smem;
        unsigned short (*Bs)[40] = (unsigned short(*)[40])(smem + 5120);
        const int t = b - 750;
        const int bx = t / 100, by = t % 100;
        const int m0 = by * 64, n0 = bx * 128;
        const int is_attn = (bx == 2);

        f32x4 acc[2][4] = {};

        for (int k0 = 0; k0 < 256; k0 += 32) {
            {                                       // A: 64x32 fp32 -> bf16
                int r = tid >> 2, kc = (tid & 3) * 8;
                float4 f0 = *(const float4*)(query + (size_t)(m0 + r) * 256 + k0 + kc);
                float4 f1 = *(const float4*)(query + (size_t)(m0 + r) * 256 + k0 + kc + 4);
                uint4 o;
                o.x = f32_to_bf16(f0.x) | ((unsigned)f32_to_bf16(f0.y) << 16);
                o.y = f32_to_bf16(f0.z) | ((unsigned)f32_to_bf16(f0.w) << 16);
                o.z = f32_to_bf16(f1.x) | ((unsigned)f32_to_bf16(f1.y) << 16);
                o.w = f32_to_bf16(f1.z) | ((unsigned)f32_to_bf16(f1.w) << 16);
                *(uint4*)&As[r][kc] = o;
            }
            #pragma unroll
            for (int i = 0; i < 2; ++i) {           // B: WqT bf16, uint4
                int idx = tid + 256 * i;
                int r = idx >> 2, kc = (idx & 3) * 8;
                *(uint4*)&Bs[r][kc] = *(const uint4*)(WqT + (size_t)(n0 + r) * 256 + k0 + kc);
            }
            __syncthreads();
            bf16x8 af[2], bfr[4];
            #pragma unroll
            for (int mi = 0; mi < 2; ++mi)
                af[mi] = *(const bf16x8*)&As[wm * 32 + mi * 16 + l16][quad * 8];
            #pragma unroll
            for (int ni = 0; ni < 4; ++ni)
                bfr[ni] = *(const bf16x8*)&Bs[wn * 64 + ni * 16 + l16][quad * 8];
            #pragma unroll
            for (int mi = 0; mi < 2; ++mi)
                #pragma unroll
                for (int ni = 0; ni < 4; ++ni)
                    acc[mi][ni] = __builtin_amdgcn_mfma_f32_16x16x32_bf16(
                        af[mi], bfr[ni], acc[mi][ni], 0, 0, 0);
            __syncthreads();
        }

        if (is_attn) {
            #pragma unroll
            for (int mi = 0; mi < 2; ++mi) {
                #pragma unroll
                for (int r = 0; r < 4; ++r) {
                    int gm = m0 + wm * 32 + mi * 16 + quad * 4 + r;
                    #pragma unroll
                    for (int ni = 0; ni < 4; ++ni) {
                        int gn = wn * 64 + ni * 16 + l16;
                        float v = acc[mi][ni][r] + battn[gn];
                        float mx = v;
                        #pragma unroll
                        for (int s = 1; s < 16; s <<= 1)
                            mx = fmaxf(mx, __shfl_xor(mx, s, 64));
                        float e = __expf(v - mx);
                        float sum = e;
                        #pragma unroll
                        for (int s = 1; s < 16; s <<= 1)
                            sum += __shfl_xor(sum, s, 64);
                        qaw[(size_t)gm * 128 + gn] = e / sum;
                    }
                }
            }
        } else {
            #pragma unroll
            for (int mi = 0; mi < 2; ++mi) {
                #pragma unroll
                for (int r = 0; r < 4; ++r) {
                    int gm = m0 + wm * 32 + mi * 16 + quad * 4 + r;
                    #pragma unroll
                    for (int ni = 0; ni < 4; ++ni) {
                        int gn = n0 + wn * 64 + ni * 16 + l16;
                        qoff[(size_t)gm * 256 + gn] = acc[mi][ni][r] + boff[gn];
                    }
                }
            }
        }
    }
}

// ---------------------------------------------------------------------------
// sample_kernel: b < 3200 -> head-partitioned fp8 deformable sampling with
// packed f32x2 (v_pk_fma) accumulation; b >= 3200 -> tail weight transpose
// (Wout/W1/W2 -> WoT/W1T/W2T), overlapped with the sampling tail.
// ---------------------------------------------------------------------------
__global__ __launch_bounds__(256) void sample_kernel(
    const unsigned char* __restrict__ vb,  // (6, 8, 7979, 32) fp8 e4m3
    const float* __restrict__ qoff,        // (6400, 256)
    const float* __restrict__ aw,          // (6400, 128)
    const float* __restrict__ refpts,      // (6, 1, 6400, 4, 2)
    const int*   __restrict__ bev_mask,    // (6, 1, 6400, 4)
    const float* __restrict__ Wout, const float* __restrict__ W1,
    const float* __restrict__ W2,
    unsigned short* __restrict__ outsum,   // (6400, 256) bf16
    float* __restrict__ visb,              // (6400)
    unsigned short* __restrict__ wsT)
{
    __shared__ unsigned s_tab[NCAMS][272][4];   // [cam][sq*17+tup][corner]
    __shared__ float s_vis[NCAMS][16];
    __shared__ int   s_cnt[NCAMS];
    __shared__ int   s_nvis[16];

    const int bid = blockIdx.x;
    const int tid = threadIdx.x;

    if (bid >= 3200) {
        // ---- tail weight transpose (reuses s_tab as the LDS tile) ----
        int t = bid - 3200;
        const float* src; int K, N, dstoff;
        if (t < 64)       { src = Wout; K = 256;  N = 256;  dstoff = 163840; }
        else if (t < 320) { src = W1;   K = 256;  N = 1024; dstoff = 229376; t -= 64; }
        else              { src = W2;   K = 1024; N = 256;  dstoff = 491520; t -= 320; }
        int ntn = N >> 5;
        int kt = t / ntn, nt = t - kt * ntn;
        float (*tile)[33] = (float(*)[33])&s_tab[0][0][0];
        int tx = tid & 31, ty = tid >> 5;
        #pragma unroll
        for (int i = 0; i < 4; ++i)
            tile[ty + i * 8][tx] = src[(size_t)(kt * 32 + ty + i * 8) * N + nt * 32 + tx];
        __syncthreads();
        #pragma unroll
        for (int i = 0; i < 4; ++i) {
            int nn = nt * 32 + ty + i * 8;
            wsT[dstoff + (size_t)nn * K + kt * 32 + tx] = f32_to_bf16(tile[tx][ty + i * 8]);
        }
        return;
    }

    const int h   = bid & 7;
    const int q0  = (bid >> 3) * 16;
    const int sq  = tid >> 4;
    const int tup = tid & 15;
    const int lvl = tup >> 2;
    const int n_s = q0 + sq;
    const int tg  = (tid >> 2) & 3;
    const int cg  = tid & 3;

    if (tid < 96) {
        int cam = tid >> 4, q = tid & 15;
        const int* bm = bev_mask + ((size_t)cam * NQ + q0 + q) * 4;
        s_vis[cam][q] = ((bm[0] + bm[1] + bm[2] + bm[3]) > 0) ? 1.f : 0.f;
    }
    __syncthreads();
    if (tid < NCAMS) {
        float s = 0.f;
        #pragma unroll
        for (int q = 0; q < 16; ++q) s += s_vis[tid][q];
        s_cnt[tid] = (int)s;
    }
    if (tid >= 32 && tid < 48) {
        int q = tid - 32;
        float s = 0.f;
        #pragma unroll
        for (int cam = 0; cam < NCAMS; ++cam) s += s_vis[cam][q];
        s_nvis[q] = (int)s;
    }

    const float my_aw = aw[(size_t)n_s * 128 + h * 16 + tup];
    const float offx  = qoff[(size_t)n_s * 256 + h * 32 + tup * 2];
    const float offy  = qoff[(size_t)n_s * 256 + h * 32 + tup * 2 + 1];
    const int Wl   = (lvl == 0) ? 100 : (lvl == 1) ? 50 : (lvl == 2) ? 25 : 13;
    const int Hl   = (lvl == 0) ? 60  : (lvl == 1) ? 30 : (lvl == 2) ? 15 : 8;
    const int base = (lvl == 0) ? 0   : (lvl == 1) ? 6000 : (lvl == 2) ? 7500 : 7875;
    const float dx = offx / (float)Wl;
    const float dy = offy / (float)Hl;
    const int tabi = sq * 17 + tup;

    float2 rp[NCAMS];
    #pragma unroll
    for (int k = 0; k < NCAMS; ++k)
        rp[k] = *(const float2*)(refpts + (((size_t)k * NQ + n_s) * 4 + lvl) * 2);
    __syncthreads();   // covers s_cnt/s_nvis writes

    #pragma unroll
    for (int k = 0; k < NCAMS; ++k) {
        float fx = (rp[k].x + dx) * (float)Wl - 0.5f;
        float fy = (rp[k].y + dy) * (float)Hl - 0.5f;
        float x0f = floorf(fx), y0f = floorf(fy);
        float lx = fx - x0f, ly = fy - y0f;
        int x0 = (int)x0f, y0 = (int)y0f;
        int x1 = x0 + 1, y1 = y0 + 1;
        float wb = my_aw * s_vis[k][sq];
        float w00 = (1.f - lx) * (1.f - ly) * wb;
        float w01 = lx * (1.f - ly) * wb;
        float w10 = (1.f - lx) * ly * wb;
        float w11 = lx * ly * wb;
        bool vx0 = (x0 >= 0) & (x0 < Wl), vx1 = (x1 >= 0) & (x1 < Wl);
        bool vy0 = (y0 >= 0) & (y0 < Hl), vy1 = (y1 >= 0) & (y1 < Hl);
        uint4 o;
        o.x = (vx0 & vy0) ? (((unsigned)(base + y0 * Wl + x0) << 16) | f32_to_bf16(w00)) : 0u;
        o.y = (vx1 & vy0) ? (((unsigned)(base + y0 * Wl + x1) << 16) | f32_to_bf16(w01)) : 0u;
        o.z = (vx0 & vy1) ? (((unsigned)(base + y1 * Wl + x0) << 16) | f32_to_bf16(w10)) : 0u;
        o.w = (vx1 & vy1) ? (((unsigned)(base + y1 * Wl + x1) << 16) | f32_to_bf16(w11)) : 0u;
        *(uint4*)&s_tab[k][tabi][0] = o;
    }
    __syncthreads();

    f32x2 a01 = {0.f, 0.f}, a23 = {0.f, 0.f};
    f32x2 a45 = {0.f, 0.f}, a67 = {0.f, 0.f};

    for (int k = 0; k < NCAMS; ++k) {
        if (s_cnt[k] == 0) continue;
        const char* vkh = (const char*)vb + (size_t)(k * 8 + h) * (LTOT * 32) + cg * 8;
        #pragma unroll
        for (int j = 0; j < 4; ++j) {
            uint4 t4 = *(const uint4*)&s_tab[k][sq * 17 + tg * 4 + j][0];
            #pragma unroll
            for (int corner = 0; corner < 4; ++corner) {
                unsigned tc = (corner == 0) ? t4.x : (corner == 1) ? t4.y
                            : (corner == 2) ? t4.z : t4.w;
                float w = __uint_as_float(tc << 16);
                f32x2 w2 = {w, w};
                uint2 d = *(const uint2*)(vkh + ((size_t)(tc >> 16) << 5));
                a01 += w2 * __builtin_amdgcn_cvt_pk_f32_fp8(d.x, false);
                a23 += w2 * __builtin_amdgcn_cvt_pk_f32_fp8(d.x, true);
                a45 += w2 * __builtin_amdgcn_cvt_pk_f32_fp8(d.y, false);
                a67 += w2 * __builtin_amdgcn_cvt_pk_f32_fp8(d.y, true);
            }
        }
    }

    float a0 = a01.x, a1 = a01.y, a2 = a23.x, a3 = a23.y;
    float a4 = a45.x, a5 = a45.y, a6 = a67.x, a7 = a67.y;

    a0 += __shfl_xor(a0, 4, 64); a0 += __shfl_xor(a0, 8, 64);
    a1 += __shfl_xor(a1, 4, 64); a1 += __shfl_xor(a1, 8, 64);
    a2 += __shfl_xor(a2, 4, 64); a2 += __shfl_xor(a2, 8, 64);
    a3 += __shfl_xor(a3, 4, 64); a3 += __shfl_xor(a3, 8, 64);
    a4 += __shfl_xor(a4, 4, 64); a4 += __shfl_xor(a4, 8, 64);
    a5 += __shfl_xor(a5, 4, 64); a5 += __shfl_xor(a5, 8, 64);
    a6 += __shfl_xor(a6, 4, 64); a6 += __shfl_xor(a6, 8, 64);
    a7 += __shfl_xor(a7, 4, 64); a7 += __shfl_xor(a7, 8, 64);

    if ((tid & 12) == 0) {
        int nv = s_nvis[sq];
        float sc = 1.f / (float)(nv > 0 ? nv : 1);
        uint4 o;
        o.x = f32_to_bf16(a0 * sc) | ((unsigned)f32_to_bf16(a1 * sc) << 16);
        o.y = f32_to_bf16(a2 * sc) | ((unsigned)f32_to_bf16(a3 * sc) << 16);
        o.z = f32_to_bf16(a4 * sc) | ((unsigned)f32_to_bf16(a5 * sc) << 16);
        o.w = f32_to_bf16(a6 * sc) | ((unsigned)f32_to_bf16(a7 * sc) << 16);
        *(uint4*)(outsum + (size_t)n_s * 256 + h * 32 + cg * 8) = o;
    }
    if (h == 0 && tid < 16) visb[q0 + tid] = (s_nvis[tid] > 0) ? 1.f : 0.f;
}

// ---------------------------------------------------------------------------
// Fused output-projection + residual + LN1. BM=32, BN=256, K=256.
// ---------------------------------------------------------------------------
__global__ __launch_bounds__(256) void projln1_kernel(
    const unsigned short* __restrict__ A, const unsigned short* __restrict__ BT,
    const float* __restrict__ query, const float* __restrict__ visb,
    const float* __restrict__ b_out, const float* __restrict__ g,
    const float* __restrict__ b,
    float* __restrict__ xout, unsigned short* __restrict__ xbf)
{
    const int K = 256;
    __shared__ __align__(16) unsigned short As[32][40];
    __shared__ __align__(16) unsigned short Bs[256][40];
    __shared__ float sred[2][4][4][2];
    __shared__ float ssred[2][4][4][2];
    __shared__ float s_mu[32], s_rs[32];

    const int tid  = threadIdx.x;
    const int wave = tid >> 6, lane = tid & 63;
    const int wm = wave >> 1, wn = wave & 1;
    const int quad = lane >> 4, l16 = lane & 15;
    const int m0 = blockIdx.x * 32;

    f32x4 acc[8] = {};

    for (int k0 = 0; k0 < K; k0 += 32) {
        {
            int r = tid >> 3, kc = (tid & 7) * 4;
            *(uint2*)&As[r][kc] = *(const uint2*)(A + (size_t)(m0 + r) * K + k0 + kc);
        }
        {
            const unsigned short* src = BT + (size_t)tid * K + k0;
            *(uint4*)&Bs[tid][0]  = *(const uint4*)(src);
            *(uint4*)&Bs[tid][8]  = *(const uint4*)(src + 8);
            *(uint4*)&Bs[tid][16] = *(const uint4*)(src + 16);
            *(uint4*)&Bs[tid][24] = *(const uint4*)(src + 24);
        }
        __syncthreads();
        bf16x8 af = *(const bf16x8*)&As[wm * 16 + l16][quad * 8];
        #pragma unroll
        for (int ni = 0; ni < 8; ++ni) {
            bf16x8 bfr = *(const bf16x8*)&Bs[wn * 128 + ni * 16 + l16][quad * 8];
            acc[ni] = __builtin_amdgcn_mfma_f32_16x16x32_bf16(af, bfr, acc[ni], 0, 0, 0);
        }
        __syncthreads();
    }

    float vals[8][4];
    #pragma unroll
    for (int r = 0; r < 4; ++r) {
        int gm = m0 + wm * 16 + quad * 4 + r;
        float vs = visb[gm];
        float s = 0.f, ss = 0.f;
        #pragma unroll
        for (int ni = 0; ni < 8; ++ni) {
            int gn = wn * 128 + ni * 16 + l16;
            float v = acc[ni][r] + vs * b_out[gn]
                    + query[(size_t)gm * 256 + gn] * (1.f + vs);
            vals[ni][r] = v;
            s += v; ss += v * v;
        }
        #pragma unroll
        for (int m = 1; m < 16; m <<= 1) {
            s  += __shfl_xor(s,  m, 64);
            ss += __shfl_xor(ss, m, 64);
        }
        if (l16 == 0) {
            sred[wm][quad][r][wn]  = s;
            ssred[wm][quad][r][wn] = ss;
        }
    }
    __syncthreads();
    if (tid < 32) {
        int lwm = tid >> 4, lq = (tid >> 2) & 3, lr = tid & 3;
        float s  = sred[lwm][lq][lr][0]  + sred[lwm][lq][lr][1];
        float ss = ssred[lwm][lq][lr][0] + ssred[lwm][lq][lr][1];
        float mu = s * (1.f / 256.f);
        float var = ss * (1.f / 256.f) - mu * mu;
        s_mu[tid] = mu;
        s_rs[tid] = rsqrtf(var + 1e-5f);
    }
    __syncthreads();

    #pragma unroll
    for (int r = 0; r < 4; ++r) {
        int rowl = wm * 16 + quad * 4 + r;
        int gm = m0 + rowl;
        float mu = s_mu[rowl], rs = s_rs[rowl];
        #pragma unroll
        for (int ni = 0; ni < 8; ++ni) {
            int gn = wn * 128 + ni * 16 + l16;
            float res = (vals[ni][r] - mu) * rs * g[gn] + b[gn];
            xout[(size_t)gm * 256 + gn] = res;
            xbf[(size_t)gm * 256 + gn] = f32_to_bf16(res);
        }
    }
}

// ---------------------------------------------------------------------------
// MFMA bf16 GEMM, BM=64 BN=128 BK=32, bf16 A + BT. Split-K over gridDim.z.
// mode 1: relu -> bf16 out; mode 2: plain bf16 out (split-K partials).
// ---------------------------------------------------------------------------
__global__ __launch_bounds__(256) void gemm64_kernel(
    const unsigned short* __restrict__ A, const unsigned short* __restrict__ BT,
    const float* __restrict__ bias, unsigned short* __restrict__ Cb,
    int M, int N, int K, int mode)
{
    __shared__ __align__(16) unsigned short As[64][40];
    __shared__ __align__(16) unsigned short Bs[128][40];

    const int tid  = threadIdx.x;
    const int wave = tid >> 6, lane = tid & 63;
    const int wm = wave >> 1, wn = wave & 1;
    const int quad = lane >> 4, l16 = lane & 15;
    const int m0 = blockIdx.y * 64, n0 = blockIdx.x * 128;
    const int nz = gridDim.z;
    const int klen = K / nz;
    const int kbase = blockIdx.z * klen;

    f32x4 acc[2][4] = {};

    for (int k0 = kbase; k0 < kbase + klen; k0 += 32) {
        {
            int r = tid >> 2, kc = (tid & 3) * 8;
            int gr = m0 + r;
            uint4 d = (gr < M) ? *(const uint4*)(A + (size_t)gr * K + k0 + kc)
                               : make_uint4(0u, 0u, 0u, 0u);
            *(uint4*)&As[r][kc] = d;
        }
        #pragma unroll
        for (int i = 0; i < 2; ++i) {
            int idx = tid + 256 * i;
            int r = idx >> 2, kc = (idx & 3) * 8;
            *(uint4*)&Bs[r][kc] = *(const uint4*)(BT + (size_t)(n0 + r) * K + k0 + kc);
        }
        __syncthreads();
        bf16x8 af[2], bfr[4];
        #pragma unroll
        for (int mi = 0; mi < 2; ++mi)
            af[mi] = *(const bf16x8*)&As[wm * 32 + mi * 16 + l16][quad * 8];
        #pragma unroll
        for (int ni = 0; ni < 4; ++ni)
            bfr[ni] = *(const bf16x8*)&Bs[wn * 64 + ni * 16 + l16][quad * 8];
        #pragma unroll
        for (int mi = 0; mi < 2; ++mi)
            #pragma unroll
            for (int ni = 0; ni < 4; ++ni)
                acc[mi][ni] = __builtin_amdgcn_mfma_f32_16x16x32_bf16(
                    af[mi], bfr[ni], acc[mi][ni], 0, 0, 0);
        __syncthreads();
    }

    const float* bz = (blockIdx.z == 0) ? bias : nullptr;
    unsigned short* Cz = Cb + (size_t)blockIdx.z * M * N;

    #pragma unroll
    for (int mi = 0; mi < 2; ++mi) {
        #pragma unroll
        for (int r = 0; r < 4; ++r) {
            int gm = m0 + wm * 32 + mi * 16 + quad * 4 + r;
            if (gm >= M) continue;
            #pragma unroll
            for (int ni = 0; ni < 4; ++ni) {
                int gn = n0 + wn * 64 + ni * 16 + l16;
                float v = acc[mi][ni][r] + (bz ? bz[gn] : 0.f);
                if (mode == 1) v = fmaxf(v, 0.f);
                Cz[(size_t)gm * N + gn] = f32_to_bf16(v);
            }
        }
    }
}

// ---------------------------------------------------------------------------
// Vectorized LN2: one wave per row; x fp32 + two bf16 split-K halves.
// ---------------------------------------------------------------------------
__global__ __launch_bounds__(256) void ln2v_kernel(
    const float* __restrict__ x, const unsigned short* __restrict__ f0,
    const unsigned short* __restrict__ f1,
    const float* __restrict__ g, const float* __restrict__ b,
    float* __restrict__ out)
{
    int row  = blockIdx.x * 4 + (threadIdx.x >> 6);
    int lane = threadIdx.x & 63;
    size_t base = (size_t)row * 256 + lane * 4;
    float4 xv = *(const float4*)(x + base);
    uint2 u0 = *(const uint2*)(f0 + base);
    uint2 u1 = *(const uint2*)(f1 + base);
    float t0 = xv.x + __uint_as_float(u0.x << 16)        + __uint_as_float(u1.x << 16);
    float t1 = xv.y + __uint_as_float(u0.x & 0xFFFF0000u) + __uint_as_float(u1.x & 0xFFFF0000u);
    float t2 = xv.z + __uint_as_float(u0.y << 16)        + __uint_as_float(u1.y << 16);
    float t3 = xv.w + __uint_as_float(u0.y & 0xFFFF0000u) + __uint_as_float(u1.y & 0xFFFF0000u);
    float s  = t0 + t1 + t2 + t3;
    float ss = t0 * t0 + t1 * t1 + t2 * t2 + t3 * t3;
    #pragma unroll
    for (int m = 1; m < 64; m <<= 1) {
        s  += __shfl_xor(s,  m, 64);
        ss += __shfl_xor(ss, m, 64);
    }
    float mu = s * (1.f / 256.f);
    float rs = rsqrtf(ss * (1.f / 256.f) - mu * mu + 1e-5f);
    float4 gv = *(const float4*)(g + lane * 4);
    float4 bv = *(const float4*)(b + lane * 4);
    float4 o;
    o.x = (t0 - mu) * rs * gv.x + bv.x;
    o.y = (t1 - mu) * rs * gv.y + bv.y;
    o.z = (t2 - mu) * rs * gv.z + bv.z;
    o.w = (t3 - mu) * rs * gv.w + bv.w;
    *(float4*)(out + base) = o;
}

// ---------------------------------------------------------------------------
extern "C" void kernel_launch(void* const* d_in, const int* in_sizes, int n_in,
                              void* d_out, int out_size, void* d_ws, size_t ws_size,
                              hipStream_t stream)
{
    const float* query   = (const float*)d_in[0];
    const float* value   = (const float*)d_in[2];
    const float* refpts  = (const float*)d_in[3];
    const int*   bevmask = (const int*)d_in[6];
    const float* W_value = (const float*)d_in[7];
    const float* b_value = (const float*)d_in[8];
    const float* W_off   = (const float*)d_in[9];
    const float* b_off   = (const float*)d_in[10];
    const float* W_attn  = (const float*)d_in[11];
    const float* b_attn  = (const float*)d_in[12];
    const float* W_out   = (const float*)d_in[13];
    const float* b_out   = (const float*)d_in[14];
    const float* ln1_g   = (const float*)d_in[15];
    const float* ln1_b   = (const float*)d_in[16];
    const float* W1      = (const float*)d_in[17];
    const float* b1      = (const float*)d_in[18];
    const float* W2      = (const float*)d_in[19];
    const float* b2      = (const float*)d_in[20];
    const float* ln2_g   = (const float*)d_in[21];
    const float* ln2_b   = (const float*)d_in[22];
    float* out = (float*)d_out;

    // workspace layout (byte offsets, temporal aliasing):
    //  [0)          vb fp8 12,255,744       (head -> sample)
    //  [0)          xbuf fp32 6,553,600     (projln1 -> ln2)   [vb dead]
    //  [7,000,000)  xbf bf16 3,276,800      (projln1 -> ffn1)  [vb dead]
    //  [13,000,000) hbf bf16 13,107,200     (ffn1 -> ffn2)
    //  [27,000,000) qoff fp32 6,553,600     (head -> sample)
    //  [34,000,000) qaw fp32 3,276,800      (head -> sample)
    //  [37,300,000) outsum bf16 3,276,800   (sample -> projln1)
    //  [40,600,000) visb 25,600             (sample -> projln1)
    //  [40,700,000) wsT bf16 1,507,328      (wt_head/sample-tail -> GEMMs)
    //  [43,000,000) ffnout bf16 2x3,276,800 (ffn2 -> ln2)
    char* ws = (char*)d_ws;
    unsigned char*  vb     = (unsigned char*)(ws + 0);
    float*          xbuf   = (float*)(ws + 0);
    unsigned short* xbf    = (unsigned short*)(ws + 7000000);
    unsigned short* hbf    = (unsigned short*)(ws + 13000000);
    float*          qoff   = (float*)(ws + 27000000);
    float*          qaw    = (float*)(ws + 34000000);
    unsigned short* outsum = (unsigned short*)(ws + 37300000);
    float*          visb   = (float*)(ws + 40600000);
    unsigned short* wsT    = (unsigned short*)(ws + 40700000);
    unsigned short* ffnout = (unsigned short*)(ws + 43000000);

    unsigned short* WvT = wsT;            // [256][256]
    unsigned short* WqT = wsT + 65536;    // [384][256]
    unsigned short* WoT = wsT + 163840;   // [256][256]
    unsigned short* W1T = wsT + 229376;   // [1024][256]
    unsigned short* W2T = wsT + 491520;   // [256][1024]

    // L0: head-side weights -> transposed bf16 (160 blocks)
    wt_head_kernel<<<dim3(160), 256, 0, stream>>>(
        W_value, W_off, W_attn, wsT);
    // L1: value proj (750 blocks, fp8 out) + query proj (300 blocks)
    head_kernel<<<dim3(1050), 256, 0, stream>>>(
        value, query, WvT, WqT, b_value, b_off, b_attn, vb, qoff, qaw);
    // L2: sampling (3200) + tail weight transpose (576, overlapped)
    sample_kernel<<<dim3(3776), 256, 0, stream>>>(
        vb, qoff, qaw, refpts, bevmask, W_out, W1, W2, outsum, visb, wsT);
    // L3: x = LN(outsum@W_out + residual algebra)
    projln1_kernel<<<dim3(200), 256, 0, stream>>>(
        outsum, WoT, query, visb, b_out, ln1_g, ln1_b, xbuf, xbf);
    // L4: hbf = bf16(relu(x @ W1 + b1))
    gemm64_kernel<<<dim3(8, 100, 1), 256, 0, stream>>>(
        xbf, W1T, b1, hbf, NQ, DFFN, 256, 1);
    // L5: ffnout[z] = bf16(h @ W2 (+b2 on z=0)), split-K x2
    gemm64_kernel<<<dim3(2, 100, 2), 256, 0, stream>>>(
        hbf, W2T, b2, ffnout, NQ, 256, DFFN, 2);
    // L6: out = LN(x + f0 + f1)
    ln2v_kernel<<<dim3(1600), 256, 0, stream>>>(
        xbuf, ffnout, ffnout + (size_t)NQ * 256, ln2_g, ln2_b, out);
}

// Round 12
// 291.656 us; speedup vs baseline: 1.1343x; 1.0060x over previous
//
#include <hip/hip_runtime.h>
#include <math.h>

#define NQ      6400
#define NCAMS   6
#define LTOT    7979
#define DM      256
#define DFFN    1024

typedef __attribute__((ext_vector_type(8))) short bf16x8;
typedef __attribute__((ext_vector_type(4))) float f32x4;
typedef __attribute__((ext_vector_type(2))) float f32x2;

__device__ inline unsigned short f32_to_bf16(float f) {
    unsigned u = __float_as_uint(f);
    unsigned r = u + 0x7FFF + ((u >> 16) & 1);   // round-to-nearest-even
    return (unsigned short)(r >> 16);
}

// ---------------------------------------------------------------------------
// wt_head: transpose+convert only the weights the head kernel needs.
// wsT layout (shorts): WvT@0, WqT@65536 ([384][256]). 160 blocks.
// ---------------------------------------------------------------------------
__global__ __launch_bounds__(256) void wt_head_kernel(
    const float* __restrict__ Wv, const float* __restrict__ Woff,
    const float* __restrict__ Wattn, unsigned short* __restrict__ wsT)
{
    int b = blockIdx.x;
    const float* src; int K, N, t0, dstoff;
    if (b < 64)       { src = Wv;    K = 256; N = 256; t0 = 0;   dstoff = 0; }
    else if (b < 128) { src = Woff;  K = 256; N = 256; t0 = 64;  dstoff = 65536; }
    else              { src = Wattn; K = 256; N = 128; t0 = 128; dstoff = 131072; }
    int t = b - t0;
    int ntn = N >> 5;
    int kt = t / ntn, nt = t - kt * ntn;
    __shared__ float tile[32][33];
    int tx = threadIdx.x & 31, ty = threadIdx.x >> 5;
    #pragma unroll
    for (int i = 0; i < 4; ++i)
        tile[ty + i * 8][tx] = src[(size_t)(kt * 32 + ty + i * 8) * N + nt * 32 + tx];
    __syncthreads();
    #pragma unroll
    for (int i = 0; i < 4; ++i) {
        int nn = nt * 32 + ty + i * 8;
        wsT[dstoff + (size_t)nn * K + kt * 32 + tx] = f32_to_bf16(tile[tx][ty + i * 8]);
    }
}

// ---------------------------------------------------------------------------
// head_kernel: merged value projection + query projections.
//  b <  750 : value proj (BM=BN=128) -> vb FP8 e4m3 head-major
//             (cam, head, pixel, 32ch), 32 B rows.
//  else     : query projections (BM=64): bx=0,1 -> qoff (bf16);
//             bx=2 -> softmax -> qaw (bf16)
// ---------------------------------------------------------------------------
__global__ __launch_bounds__(256) void head_kernel(
    const float* __restrict__ value, const float* __restrict__ query,
    const unsigned short* __restrict__ WvT, const unsigned short* __restrict__ WqT,
    const float* __restrict__ bv, const float* __restrict__ boff,
    const float* __restrict__ battn,
    unsigned char* __restrict__ vb, unsigned short* __restrict__ qoffb,
    unsigned short* __restrict__ qawb)
{
    __shared__ __align__(16) unsigned char smem[20480];
    const int b = blockIdx.x;
    const int tid = threadIdx.x;
    const int wave = tid >> 6, lane = tid & 63;
    const int wm = wave >> 1, wn = wave & 1;
    const int quad = lane >> 4, l16 = lane & 15;

    if (b < 750) {
        unsigned short (*As)[40] = (unsigned short(*)[40])smem;
        unsigned short (*Bs)[40] = (unsigned short(*)[40])(smem + 10240);
        const int m0 = (b >> 1) * 128, n0 = (b & 1) * 128;
        const int M = NCAMS * LTOT;

        f32x4 acc[4][4] = {};

        for (int k0 = 0; k0 < 256; k0 += 32) {
            #pragma unroll
            for (int i = 0; i < 2; ++i) {          // A: 128x32 fp32 -> bf16
                int idx = tid + 256 * i;
                int r = idx >> 2, kc = (idx & 3) * 8;
                int gr = m0 + r;
                float4 f0, f1;
                if (gr < M) {
                    f0 = *(const float4*)(value + (size_t)gr * 256 + k0 + kc);
                    f1 = *(const float4*)(value + (size_t)gr * 256 + k0 + kc + 4);
                } else { f0 = make_float4(0.f,0.f,0.f,0.f); f1 = f0; }
                uint4 o;
                o.x = f32_to_bf16(f0.x) | ((unsigned)f32_to_bf16(f0.y) << 16);
                o.y = f32_to_bf16(f0.z) | ((unsigned)f32_to_bf16(f0.w) << 16);
                o.z = f32_to_bf16(f1.x) | ((unsigned)f32_to_bf16(f1.y) << 16);
                o.w = f32_to_bf16(f1.z) | ((unsigned)f32_to_bf16(f1.w) << 16);
                *(uint4*)&As[r][kc] = o;
            }
            #pragma unroll
            for (int i = 0; i < 2; ++i) {          // B: WvT bf16, uint4
                int idx = tid + 256 * i;
                int r = idx >> 2, kc = (idx & 3) * 8;
                *(uint4*)&Bs[r][kc] = *(const uint4*)(WvT + (size_t)(n0 + r) * 256 + k0 + kc);
            }
            __syncthreads();
            bf16x8 af[4], bfr[4];
            #pragma unroll
            for (int mi = 0; mi < 4; ++mi)
                af[mi] = *(const bf16x8*)&As[wm * 64 + mi * 16 + l16][quad * 8];
            #pragma unroll
            for (int ni = 0; ni < 4; ++ni)
                bfr[ni] = *(const bf16x8*)&Bs[wn * 64 + ni * 16 + l16][quad * 8];
            #pragma unroll
            for (int mi = 0; mi < 4; ++mi)
                #pragma unroll
                for (int ni = 0; ni < 4; ++ni)
                    acc[mi][ni] = __builtin_amdgcn_mfma_f32_16x16x32_bf16(
                        af[mi], bfr[ni], acc[mi][ni], 0, 0, 0);
            __syncthreads();
        }

        #pragma unroll
        for (int mi = 0; mi < 4; ++mi) {
            #pragma unroll
            for (int r = 0; r < 4; ++r) {
                int gm = m0 + wm * 64 + mi * 16 + quad * 4 + r;
                if (gm >= M) continue;
                int cam = gm / LTOT;
                int pix = gm - cam * LTOT;
                #pragma unroll
                for (int ni = 0; ni < 4; ++ni) {
                    int gn = n0 + wn * 64 + ni * 16 + l16;
                    int head = gn >> 5, ch = gn & 31;
                    float v = acc[mi][ni][r] + bv[gn];
                    int p8 = __builtin_amdgcn_cvt_pk_fp8_f32(v, 0.f, 0, false);
                    vb[(((size_t)(cam * 8 + head)) * LTOT + pix) * 32 + ch] =
                        (unsigned char)(p8 & 0xFF);
                }
            }
        }
    } else {
        unsigned short (*As)[40] = (unsigned short(*)[40])smem;
        unsigned short (*Bs)[40] = (unsigned short(*)[40])(smem + 5120);
        const int t = b - 750;
        const int bx = t / 100, by = t % 100;
        const int m0 = by * 64, n0 = bx * 128;
        const int is_attn = (bx == 2);

        f32x4 acc[2][4] = {};

        for (int k0 = 0; k0 < 256; k0 += 32) {
            {                                       // A: 64x32 fp32 -> bf16
                int r = tid >> 2, kc = (tid & 3) * 8;
                float4 f0 = *(const float4*)(query + (size_t)(m0 + r) * 256 + k0 + kc);
                float4 f1 = *(const float4*)(query + (size_t)(m0 + r) * 256 + k0 + kc + 4);
                uint4 o;
                o.x = f32_to_bf16(f0.x) | ((unsigned)f32_to_bf16(f0.y) << 16);
                o.y = f32_to_bf16(f0.z) | ((unsigned)f32_to_bf16(f0.w) << 16);
                o.z = f32_to_bf16(f1.x) | ((unsigned)f32_to_bf16(f1.y) << 16);
                o.w = f32_to_bf16(f1.z) | ((unsigned)f32_to_bf16(f1.w) << 16);
                *(uint4*)&As[r][kc] = o;
            }
            #pragma unroll
            for (int i = 0; i < 2; ++i) {           // B: WqT bf16, uint4
                int idx = tid + 256 * i;
                int r = idx >> 2, kc = (idx & 3) * 8;
                *(uint4*)&Bs[r][kc] = *(const uint4*)(WqT + (size_t)(n0 + r) * 256 + k0 + kc);
            }
            __syncthreads();
            bf16x8 af[2], bfr[4];
            #pragma unroll
            for (int mi = 0; mi < 2; ++mi)
                af[mi] = *(const bf16x8*)&As[wm * 32 + mi * 16 + l16][quad * 8];
            #pragma unroll
            for (int ni = 0; ni < 4; ++ni)
                bfr[ni] = *(const bf16x8*)&Bs[wn * 64 + ni * 16 + l16][quad * 8];
            #pragma unroll
            for (int mi = 0; mi < 2; ++mi)
                #pragma unroll
                for (int ni = 0; ni < 4; ++ni)
                    acc[mi][ni] = __builtin_amdgcn_mfma_f32_16x16x32_bf16(
                        af[mi], bfr[ni], acc[mi][ni], 0, 0, 0);
            __syncthreads();
        }

        if (is_attn) {
            #pragma unroll
            for (int mi = 0; mi < 2; ++mi) {
                #pragma unroll
                for (int r = 0; r < 4; ++r) {
                    int gm = m0 + wm * 32 + mi * 16 + quad * 4 + r;
                    #pragma unroll
                    for (int ni = 0; ni < 4; ++ni) {
                        int gn = wn * 64 + ni * 16 + l16;
                        float v = acc[mi][ni][r] + battn[gn];
                        float mx = v;
                        #pragma unroll
                        for (int s = 1; s < 16; s <<= 1)
                            mx = fmaxf(mx, __shfl_xor(mx, s, 64));
                        float e = __expf(v - mx);
                        float sum = e;
                        #pragma unroll
                        for (int s = 1; s < 16; s <<= 1)
                            sum += __shfl_xor(sum, s, 64);
                        qawb[(size_t)gm * 128 + gn] = f32_to_bf16(e / sum);
                    }
                }
            }
        } else {
            #pragma unroll
            for (int mi = 0; mi < 2; ++mi) {
                #pragma unroll
                for (int r = 0; r < 4; ++r) {
                    int gm = m0 + wm * 32 + mi * 16 + quad * 4 + r;
                    #pragma unroll
                    for (int ni = 0; ni < 4; ++ni) {
                        int gn = n0 + wn * 64 + ni * 16 + l16;
                        qoffb[(size_t)gm * 256 + gn] = f32_to_bf16(acc[mi][ni][r] + boff[gn]);
                    }
                }
            }
        }
    }
}

// ---------------------------------------------------------------------------
// sample_kernel: b < 3200 -> head-partitioned fp8 deformable sampling with
// packed f32x2 accumulation; b >= 3200 -> tail weight transpose
// (Wout/W1/W2 -> WoT/W1T/W2T), overlapped with the sampling tail.
// qoff/qaw inputs are bf16.
// ---------------------------------------------------------------------------
__global__ __launch_bounds__(256) void sample_kernel(
    const unsigned char* __restrict__ vb,  // (6, 8, 7979, 32) fp8 e4m3
    const unsigned short* __restrict__ qoffb, // (6400, 256) bf16
    const unsigned short* __restrict__ qawb,  // (6400, 128) bf16
    const float* __restrict__ refpts,      // (6, 1, 6400, 4, 2)
    const int*   __restrict__ bev_mask,    // (6, 1, 6400, 4)
    const float* __restrict__ Wout, const float* __restrict__ W1,
    const float* __restrict__ W2,
    unsigned short* __restrict__ outsum,   // (6400, 256) bf16
    float* __restrict__ visb,              // (6400)
    unsigned short* __restrict__ wsT)
{
    __shared__ unsigned s_tab[NCAMS][272][4];   // [cam][sq*17+tup][corner]
    __shared__ float s_vis[NCAMS][16];
    __shared__ int   s_cnt[NCAMS];
    __shared__ int   s_nvis[16];

    const int bid = blockIdx.x;
    const int tid = threadIdx.x;

    if (bid >= 3200) {
        // ---- tail weight transpose (reuses s_tab as the LDS tile) ----
        int t = bid - 3200;
        const float* src; int K, N, dstoff;
        if (t < 64)       { src = Wout; K = 256;  N = 256;  dstoff = 163840; }
        else if (t < 320) { src = W1;   K = 256;  N = 1024; dstoff = 229376; t -= 64; }
        else              { src = W2;   K = 1024; N = 256;  dstoff = 491520; t -= 320; }
        int ntn = N >> 5;
        int kt = t / ntn, nt = t - kt * ntn;
        float (*tile)[33] = (float(*)[33])&s_tab[0][0][0];
        int tx = tid & 31, ty = tid >> 5;
        #pragma unroll
        for (int i = 0; i < 4; ++i)
            tile[ty + i * 8][tx] = src[(size_t)(kt * 32 + ty + i * 8) * N + nt * 32 + tx];
        __syncthreads();
        #pragma unroll
        for (int i = 0; i < 4; ++i) {
            int nn = nt * 32 + ty + i * 8;
            wsT[dstoff + (size_t)nn * K + kt * 32 + tx] = f32_to_bf16(tile[tx][ty + i * 8]);
        }
        return;
    }

    const int h   = bid & 7;
    const int q0  = (bid >> 3) * 16;
    const int sq  = tid >> 4;
    const int tup = tid & 15;
    const int lvl = tup >> 2;
    const int n_s = q0 + sq;
    const int tg  = (tid >> 2) & 3;
    const int cg  = tid & 3;

    if (tid < 96) {
        int cam = tid >> 4, q = tid & 15;
        const int* bm = bev_mask + ((size_t)cam * NQ + q0 + q) * 4;
        s_vis[cam][q] = ((bm[0] + bm[1] + bm[2] + bm[3]) > 0) ? 1.f : 0.f;
    }
    __syncthreads();
    if (tid < NCAMS) {
        float s = 0.f;
        #pragma unroll
        for (int q = 0; q < 16; ++q) s += s_vis[tid][q];
        s_cnt[tid] = (int)s;
    }
    if (tid >= 32 && tid < 48) {
        int q = tid - 32;
        float s = 0.f;
        #pragma unroll
        for (int cam = 0; cam < NCAMS; ++cam) s += s_vis[cam][q];
        s_nvis[q] = (int)s;
    }

    unsigned uoff = *(const unsigned*)(qoffb + (size_t)n_s * 256 + h * 32 + tup * 2);
    const float offx  = __uint_as_float(uoff << 16);
    const float offy  = __uint_as_float(uoff & 0xFFFF0000u);
    const float my_aw = __uint_as_float((unsigned)qawb[(size_t)n_s * 128 + h * 16 + tup] << 16);
    const int Wl   = (lvl == 0) ? 100 : (lvl == 1) ? 50 : (lvl == 2) ? 25 : 13;
    const int Hl   = (lvl == 0) ? 60  : (lvl == 1) ? 30 : (lvl == 2) ? 15 : 8;
    const int base = (lvl == 0) ? 0   : (lvl == 1) ? 6000 : (lvl == 2) ? 7500 : 7875;
    const float dx = offx / (float)Wl;
    const float dy = offy / (float)Hl;
    const int tabi = sq * 17 + tup;

    float2 rp[NCAMS];
    #pragma unroll
    for (int k = 0; k < NCAMS; ++k)
        rp[k] = *(const float2*)(refpts + (((size_t)k * NQ + n_s) * 4 + lvl) * 2);
    __syncthreads();   // covers s_cnt/s_nvis writes

    #pragma unroll
    for (int k = 0; k < NCAMS; ++k) {
        float fx = (rp[k].x + dx) * (float)Wl - 0.5f;
        float fy = (rp[k].y + dy) * (float)Hl - 0.5f;
        float x0f = floorf(fx), y0f = floorf(fy);
        float lx = fx - x0f, ly = fy - y0f;
        int x0 = (int)x0f, y0 = (int)y0f;
        int x1 = x0 + 1, y1 = y0 + 1;
        float wb = my_aw * s_vis[k][sq];
        float w00 = (1.f - lx) * (1.f - ly) * wb;
        float w01 = lx * (1.f - ly) * wb;
        float w10 = (1.f - lx) * ly * wb;
        float w11 = lx * ly * wb;
        bool vx0 = (x0 >= 0) & (x0 < Wl), vx1 = (x1 >= 0) & (x1 < Wl);
        bool vy0 = (y0 >= 0) & (y0 < Hl), vy1 = (y1 >= 0) & (y1 < Hl);
        uint4 o;
        o.x = (vx0 & vy0) ? (((unsigned)(base + y0 * Wl + x0) << 16) | f32_to_bf16(w00)) : 0u;
        o.y = (vx1 & vy0) ? (((unsigned)(base + y0 * Wl + x1) << 16) | f32_to_bf16(w01)) : 0u;
        o.z = (vx0 & vy1) ? (((unsigned)(base + y1 * Wl + x0) << 16) | f32_to_bf16(w10)) : 0u;
        o.w = (vx1 & vy1) ? (((unsigned)(base + y1 * Wl + x1) << 16) | f32_to_bf16(w11)) : 0u;
        *(uint4*)&s_tab[k][tabi][0] = o;
    }
    __syncthreads();

    f32x2 a01 = {0.f, 0.f}, a23 = {0.f, 0.f};
    f32x2 a45 = {0.f, 0.f}, a67 = {0.f, 0.f};

    for (int k = 0; k < NCAMS; ++k) {
        if (s_cnt[k] == 0) continue;
        const char* vkh = (const char*)vb + (size_t)(k * 8 + h) * (LTOT * 32) + cg * 8;
        #pragma unroll
        for (int j = 0; j < 4; ++j) {
            uint4 t4 = *(const uint4*)&s_tab[k][sq * 17 + tg * 4 + j][0];
            #pragma unroll
            for (int corner = 0; corner < 4; ++corner) {
                unsigned tc = (corner == 0) ? t4.x : (corner == 1) ? t4.y
                            : (corner == 2) ? t4.z : t4.w;
                float w = __uint_as_float(tc << 16);
                f32x2 w2 = {w, w};
                uint2 d = *(const uint2*)(vkh + ((size_t)(tc >> 16) << 5));
                a01 += w2 * __builtin_amdgcn_cvt_pk_f32_fp8(d.x, false);
                a23 += w2 * __builtin_amdgcn_cvt_pk_f32_fp8(d.x, true);
                a45 += w2 * __builtin_amdgcn_cvt_pk_f32_fp8(d.y, false);
                a67 += w2 * __builtin_amdgcn_cvt_pk_f32_fp8(d.y, true);
            }
        }
    }

    float a0 = a01.x, a1 = a01.y, a2 = a23.x, a3 = a23.y;
    float a4 = a45.x, a5 = a45.y, a6 = a67.x, a7 = a67.y;

    a0 += __shfl_xor(a0, 4, 64); a0 += __shfl_xor(a0, 8, 64);
    a1 += __shfl_xor(a1, 4, 64); a1 += __shfl_xor(a1, 8, 64);
    a2 += __shfl_xor(a2, 4, 64); a2 += __shfl_xor(a2, 8, 64);
    a3 += __shfl_xor(a3, 4, 64); a3 += __shfl_xor(a3, 8, 64);
    a4 += __shfl_xor(a4, 4, 64); a4 += __shfl_xor(a4, 8, 64);
    a5 += __shfl_xor(a5, 4, 64); a5 += __shfl_xor(a5, 8, 64);
    a6 += __shfl_xor(a6, 4, 64); a6 += __shfl_xor(a6, 8, 64);
    a7 += __shfl_xor(a7, 4, 64); a7 += __shfl_xor(a7, 8, 64);

    if ((tid & 12) == 0) {
        int nv = s_nvis[sq];
        float sc = 1.f / (float)(nv > 0 ? nv : 1);
        uint4 o;
        o.x = f32_to_bf16(a0 * sc) | ((unsigned)f32_to_bf16(a1 * sc) << 16);
        o.y = f32_to_bf16(a2 * sc) | ((unsigned)f32_to_bf16(a3 * sc) << 16);
        o.z = f32_to_bf16(a4 * sc) | ((unsigned)f32_to_bf16(a5 * sc) << 16);
        o.w = f32_to_bf16(a6 * sc) | ((unsigned)f32_to_bf16(a7 * sc) << 16);
        *(uint4*)(outsum + (size_t)n_s * 256 + h * 32 + cg * 8) = o;
    }
    if (h == 0 && tid < 16) visb[q0 + tid] = (s_nvis[tid] > 0) ? 1.f : 0.f;
}

// ---------------------------------------------------------------------------
// Fused output-projection + residual + LN1 + FFN layer 1.
// Phase 1: BM=32 BN=256 K=256: x = LN(outsum@W_out + residual algebra),
//          written to xbuf (fp32 global, for LN2) and xs (bf16 LDS).
// Phase 2: h = relu(x @ W1 + b1) with x-fragments from LDS, W1T streamed
//          in 128x64 tiles (L2-resident). Writes hbf.
// ---------------------------------------------------------------------------
__global__ __launch_bounds__(256) void projln1_ffn1_kernel(
    const unsigned short* __restrict__ A, const unsigned short* __restrict__ BT,
    const unsigned short* __restrict__ W1T,
    const float* __restrict__ query, const float* __restrict__ visb,
    const float* __restrict__ b_out, const float* __restrict__ g,
    const float* __restrict__ b, const float* __restrict__ b1,
    float* __restrict__ xout, unsigned short* __restrict__ hbf)
{
    const int K = 256;
    __shared__ __align__(16) unsigned short As[32][40];
    __shared__ __align__(16) unsigned short Bs[256][40];
    __shared__ __align__(16) unsigned short xs[32][264];
    __shared__ __align__(16) unsigned short Bs2[128][72];
    __shared__ float sred[2][4][4][2];
    __shared__ float ssred[2][4][4][2];
    __shared__ float s_mu[32], s_rs[32];

    const int tid  = threadIdx.x;
    const int wave = tid >> 6, lane = tid & 63;
    const int wm = wave >> 1, wn = wave & 1;
    const int quad = lane >> 4, l16 = lane & 15;
    const int m0 = blockIdx.x * 32;

    f32x4 acc[8] = {};

    for (int k0 = 0; k0 < K; k0 += 32) {
        {
            int r = tid >> 3, kc = (tid & 7) * 4;
            *(uint2*)&As[r][kc] = *(const uint2*)(A + (size_t)(m0 + r) * K + k0 + kc);
        }
        {
            const unsigned short* src = BT + (size_t)tid * K + k0;
            *(uint4*)&Bs[tid][0]  = *(const uint4*)(src);
            *(uint4*)&Bs[tid][8]  = *(const uint4*)(src + 8);
            *(uint4*)&Bs[tid][16] = *(const uint4*)(src + 16);
            *(uint4*)&Bs[tid][24] = *(const uint4*)(src + 24);
        }
        __syncthreads();
        bf16x8 af = *(const bf16x8*)&As[wm * 16 + l16][quad * 8];
        #pragma unroll
        for (int ni = 0; ni < 8; ++ni) {
            bf16x8 bfr = *(const bf16x8*)&Bs[wn * 128 + ni * 16 + l16][quad * 8];
            acc[ni] = __builtin_amdgcn_mfma_f32_16x16x32_bf16(af, bfr, acc[ni], 0, 0, 0);
        }
        __syncthreads();
    }

    float vals[8][4];
    #pragma unroll
    for (int r = 0; r < 4; ++r) {
        int gm = m0 + wm * 16 + quad * 4 + r;
        float vs = visb[gm];
        float s = 0.f, ss = 0.f;
        #pragma unroll
        for (int ni = 0; ni < 8; ++ni) {
            int gn = wn * 128 + ni * 16 + l16;
            float v = acc[ni][r] + vs * b_out[gn]
                    + query[(size_t)gm * 256 + gn] * (1.f + vs);
            vals[ni][r] = v;
            s += v; ss += v * v;
        }
        #pragma unroll
        for (int m = 1; m < 16; m <<= 1) {
            s  += __shfl_xor(s,  m, 64);
            ss += __shfl_xor(ss, m, 64);
        }
        if (l16 == 0) {
            sred[wm][quad][r][wn]  = s;
            ssred[wm][quad][r][wn] = ss;
        }
    }
    __syncthreads();
    if (tid < 32) {
        int lwm = tid >> 4, lq = (tid >> 2) & 3, lr = tid & 3;
        float s  = sred[lwm][lq][lr][0]  + sred[lwm][lq][lr][1];
        float ss = ssred[lwm][lq][lr][0] + ssred[lwm][lq][lr][1];
        float mu = s * (1.f / 256.f);
        float var = ss * (1.f / 256.f) - mu * mu;
        s_mu[tid] = mu;
        s_rs[tid] = rsqrtf(var + 1e-5f);
    }
    __syncthreads();

    #pragma unroll
    for (int r = 0; r < 4; ++r) {
        int rowl = wm * 16 + quad * 4 + r;
        int gm = m0 + rowl;
        float mu = s_mu[rowl], rs = s_rs[rowl];
        #pragma unroll
        for (int ni = 0; ni < 8; ++ni) {
            int gn = wn * 128 + ni * 16 + l16;
            float res = (vals[ni][r] - mu) * rs * g[gn] + b[gn];
            xout[(size_t)gm * 256 + gn] = res;
            xs[rowl][gn] = f32_to_bf16(res);
        }
    }
    // (xs visible to all after the first phase-2 __syncthreads)

    // ---- phase 2: h = relu(x @ W1 + b1), x in LDS ----
    for (int nc = 0; nc < 8; ++nc) {
        f32x4 acc2[4] = {};
        for (int k0 = 0; k0 < 256; k0 += 64) {
            #pragma unroll
            for (int i = 0; i < 4; ++i) {          // stage W1T 128 rows x 64 k
                int idx = tid + 256 * i;
                int rr = idx >> 3, c8 = (idx & 7) * 8;
                *(uint4*)&Bs2[rr][c8] =
                    *(const uint4*)(W1T + (size_t)(nc * 128 + rr) * 256 + k0 + c8);
            }
            __syncthreads();
            #pragma unroll
            for (int s = 0; s < 2; ++s) {
                bf16x8 a2 = *(const bf16x8*)&xs[wm * 16 + l16][k0 + s * 32 + quad * 8];
                #pragma unroll
                for (int ni = 0; ni < 4; ++ni) {
                    bf16x8 b2v = *(const bf16x8*)&Bs2[wn * 64 + ni * 16 + l16][s * 32 + quad * 8];
                    acc2[ni] = __builtin_amdgcn_mfma_f32_16x16x32_bf16(a2, b2v, acc2[ni], 0, 0, 0);
                }
            }
            __syncthreads();
        }
        #pragma unroll
        for (int ni = 0; ni < 4; ++ni) {
            #pragma unroll
            for (int r = 0; r < 4; ++r) {
                int gm = m0 + wm * 16 + quad * 4 + r;
                int gn = nc * 128 + wn * 64 + ni * 16 + l16;
                float v = acc2[ni][r] + b1[gn];
                hbf[(size_t)gm * 1024 + gn] = f32_to_bf16(fmaxf(v, 0.f));
            }
        }
    }
}

// ---------------------------------------------------------------------------
// MFMA bf16 GEMM, BM=64 BN=128 BK=32, bf16 A + BT. Split-K over gridDim.z.
// mode 1: relu -> bf16 out; mode 2: plain bf16 out (split-K partials).
// ---------------------------------------------------------------------------
__global__ __launch_bounds__(256) void gemm64_kernel(
    const unsigned short* __restrict__ A, const unsigned short* __restrict__ BT,
    const float* __restrict__ bias, unsigned short* __restrict__ Cb,
    int M, int N, int K, int mode)
{
    __shared__ __align__(16) unsigned short As[64][40];
    __shared__ __align__(16) unsigned short Bs[128][40];

    const int tid  = threadIdx.x;
    const int wave = tid >> 6, lane = tid & 63;
    const int wm = wave >> 1, wn = wave & 1;
    const int quad = lane >> 4, l16 = lane & 15;
    const int m0 = blockIdx.y * 64, n0 = blockIdx.x * 128;
    const int nz = gridDim.z;
    const int klen = K / nz;
    const int kbase = blockIdx.z * klen;

    f32x4 acc[2][4] = {};

    for (int k0 = kbase; k0 < kbase + klen; k0 += 32) {
        {
            int r = tid >> 2, kc = (tid & 3) * 8;
            int gr = m0 + r;
            uint4 d = (gr < M) ? *(const uint4*)(A + (size_t)gr * K + k0 + kc)
                               : make_uint4(0u, 0u, 0u, 0u);
            *(uint4*)&As[r][kc] = d;
        }
        #pragma unroll
        for (int i = 0; i < 2; ++i) {
            int idx = tid + 256 * i;
            int r = idx >> 2, kc = (idx & 3) * 8;
            *(uint4*)&Bs[r][kc] = *(const uint4*)(BT + (size_t)(n0 + r) * K + k0 + kc);
        }
        __syncthreads();
        bf16x8 af[2], bfr[4];
        #pragma unroll
        for (int mi = 0; mi < 2; ++mi)
            af[mi] = *(const bf16x8*)&As[wm * 32 + mi * 16 + l16][quad * 8];
        #pragma unroll
        for (int ni = 0; ni < 4; ++ni)
            bfr[ni] = *(const bf16x8*)&Bs[wn * 64 + ni * 16 + l16][quad * 8];
        #pragma unroll
        for (int mi = 0; mi < 2; ++mi)
            #pragma unroll
            for (int ni = 0; ni < 4; ++ni)
                acc[mi][ni] = __builtin_amdgcn_mfma_f32_16x16x32_bf16(
                    af[mi], bfr[ni], acc[mi][ni], 0, 0, 0);
        __syncthreads();
    }

    const float* bz = (blockIdx.z == 0) ? bias : nullptr;
    unsigned short* Cz = Cb + (size_t)blockIdx.z * M * N;

    #pragma unroll
    for (int mi = 0; mi < 2; ++mi) {
        #pragma unroll
        for (int r = 0; r < 4; ++r) {
            int gm = m0 + wm * 32 + mi * 16 + quad * 4 + r;
            if (gm >= M) continue;
            #pragma unroll
            for (int ni = 0; ni < 4; ++ni) {
                int gn = n0 + wn * 64 + ni * 16 + l16;
                float v = acc[mi][ni][r] + (bz ? bz[gn] : 0.f);
                if (mode == 1) v = fmaxf(v, 0.f);
                Cz[(size_t)gm * N + gn] = f32_to_bf16(v);
            }
        }
    }
}

// ---------------------------------------------------------------------------
// Vectorized LN2: one wave per row; x fp32 + two bf16 split-K halves.
// ---------------------------------------------------------------------------
__global__ __launch_bounds__(256) void ln2v_kernel(
    const float* __restrict__ x, const unsigned short* __restrict__ f0,
    const unsigned short* __restrict__ f1,
    const float* __restrict__ g, const float* __restrict__ b,
    float* __restrict__ out)
{
    int row  = blockIdx.x * 4 + (threadIdx.x >> 6);
    int lane = threadIdx.x & 63;
    size_t base = (size_t)row * 256 + lane * 4;
    float4 xv = *(const float4*)(x + base);
    uint2 u0 = *(const uint2*)(f0 + base);
    uint2 u1 = *(const uint2*)(f1 + base);
    float t0 = xv.x + __uint_as_float(u0.x << 16)        + __uint_as_float(u1.x << 16);
    float t1 = xv.y + __uint_as_float(u0.x & 0xFFFF0000u) + __uint_as_float(u1.x & 0xFFFF0000u);
    float t2 = xv.z + __uint_as_float(u0.y << 16)        + __uint_as_float(u1.y << 16);
    float t3 = xv.w + __uint_as_float(u0.y & 0xFFFF0000u) + __uint_as_float(u1.y & 0xFFFF0000u);
    float s  = t0 + t1 + t2 + t3;
    float ss = t0 * t0 + t1 * t1 + t2 * t2 + t3 * t3;
    #pragma unroll
    for (int m = 1; m < 64; m <<= 1) {
        s  += __shfl_xor(s,  m, 64);
        ss += __shfl_xor(ss, m, 64);
    }
    float mu = s * (1.f / 256.f);
    float rs = rsqrtf(ss * (1.f / 256.f) - mu * mu + 1e-5f);
    float4 gv = *(const float4*)(g + lane * 4);
    float4 bv = *(const float4*)(b + lane * 4);
    float4 o;
    o.x = (t0 - mu) * rs * gv.x + bv.x;
    o.y = (t1 - mu) * rs * gv.y + bv.y;
    o.z = (t2 - mu) * rs * gv.z + bv.z;
    o.w = (t3 - mu) * rs * gv.w + bv.w;
    *(float4*)(out + base) = o;
}

// ---------------------------------------------------------------------------
extern "C" void kernel_launch(void* const* d_in, const int* in_sizes, int n_in,
                              void* d_out, int out_size, void* d_ws, size_t ws_size,
                              hipStream_t stream)
{
    const float* query   = (const float*)d_in[0];
    const float* value   = (const float*)d_in[2];
    const float* refpts  = (const float*)d_in[3];
    const int*   bevmask = (const int*)d_in[6];
    const float* W_value = (const float*)d_in[7];
    const float* b_value = (const float*)d_in[8];
    const float* W_off   = (const float*)d_in[9];
    const float* b_off   = (const float*)d_in[10];
    const float* W_attn  = (const float*)d_in[11];
    const float* b_attn  = (const float*)d_in[12];
    const float* W_out   = (const float*)d_in[13];
    const float* b_out   = (const float*)d_in[14];
    const float* ln1_g   = (const float*)d_in[15];
    const float* ln1_b   = (const float*)d_in[16];
    const float* W1      = (const float*)d_in[17];
    const float* b1      = (const float*)d_in[18];
    const float* W2      = (const float*)d_in[19];
    const float* b2      = (const float*)d_in[20];
    const float* ln2_g   = (const float*)d_in[21];
    const float* ln2_b   = (const float*)d_in[22];
    float* out = (float*)d_out;

    // workspace layout (byte offsets, temporal aliasing):
    //  [0)          vb fp8 12,255,744       (head -> sample)
    //  [0)          xbuf fp32 6,553,600     (projln1_ffn1 -> ln2) [vb dead]
    //  [13,000,000) hbf bf16 13,107,200     (projln1_ffn1 -> ffn2)
    //  [27,000,000) qoffb bf16 3,276,800    (head -> sample)
    //  [31,000,000) qawb bf16 1,638,400     (head -> sample)
    //  [33,000,000) outsum bf16 3,276,800   (sample -> projln1_ffn1)
    //  [36,500,000) visb 25,600             (sample -> projln1_ffn1)
    //  [36,600,000) wsT bf16 1,507,328      (wt_head/sample-tail -> GEMMs)
    //  [39,000,000) ffnout bf16 2x3,276,800 (ffn2 -> ln2)
    char* ws = (char*)d_ws;
    unsigned char*  vb     = (unsigned char*)(ws + 0);
    float*          xbuf   = (float*)(ws + 0);
    unsigned short* hbf    = (unsigned short*)(ws + 13000000);
    unsigned short* qoffb  = (unsigned short*)(ws + 27000000);
    unsigned short* qawb   = (unsigned short*)(ws + 31000000);
    unsigned short* outsum = (unsigned short*)(ws + 33000000);
    float*          visb   = (float*)(ws + 36500000);
    unsigned short* wsT    = (unsigned short*)(ws + 36600000);
    unsigned short* ffnout = (unsigned short*)(ws + 39000000);

    unsigned short* WvT = wsT;            // [256][256]
    unsigned short* WqT = wsT + 65536;    // [384][256]
    unsigned short* WoT = wsT + 163840;   // [256][256]
    unsigned short* W1T = wsT + 229376;   // [1024][256]
    unsigned short* W2T = wsT + 491520;   // [256][1024]

    // L0: head-side weights -> transposed bf16 (160 blocks)
    wt_head_kernel<<<dim3(160), 256, 0, stream>>>(
        W_value, W_off, W_attn, wsT);
    // L1: value proj (750 blocks, fp8 out) + query proj (300 blocks, bf16 out)
    head_kernel<<<dim3(1050), 256, 0, stream>>>(
        value, query, WvT, WqT, b_value, b_off, b_attn, vb, qoffb, qawb);
    // L2: sampling (3200) + tail weight transpose (576, overlapped)
    sample_kernel<<<dim3(3776), 256, 0, stream>>>(
        vb, qoffb, qawb, refpts, bevmask, W_out, W1, W2, outsum, visb, wsT);
    // L3: x = LN(outsum@W_out + residual) ; h = relu(x@W1+b1)  (fused)
    projln1_ffn1_kernel<<<dim3(200), 256, 0, stream>>>(
        outsum, WoT, W1T, query, visb, b_out, ln1_g, ln1_b, b1, xbuf, hbf);
    // L4: ffnout[z] = bf16(h @ W2 (+b2 on z=0)), split-K x2
    gemm64_kernel<<<dim3(2, 100, 2), 256, 0, stream>>>(
        hbf, W2T, b2, ffnout, NQ, 256, DFFN, 2);
    // L5: out = LN(x + f0 + f1)
    ln2v_kernel<<<dim3(1600), 256, 0, stream>>>(
        xbuf, ffnout, ffnout + (size_t)NQ * 256, ln2_g, ln2_b, out);
}